// Round 5
// baseline (52521.454 us; speedup 1.0000x reference)
//
#include <hip/hip_runtime.h>
#include <cstddef>
#include <cstdint>

typedef __attribute__((ext_vector_type(8))) short short8v;
typedef __attribute__((ext_vector_type(4))) float f32x4;

__device__ __forceinline__ float sigmf(float x) { return 1.0f / (1.0f + __expf(-x)); }

__device__ __forceinline__ unsigned short bf16_rn(float x) {
    union { float f; unsigned u; } v; v.f = x;
    unsigned r = v.u + 0x7FFF + ((v.u >> 16) & 1);
    return (unsigned short)(r >> 16);
}
__device__ __forceinline__ float bf16_to_f(unsigned short h) {
    union { unsigned u; float f; } v; v.u = ((unsigned)h) << 16; return v.f;
}
__device__ __forceinline__ unsigned long long pack4(unsigned short a, unsigned short b,
                                                    unsigned short c, unsigned short d) {
    return (unsigned long long)a | ((unsigned long long)b << 16)
         | ((unsigned long long)c << 32) | ((unsigned long long)d << 48);
}

#define MFMA_(d, va, vb) d = __builtin_amdgcn_mfma_f32_16x16x32_bf16(va, vb, d, 0, 0, 0)

// ---------------------------------------------------------------------------
// Software grid barrier: bar[0]=arrive count, bar[1]=generation.
// Requires all blocks co-resident (grid=64 <= 256 CUs, __launch_bounds__(256,1)).
// ---------------------------------------------------------------------------
__device__ __forceinline__ void grid_barrier(unsigned* bar, int nblk)
{
    __syncthreads();
    if (threadIdx.x == 0) {
        __threadfence();   // release all prior writes device-wide
        unsigned my_gen = __hip_atomic_load(&bar[1], __ATOMIC_RELAXED, __HIP_MEMORY_SCOPE_AGENT);
        unsigned prev = __hip_atomic_fetch_add(&bar[0], 1u, __ATOMIC_ACQ_REL, __HIP_MEMORY_SCOPE_AGENT);
        if (prev == (unsigned)(nblk - 1)) {
            __hip_atomic_store(&bar[0], 0u, __ATOMIC_RELAXED, __HIP_MEMORY_SCOPE_AGENT);
            __hip_atomic_fetch_add(&bar[1], 1u, __ATOMIC_RELEASE, __HIP_MEMORY_SCOPE_AGENT);
        } else {
            unsigned g;
            do { g = __hip_atomic_load(&bar[1], __ATOMIC_ACQUIRE, __HIP_MEMORY_SCOPE_AGENT); }
            while (g == my_gen);
        }
        __threadfence();   // acquire
    }
    __syncthreads();
}

// ---------------------------------------------------------------------------
// Batched fp32 GEMM via bf16-split MFMA (validated R3): C = A@W^T + bias.
// NS=3 fp32-accurate; NS=1 plain bf16 (output-facing only).
// ---------------------------------------------------------------------------
template <int NS>
__launch_bounds__(256, 2)
__global__ void gemm_mfma_split(const float* __restrict__ A, int lda,
                                const float* __restrict__ W, int ldw,
                                float* __restrict__ C, int ldc,
                                const float* __restrict__ bias,
                                int M, int N, int K)
{
    __shared__ unsigned short Abf[NS][128][40];
    __shared__ unsigned short Bbf[NS][128][40];
    const int tid = threadIdx.x;
    const int m0 = blockIdx.y * 128, n0 = blockIdx.x * 128;
    const int wave = tid >> 6, lane = tid & 63;
    const int wr = wave >> 1, wc = wave & 1;
    const int lr = lane & 15, lk = (lane >> 4) * 8;

    f32x4 acc[4][4];
#pragma unroll
    for (int i = 0; i < 4; ++i)
#pragma unroll
        for (int j = 0; j < 4; ++j) acc[i][j] = (f32x4){0.f, 0.f, 0.f, 0.f};

    const int arow = tid >> 1;
    const int akh  = (tid & 1) * 16;

    int gr = m0 + arow; if (gr > M - 1) gr = M - 1;
    int gn = n0 + arow; if (gn > N - 1) gn = N - 1;
    const float* aptr = A + (size_t)gr * lda + akh;
    const float* wptr = W + (size_t)gn * ldw + akh;

    for (int k0 = 0; k0 < K; k0 += 32) {
#pragma unroll
        for (int q = 0; q < 4; ++q) {
            float4 v = *(const float4*)(aptr + k0 + q * 4);
            float xs[4] = {v.x, v.y, v.z, v.w};
            unsigned short h[4], hm[4], hl[4];
#pragma unroll
            for (int e = 0; e < 4; ++e) {
                h[e] = bf16_rn(xs[e]);
                if (NS == 3) {
                    float r1 = xs[e] - bf16_to_f(h[e]);
                    hm[e] = bf16_rn(r1);
                    hl[e] = bf16_rn(r1 - bf16_to_f(hm[e]));
                }
            }
            *(unsigned long long*)&Abf[0][arow][akh + q * 4] = pack4(h[0], h[1], h[2], h[3]);
            if (NS == 3) {
                *(unsigned long long*)&Abf[1][arow][akh + q * 4] = pack4(hm[0], hm[1], hm[2], hm[3]);
                *(unsigned long long*)&Abf[2][arow][akh + q * 4] = pack4(hl[0], hl[1], hl[2], hl[3]);
            }
        }
#pragma unroll
        for (int q = 0; q < 4; ++q) {
            float4 v = *(const float4*)(wptr + k0 + q * 4);
            float xs[4] = {v.x, v.y, v.z, v.w};
            unsigned short h[4], hm[4], hl[4];
#pragma unroll
            for (int e = 0; e < 4; ++e) {
                h[e] = bf16_rn(xs[e]);
                if (NS == 3) {
                    float r1 = xs[e] - bf16_to_f(h[e]);
                    hm[e] = bf16_rn(r1);
                    hl[e] = bf16_rn(r1 - bf16_to_f(hm[e]));
                }
            }
            *(unsigned long long*)&Bbf[0][arow][akh + q * 4] = pack4(h[0], h[1], h[2], h[3]);
            if (NS == 3) {
                *(unsigned long long*)&Bbf[1][arow][akh + q * 4] = pack4(hm[0], hm[1], hm[2], hm[3]);
                *(unsigned long long*)&Bbf[2][arow][akh + q * 4] = pack4(hl[0], hl[1], hl[2], hl[3]);
            }
        }
        __syncthreads();

        short8v a[NS][4], b[4];
#pragma unroll
        for (int p = 0; p < NS; ++p)
#pragma unroll
            for (int i = 0; i < 4; ++i)
                a[p][i] = *(const short8v*)&Abf[p][wr * 64 + i * 16 + lr][lk];

#pragma unroll
        for (int q = 0; q < NS; ++q) {
#pragma unroll
            for (int j = 0; j < 4; ++j)
                b[j] = *(const short8v*)&Bbf[q][wc * 64 + j * 16 + lr][lk];
            const int pmax = (NS == 1) ? 1 : (3 - q);
#pragma unroll
            for (int p = 0; p < 3; ++p) {
                if (p >= pmax) break;
#pragma unroll
                for (int i = 0; i < 4; ++i)
#pragma unroll
                    for (int j = 0; j < 4; ++j)
                        acc[i][j] = __builtin_amdgcn_mfma_f32_16x16x32_bf16(
                            a[p][i], b[j], acc[i][j], 0, 0, 0);
            }
        }
        __syncthreads();
    }

    const int crow = (lane >> 4) * 4;
#pragma unroll
    for (int i = 0; i < 4; ++i) {
        int mbase = m0 + wr * 64 + i * 16 + crow;
#pragma unroll
        for (int j = 0; j < 4; ++j) {
            int n = n0 + wc * 64 + j * 16 + lr;
            if (n < N) {
                float bv = bias[n];
#pragma unroll
                for (int r = 0; r < 4; ++r) {
                    int m = mbase + r;
                    if (m < M) C[(size_t)m * ldc + n] = acc[i][j][r] + bv;
                }
            }
        }
    }
}

// ---------------------------------------------------------------------------
// Split fp32 matrix [R rows x C cols] (ld, col offset) into 3 bf16 planes.
// ---------------------------------------------------------------------------
__launch_bounds__(256)
__global__ void split3(const float* __restrict__ src, int ld, int c0,
                       unsigned short* __restrict__ dst, int R, int C)
{
    size_t idx = (size_t)blockIdx.x * 256 + threadIdx.x;
    if (idx >= (size_t)R * C) return;
    int r = idx / C, c = idx % C;
    float x = src[(size_t)r * ld + c0 + c];
    unsigned short hi = bf16_rn(x); float r1 = x - bf16_to_f(hi);
    unsigned short md = bf16_rn(r1);
    unsigned short lo = bf16_rn(r1 - bf16_to_f(md));
    size_t pc = (size_t)R * C;
    dst[idx] = hi; dst[pc + idx] = md; dst[2 * pc + idx] = lo;
}

__launch_bounds__(256)
__global__ void zero_f(float* __restrict__ p, int n)
{
    int i = blockIdx.x * 256 + threadIdx.x;
    if (i < n) p[i] = 0.f;
}

__launch_bounds__(256)
__global__ void vec_add2(const float* __restrict__ a, const float* __restrict__ b,
                         float* __restrict__ o, int n)
{
    int i = blockIdx.x * 256 + threadIdx.x;
    if (i < n) o[i] = a[i] + b[i];
}

__launch_bounds__(256)
__global__ void sample0_fill(const float* __restrict__ emW, const float* __restrict__ emb,
                             float* __restrict__ samples)
{
    int idx = blockIdx.x * 256 + threadIdx.x; // 65536
    int d = idx & 1023;
    samples[idx] = emW[(size_t)d * 20000 + 19998] + emb[d];
}

// ---------------------------------------------------------------------------
// Staging of [3][64][1024]-bf16 plane k-chunk into LDS [3][64][72].
// ---------------------------------------------------------------------------
__device__ __forceinline__ void stage_planes(unsigned short lb[3][64][72],
                                             const unsigned short* __restrict__ src,
                                             int k0, int tid)
{
    for (int i = tid; i < 1536; i += 256) {
        int p = i >> 9, rem = i & 511, r = rem >> 3, kg = rem & 7;
        *(short8v*)&lb[p][r][kg * 8] =
            *(const short8v*)&src[(size_t)p * 65536 + r * 1024 + k0 + kg * 8];
    }
}

// ---------------------------------------------------------------------------
// Persistent encoder: 160 LSTM steps (80 real + 80 pad), grid = 64 blocks.
// Block bid owns j-cols [bid*16, bid*16+16) of h/c; c lives in registers.
// ---------------------------------------------------------------------------
__launch_bounds__(256, 1)
__global__ void coop_enc(const unsigned short* __restrict__ Wpl,  // [3][4096][1024]
                         const float* __restrict__ Xbig,          // [80][64][4096]
                         const float* __restrict__ benc,          // [4096]
                         unsigned short* __restrict__ hpl,        // [2][3][64][1024]
                         float* __restrict__ enc_seq,
                         float* __restrict__ enc_pad,
                         unsigned* __restrict__ bar)
{
    __shared__ unsigned short lbuf[3][64][72];
    __shared__ float gbuf[4][64][20];
    const int bid = blockIdx.x, tid = threadIdx.x;
    const int w = tid >> 6, lane = tid & 63;
    const int lr = lane & 15, hk = lane >> 4;
    const int j0 = bid * 16;
    const int gm = tid >> 2, gj = (tid & 3) * 4;
    float c4[4] = {0.f, 0.f, 0.f, 0.f};

    for (int s = 0; s < 160; ++s) {
        const unsigned short* hin = hpl + (s & 1) * 196608;
        unsigned short* hout = hpl + ((s + 1) & 1) * 196608;

        f32x4 acc[4];
#pragma unroll
        for (int g = 0; g < 4; ++g) acc[g] = (f32x4){0.f, 0.f, 0.f, 0.f};

        for (int c = 0; c < 16; ++c) {
            stage_planes(lbuf, hin, c * 64, tid);
            __syncthreads();
            const int kb = c * 64;
#pragma unroll
            for (int kk = 0; kk < 2; ++kk) {
                short8v a[3], b[3][4];
#pragma unroll
                for (int p = 0; p < 3; ++p)
                    a[p] = *(const short8v*)&lbuf[p][w * 16 + lr][kk * 32 + hk * 8];
#pragma unroll
                for (int q = 0; q < 3; ++q)
#pragma unroll
                    for (int g = 0; g < 4; ++g)
                        b[q][g] = *(const short8v*)&Wpl[((size_t)q * 4096 + g * 1024 + j0 + lr) * 1024 + kb + kk * 32 + hk * 8];
#pragma unroll
                for (int g = 0; g < 4; ++g) {
                    MFMA_(acc[g], a[0], b[0][g]);
                    MFMA_(acc[g], a[0], b[1][g]);
                    MFMA_(acc[g], a[1], b[0][g]);
                    MFMA_(acc[g], a[1], b[1][g]);
                    MFMA_(acc[g], a[0], b[2][g]);
                    MFMA_(acc[g], a[2], b[0][g]);
                }
            }
            __syncthreads();
        }
#pragma unroll
        for (int g = 0; g < 4; ++g)
#pragma unroll
            for (int r = 0; r < 4; ++r)
                gbuf[g][w * 16 + hk * 4 + r][lr] = acc[g][r];
        __syncthreads();

        // gates for (row gm, cols j0+gj..+4)
        {
            float ggx[4][4];
#pragma unroll
            for (int g = 0; g < 4; ++g) {
                float4 gv = *(const float4*)&gbuf[g][gm][gj];
                float4 xv;
                if (s < 80) xv = *(const float4*)&Xbig[((size_t)s * 64 + gm) * 4096 + g * 1024 + j0 + gj];
                else        xv = *(const float4*)&benc[g * 1024 + j0 + gj];
                ggx[g][0] = gv.x + xv.x; ggx[g][1] = gv.y + xv.y;
                ggx[g][2] = gv.z + xv.z; ggx[g][3] = gv.w + xv.w;
            }
            float* st = (s < 80) ? (enc_seq + (size_t)s * 65536) : (enc_pad + (size_t)(s - 80) * 65536);
#pragma unroll
            for (int jj = 0; jj < 4; ++jj) {
                float cn = sigmf(ggx[1][jj]) * c4[jj] + sigmf(ggx[0][jj]) * tanhf(ggx[2][jj]);
                float hn = sigmf(ggx[3][jj]) * tanhf(cn);
                c4[jj] = cn;
                int col = j0 + gj + jj;
                st[gm * 1024 + col] = hn;
                unsigned short hi = bf16_rn(hn); float r1 = hn - bf16_to_f(hi);
                unsigned short md = bf16_rn(r1);
                unsigned short lo = bf16_rn(r1 - bf16_to_f(md));
                hout[gm * 1024 + col] = hi;
                hout[65536 + gm * 1024 + col] = md;
                hout[131072 + gm * 1024 + col] = lo;
            }
        }
        grid_barrier(bar, 64);
    }
}

// ---------------------------------------------------------------------------
// Persistent decoder: 80 warm-up steps + 80 attention-decode steps.
// ---------------------------------------------------------------------------
__launch_bounds__(256, 1)
__global__ void coop_dec(const unsigned short* __restrict__ WhhPl,   // [3][4096][1024]
                         const unsigned short* __restrict__ WihcPl,  // [3][4096][1024]
                         const unsigned short* __restrict__ W2fPl,   // [3][1024][1024]
                         const float* __restrict__ Xwarm,            // [80][64][4096]
                         const float* __restrict__ S_g,              // [80][64][4096]
                         const float* __restrict__ ctxS,             // [80][64][1024]
                         const float* __restrict__ S_log,            // [80][64][80]
                         const float* __restrict__ W1,               // [80][2048] (h-cols 0..1024)
                         const float* __restrict__ enc_seq,          // E [80][64][1024]
                         const float* __restrict__ enc_pad,          // [80][64][1024]
                         const float* __restrict__ prelu_w,
                         unsigned short* __restrict__ hpl,           // [2][3][64][1024]
                         unsigned short* __restrict__ fpl,           // [3][64][1024]
                         unsigned short* __restrict__ ctxpl,         // [3][64][1024]
                         float* __restrict__ h_fp32,                 // [64][1024]
                         float* __restrict__ h_all,                  // [80][64][1024]
                         unsigned* __restrict__ bar)
{
    __shared__ unsigned short lbuf[3][64][72];
    __shared__ float gbuf[4][64][20];
    __shared__ float hsm[1024];
    __shared__ float wsm[80];
    __shared__ float rbuf[128];
    const int bid = blockIdx.x, tid = threadIdx.x;
    const int w = tid >> 6, lane = tid & 63;
    const int lr = lane & 15, hk = lane >> 4;
    const int j0 = bid * 16;
    const int gm = tid >> 2, gj = (tid & 3) * 4;
    float c4[4] = {0.f, 0.f, 0.f, 0.f};
    const float pw = prelu_w[0];

    for (int s = 0; s < 160; ++s) {
        const unsigned short* hin = hpl + (s & 1) * 196608;
        unsigned short* hout = hpl + ((s + 1) & 1) * 196608;
        const int t = s - 80;

        if (s >= 80) {
            // ---- attention for batch b = bid ----
            for (int i = tid; i < 1024; i += 256) hsm[i] = h_fp32[bid * 1024 + i];
            __syncthreads();
            for (int i = 0; i < 20; ++i) {
                int sx = w * 20 + i;
                float p = 0.f;
#pragma unroll
                for (int kq = 0; kq < 16; ++kq)
                    p = fmaf(hsm[lane + kq * 64], W1[(size_t)sx * 2048 + lane + kq * 64], p);
#pragma unroll
                for (int off = 32; off; off >>= 1) p += __shfl_down(p, off, 64);
                if (lane == 0) wsm[sx] = p + S_log[((size_t)t * 64 + bid) * 80 + sx];
            }
            __syncthreads();
            float v = (tid < 80) ? wsm[tid] : -3.4e38f;
            if (tid < 128) rbuf[tid] = v;
            __syncthreads();
            for (int off = 64; off >= 1; off >>= 1) {
                if (tid < off) rbuf[tid] = fmaxf(rbuf[tid], rbuf[tid + off]);
                __syncthreads();
            }
            float mx = rbuf[0];
            __syncthreads();
            float e = (tid < 80) ? __expf(wsm[tid] - mx) : 0.f;
            if (tid < 128) rbuf[tid] = e;
            __syncthreads();
            for (int off = 64; off >= 1; off >>= 1) {
                if (tid < off) rbuf[tid] += rbuf[tid + off];
                __syncthreads();
            }
            float inv = 1.f / rbuf[0];
            __syncthreads();
            if (tid < 80) wsm[tid] = e * inv;
            __syncthreads();
            {
                int j = tid * 4;
                float f0 = 0, f1 = 0, f2 = 0, f3 = 0;
                for (int ss = 0; ss < 80; ++ss) {
                    float wv = wsm[ss];
                    float4 ev = *(const float4*)&enc_seq[((size_t)ss * 64 + bid) * 1024 + j];
                    f0 = fmaf(wv, ev.x, f0); f1 = fmaf(wv, ev.y, f1);
                    f2 = fmaf(wv, ev.z, f2); f3 = fmaf(wv, ev.w, f3);
                }
                float fv[4] = {f0, f1, f2, f3};
#pragma unroll
                for (int e2 = 0; e2 < 4; ++e2) {
                    float x = fv[e2];
                    unsigned short hi = bf16_rn(x); float r1 = x - bf16_to_f(hi);
                    unsigned short md = bf16_rn(r1);
                    unsigned short lo = bf16_rn(r1 - bf16_to_f(md));
                    fpl[bid * 1024 + j + e2] = hi;
                    fpl[65536 + bid * 1024 + j + e2] = md;
                    fpl[131072 + bid * 1024 + j + e2] = lo;
                }
            }
            grid_barrier(bar, 64);

            // ---- ctx GEMM: out 64x16 (cols j0..j0+16), K=1024 over f-planes ----
            {
                f32x4 a1 = (f32x4){0.f, 0.f, 0.f, 0.f};
                for (int c = 0; c < 16; ++c) {
                    stage_planes(lbuf, fpl, c * 64, tid);
                    __syncthreads();
                    const int kb = c * 64;
#pragma unroll
                    for (int kk = 0; kk < 2; ++kk) {
                        short8v a[3], b[3];
#pragma unroll
                        for (int p = 0; p < 3; ++p)
                            a[p] = *(const short8v*)&lbuf[p][w * 16 + lr][kk * 32 + hk * 8];
#pragma unroll
                        for (int q = 0; q < 3; ++q)
                            b[q] = *(const short8v*)&W2fPl[((size_t)q * 1024 + j0 + lr) * 1024 + kb + kk * 32 + hk * 8];
                        MFMA_(a1, a[0], b[0]);
                        MFMA_(a1, a[0], b[1]);
                        MFMA_(a1, a[1], b[0]);
                        MFMA_(a1, a[1], b[1]);
                        MFMA_(a1, a[0], b[2]);
                        MFMA_(a1, a[2], b[0]);
                    }
                    __syncthreads();
                }
#pragma unroll
                for (int r = 0; r < 4; ++r) {
                    int row = w * 16 + hk * 4 + r, col = j0 + lr;
                    float x = a1[r] + ctxS[((size_t)t * 64 + row) * 1024 + col];
                    x = (x >= 0.f) ? x : pw * x;
                    x += enc_pad[((size_t)t * 64 + row) * 1024 + col];
                    unsigned short hi = bf16_rn(x); float r1 = x - bf16_to_f(hi);
                    unsigned short md = bf16_rn(r1);
                    unsigned short lo = bf16_rn(r1 - bf16_to_f(md));
                    ctxpl[row * 1024 + col] = hi;
                    ctxpl[65536 + row * 1024 + col] = md;
                    ctxpl[131072 + row * 1024 + col] = lo;
                }
            }
            grid_barrier(bar, 64);
        }

        // ---- main gate GEMM: K=1024 (warmup: h) or K=2048 (decode: ctx|h) ----
        {
            f32x4 acc[4];
#pragma unroll
            for (int g = 0; g < 4; ++g) acc[g] = (f32x4){0.f, 0.f, 0.f, 0.f};
            const int NC = (s < 80) ? 16 : 32;
            for (int c = 0; c < NC; ++c) {
                const unsigned short* src = (s < 80) ? hin : (c < 16 ? ctxpl : hin);
                const int kb = (s >= 80 && c >= 16) ? (c - 16) * 64 : c * 64;
                stage_planes(lbuf, src, kb, tid);
                __syncthreads();
                const unsigned short* Wb = (s < 80) ? WhhPl : (c < 16 ? WihcPl : WhhPl);
#pragma unroll
                for (int kk = 0; kk < 2; ++kk) {
                    short8v a[3], b[3][4];
#pragma unroll
                    for (int p = 0; p < 3; ++p)
                        a[p] = *(const short8v*)&lbuf[p][w * 16 + lr][kk * 32 + hk * 8];
#pragma unroll
                    for (int q = 0; q < 3; ++q)
#pragma unroll
                        for (int g = 0; g < 4; ++g)
                            b[q][g] = *(const short8v*)&Wb[((size_t)q * 4096 + g * 1024 + j0 + lr) * 1024 + kb + kk * 32 + hk * 8];
#pragma unroll
                    for (int g = 0; g < 4; ++g) {
                        MFMA_(acc[g], a[0], b[0][g]);
                        MFMA_(acc[g], a[0], b[1][g]);
                        MFMA_(acc[g], a[1], b[0][g]);
                        MFMA_(acc[g], a[1], b[1][g]);
                        MFMA_(acc[g], a[0], b[2][g]);
                        MFMA_(acc[g], a[2], b[0][g]);
                    }
                }
                __syncthreads();
            }
#pragma unroll
            for (int g = 0; g < 4; ++g)
#pragma unroll
                for (int r = 0; r < 4; ++r)
                    gbuf[g][w * 16 + hk * 4 + r][lr] = acc[g][r];
            __syncthreads();

            const float* xadd = (s < 80) ? (Xwarm + ((size_t)s * 64 + gm) * 4096)
                                         : (S_g + ((size_t)t * 64 + gm) * 4096);
            float ggx[4][4];
#pragma unroll
            for (int g = 0; g < 4; ++g) {
                float4 gv = *(const float4*)&gbuf[g][gm][gj];
                float4 xv = *(const float4*)&xadd[g * 1024 + j0 + gj];
                ggx[g][0] = gv.x + xv.x; ggx[g][1] = gv.y + xv.y;
                ggx[g][2] = gv.z + xv.z; ggx[g][3] = gv.w + xv.w;
            }
#pragma unroll
            for (int jj = 0; jj < 4; ++jj) {
                float cn = sigmf(ggx[1][jj]) * c4[jj] + sigmf(ggx[0][jj]) * tanhf(ggx[2][jj]);
                float hn = sigmf(ggx[3][jj]) * tanhf(cn);
                c4[jj] = cn;
                int col = j0 + gj + jj;
                h_fp32[gm * 1024 + col] = hn;
                if (s >= 80) h_all[((size_t)t * 64 + gm) * 1024 + col] = hn;
                unsigned short hi = bf16_rn(hn); float r1 = hn - bf16_to_f(hi);
                unsigned short md = bf16_rn(r1);
                unsigned short lo = bf16_rn(r1 - bf16_to_f(md));
                hout[gm * 1024 + col] = hi;
                hout[65536 + gm * 1024 + col] = md;
                hout[131072 + gm * 1024 + col] = lo;
            }
        }
        grid_barrier(bar, 64);
    }
}

// ---------------------------------------------------------------------------
extern "C" void kernel_launch(void* const* d_in, const int* in_sizes, int n_in,
                              void* d_out, int out_size, void* d_ws, size_t ws_size,
                              hipStream_t stream)
{
    (void)in_sizes; (void)n_in; (void)out_size; (void)ws_size;

    const float* input_data     = (const float*)d_in[0];
    const float* correct_answer = (const float*)d_in[1];
    const float* enc_W_ih = (const float*)d_in[2];
    const float* enc_W_hh = (const float*)d_in[3];
    const float* enc_b_ih = (const float*)d_in[4];
    const float* enc_b_hh = (const float*)d_in[5];
    const float* dec_W_ih = (const float*)d_in[6];
    const float* dec_W_hh = (const float*)d_in[7];
    const float* dec_b_ih = (const float*)d_in[8];
    const float* dec_b_hh = (const float*)d_in[9];
    const float* in_emb_W = (const float*)d_in[10];
    const float* in_emb_b = (const float*)d_in[11];
    const float* out_emb_W = (const float*)d_in[12];
    const float* out_emb_b = (const float*)d_in[13];
    const float* att_W1 = (const float*)d_in[14];
    const float* att_b1 = (const float*)d_in[15];
    const float* att_W2 = (const float*)d_in[16];
    const float* att_b2 = (const float*)d_in[17];
    const float* prelu_w = (const float*)d_in[18];

    float* out = (float*)d_out;
    char* ws = (char*)d_ws;

    // ---- d_out scratch map (102.4M floats; all reads precede final vocab GEMM) ----
    float* Xbig   = out;                       // [80][64][4096]
    float* S_g    = out + 20971520;            // [80][64][4096]
    float* ctxS   = out + 41943040;            // [80][64][1024]
    float* S_log  = out + 47185920;            // [80][64][80]
    float* samples= out + 47595520;            // [80][64][1024]
    unsigned short* encWhhPl = (unsigned short*)(out + 52838400);  // [3][4096][1024] bf16
    unsigned short* decWhhPl = (unsigned short*)(out + 59129856);
    unsigned short* decWihcPl= (unsigned short*)(out + 65421312);
    unsigned short* attW2fPl = (unsigned short*)(out + 71712768);  // [3][1024][1024]

    // ---- d_ws map ----
    size_t off = 0;
    auto alloc = [&](size_t nfloats) { float* p = (float*)(ws + off); off += nfloats * 4; return p; };
    float* enc_seq = alloc(80 * 64 * 1024);
    float* enc_pad = alloc(80 * 64 * 1024);
    float* h_all   = alloc(80 * 64 * 1024);
    float* benc    = alloc(4096);
    float* bdec    = alloc(4096);
    float* hplA_f  = alloc(196608);   // [2][3][64][1024] bf16
    float* hplB_f  = alloc(196608);
    float* fpl_f   = alloc(98304);    // [3][64][1024] bf16
    float* ctxpl_f = alloc(98304);
    float* h_fp32  = alloc(65536);
    float* bar_f   = alloc(8);        // 2 barrier states (2 uints each)
    unsigned short* hplA  = (unsigned short*)hplA_f;
    unsigned short* hplB  = (unsigned short*)hplB_f;
    unsigned short* fpl   = (unsigned short*)fpl_f;
    unsigned short* ctxpl = (unsigned short*)ctxpl_f;
    unsigned* bar0 = (unsigned*)bar_f;      // enc barrier
    unsigned* bar1 = ((unsigned*)bar_f) + 4; // dec barrier

    auto big3 = [&](const float* A, int lda, const float* W, int ldw,
                    float* C, int ldc, const float* bias, int M, int N, int K) {
        dim3 g((N + 127) / 128, (M + 127) / 128);
        hipLaunchKernelGGL((gemm_mfma_split<3>), g, dim3(256), 0, stream,
                           A, lda, W, ldw, C, ldc, bias, M, N, K);
    };

    // ---- setup ----
    hipLaunchKernelGGL(vec_add2, dim3(16), dim3(256), 0, stream, enc_b_ih, enc_b_hh, benc, 4096);
    hipLaunchKernelGGL(vec_add2, dim3(16), dim3(256), 0, stream, dec_b_ih, dec_b_hh, bdec, 4096);
    hipLaunchKernelGGL(zero_f, dim3(768), dim3(256), 0, stream, hplA_f, 196608);
    hipLaunchKernelGGL(zero_f, dim3(768), dim3(256), 0, stream, hplB_f, 196608);
    hipLaunchKernelGGL(zero_f, dim3(256), dim3(256), 0, stream, h_fp32, 65536);
    hipLaunchKernelGGL(zero_f, dim3(1), dim3(256), 0, stream, bar_f, 8);

    // ---- weight plane splits ----
    hipLaunchKernelGGL(split3, dim3(16384), dim3(256), 0, stream, enc_W_hh, 1024, 0, encWhhPl, 4096, 1024);
    hipLaunchKernelGGL(split3, dim3(16384), dim3(256), 0, stream, dec_W_hh, 1024, 0, decWhhPl, 4096, 1024);
    hipLaunchKernelGGL(split3, dim3(16384), dim3(256), 0, stream, dec_W_ih, 2048, 1024, decWihcPl, 4096, 1024);
    hipLaunchKernelGGL(split3, dim3(4096),  dim3(256), 0, stream, att_W2,  2048, 1024, attW2fPl, 1024, 1024);

    // ---- big batched GEMMs (all NS=3; feed recurrences) ----
    big3(input_data, 4096, enc_W_ih, 4096, Xbig, 4096, benc, 5120, 4096, 4096);
    hipLaunchKernelGGL(sample0_fill, dim3(256), dim3(256), 0, stream, in_emb_W, in_emb_b, samples);
    big3(correct_answer + (size_t)64 * 20000, 20000, in_emb_W, 20000,
         samples + 65536, 1024, in_emb_b, 5056, 1024, 20000);
    big3(samples, 1024, dec_W_ih, 2048, S_g, 4096, bdec, 5120, 4096, 1024);
    big3(samples, 1024, att_W2, 2048, ctxS, 1024, att_b2, 5120, 1024, 1024);
    big3(samples, 1024, att_W1 + 1024, 2048, S_log, 80, att_b1, 5120, 80, 1024);

    // ---- persistent encoder (160 steps, software grid barrier) ----
    hipLaunchKernelGGL(coop_enc, dim3(64), dim3(256), 0, stream,
                       encWhhPl, Xbig, benc, hplA, enc_seq, enc_pad, bar0);

    // ---- decoder warm-up input projection (reuses Xbig region) ----
    big3(enc_seq, 1024, dec_W_ih, 2048, Xbig, 4096, bdec, 5120, 4096, 1024);

    // ---- persistent decoder (80 warm-up + 80 decode steps) ----
    hipLaunchKernelGGL(coop_dec, dim3(64), dim3(256), 0, stream,
                       decWhhPl, decWihcPl, attW2fPl,
                       Xbig, S_g, ctxS, S_log,
                       att_W1, enc_seq, enc_pad, prelu_w,
                       hplB, fpl, ctxpl, h_fp32, h_all, bar1);

    // ---- final vocab projection (NS=1, output-facing) ----
    {
        dim3 g((20000 + 127) / 128, (5120 + 127) / 128);
        hipLaunchKernelGGL((gemm_mfma_split<1>), g, dim3(256), 0, stream,
                           h_all, 1024, out_emb_W, 1024, out, 20000, out_emb_b, 5120, 20000, 1024);
    }
}

// Round 6
// 50866.577 us; speedup vs baseline: 1.0325x; 1.0325x over previous
//
#include <hip/hip_runtime.h>
#include <cstddef>
#include <cstdint>

typedef __attribute__((ext_vector_type(8))) short short8v;
typedef __attribute__((ext_vector_type(4))) float f32x4;

__device__ __forceinline__ float sigmf(float x) { return 1.0f / (1.0f + __expf(-x)); }

__device__ __forceinline__ unsigned short bf16_rn(float x) {
    union { float f; unsigned u; } v; v.f = x;
    unsigned r = v.u + 0x7FFF + ((v.u >> 16) & 1);
    return (unsigned short)(r >> 16);
}
__device__ __forceinline__ float bf16_to_f(unsigned short h) {
    union { unsigned u; float f; } v; v.u = ((unsigned)h) << 16; return v.f;
}
__device__ __forceinline__ unsigned long long pack4(unsigned short a, unsigned short b,
                                                    unsigned short c, unsigned short d) {
    return (unsigned long long)a | ((unsigned long long)b << 16)
         | ((unsigned long long)c << 32) | ((unsigned long long)d << 48);
}

#define MFMA_(d, va, vb) d = __builtin_amdgcn_mfma_f32_16x16x32_bf16(va, vb, d, 0, 0, 0)

// ---------------------------------------------------------------------------
// Fragment layout: F[p][rgw][kf][l][e], short; rgw=r>>4, kf=k>>5,
// l=((k>>3)&3)*16+(r&15), e=k&7.  Per-(p,rgw) chunk = 32*64*8 = 16384 shorts.
// A wave's frag read = 16B at lane*16 offset -> fully coalesced 1KB.
// ---------------------------------------------------------------------------
__device__ __forceinline__ void write_frag3(unsigned short* __restrict__ dst, int NRGW,
                                            int r, int k, float x)
{
    unsigned short hi = bf16_rn(x); float r1 = x - bf16_to_f(hi);
    unsigned short md = bf16_rn(r1);
    unsigned short lo = bf16_rn(r1 - bf16_to_f(md));
    int base = (((r >> 4) * 32 + (k >> 5)) * 64 + ((k >> 3) & 3) * 16 + (r & 15)) * 8 + (k & 7);
    int ps = NRGW * 16384;
    dst[base] = hi; dst[ps + base] = md; dst[2 * ps + base] = lo;
}

// rearrange fp32 [R][ld] (col offset c0, K cols) -> 3-plane frag bf16
__launch_bounds__(256)
__global__ void rearr_frag(const float* __restrict__ src, int ld, int c0,
                           unsigned short* __restrict__ dst, int R, int K)
{
    int idx = blockIdx.x * 256 + threadIdx.x;
    int kpr = K >> 3;
    if (idx >= R * kpr) return;
    int r = idx / kpr, k = (idx % kpr) * 8;
    int NRGW = R >> 4;
    const float* s = src + (size_t)r * ld + c0 + k;
    float4 v0 = *(const float4*)s, v1 = *(const float4*)(s + 4);
    float xs[8] = {v0.x, v0.y, v0.z, v0.w, v1.x, v1.y, v1.z, v1.w};
    unsigned short hi[8], md[8], lo[8];
#pragma unroll
    for (int e = 0; e < 8; ++e) {
        hi[e] = bf16_rn(xs[e]); float r1 = xs[e] - bf16_to_f(hi[e]);
        md[e] = bf16_rn(r1);
        lo[e] = bf16_rn(r1 - bf16_to_f(md[e]));
    }
    int base = (((r >> 4) * 32 + (k >> 5)) * 64 + ((k >> 3) & 3) * 16 + (r & 15)) * 8;
    size_t ps = (size_t)NRGW * 16384;
    *(unsigned long long*)&dst[base]          = pack4(hi[0], hi[1], hi[2], hi[3]);
    *(unsigned long long*)&dst[base + 4]      = pack4(hi[4], hi[5], hi[6], hi[7]);
    *(unsigned long long*)&dst[ps + base]     = pack4(md[0], md[1], md[2], md[3]);
    *(unsigned long long*)&dst[ps + base + 4] = pack4(md[4], md[5], md[6], md[7]);
    *(unsigned long long*)&dst[2*ps + base]     = pack4(lo[0], lo[1], lo[2], lo[3]);
    *(unsigned long long*)&dst[2*ps + base + 4] = pack4(lo[4], lo[5], lo[6], lo[7]);
}

// ---------------------------------------------------------------------------
// Software grid barrier (R5-proven). Requires all blocks co-resident.
// ---------------------------------------------------------------------------
__device__ __forceinline__ void grid_barrier(unsigned* bar, int nblk)
{
    __syncthreads();
    if (threadIdx.x == 0) {
        __threadfence();
        unsigned my_gen = __hip_atomic_load(&bar[1], __ATOMIC_RELAXED, __HIP_MEMORY_SCOPE_AGENT);
        unsigned prev = __hip_atomic_fetch_add(&bar[0], 1u, __ATOMIC_ACQ_REL, __HIP_MEMORY_SCOPE_AGENT);
        if (prev == (unsigned)(nblk - 1)) {
            __hip_atomic_store(&bar[0], 0u, __ATOMIC_RELAXED, __HIP_MEMORY_SCOPE_AGENT);
            __hip_atomic_fetch_add(&bar[1], 1u, __ATOMIC_RELEASE, __HIP_MEMORY_SCOPE_AGENT);
        } else {
            unsigned g;
            do { g = __hip_atomic_load(&bar[1], __ATOMIC_ACQUIRE, __HIP_MEMORY_SCOPE_AGENT); }
            while (g == my_gen);
        }
        __threadfence();
    }
    __syncthreads();
}

// ---------------------------------------------------------------------------
// Batched fp32 GEMM via bf16-split MFMA (validated R3): C = A@W^T + bias.
// ---------------------------------------------------------------------------
template <int NS>
__launch_bounds__(256, 2)
__global__ void gemm_mfma_split(const float* __restrict__ A, int lda,
                                const float* __restrict__ W, int ldw,
                                float* __restrict__ C, int ldc,
                                const float* __restrict__ bias,
                                int M, int N, int K)
{
    __shared__ unsigned short Abf[NS][128][40];
    __shared__ unsigned short Bbf[NS][128][40];
    const int tid = threadIdx.x;
    const int m0 = blockIdx.y * 128, n0 = blockIdx.x * 128;
    const int wave = tid >> 6, lane = tid & 63;
    const int wr = wave >> 1, wc = wave & 1;
    const int lr = lane & 15, lk = (lane >> 4) * 8;

    f32x4 acc[4][4];
#pragma unroll
    for (int i = 0; i < 4; ++i)
#pragma unroll
        for (int j = 0; j < 4; ++j) acc[i][j] = (f32x4){0.f, 0.f, 0.f, 0.f};

    const int arow = tid >> 1;
    const int akh  = (tid & 1) * 16;
    int gr = m0 + arow; if (gr > M - 1) gr = M - 1;
    int gn = n0 + arow; if (gn > N - 1) gn = N - 1;
    const float* aptr = A + (size_t)gr * lda + akh;
    const float* wptr = W + (size_t)gn * ldw + akh;

    for (int k0 = 0; k0 < K; k0 += 32) {
#pragma unroll
        for (int q = 0; q < 4; ++q) {
            float4 v = *(const float4*)(aptr + k0 + q * 4);
            float xs[4] = {v.x, v.y, v.z, v.w};
            unsigned short h[4], hm[4], hl[4];
#pragma unroll
            for (int e = 0; e < 4; ++e) {
                h[e] = bf16_rn(xs[e]);
                if (NS == 3) {
                    float r1 = xs[e] - bf16_to_f(h[e]);
                    hm[e] = bf16_rn(r1);
                    hl[e] = bf16_rn(r1 - bf16_to_f(hm[e]));
                }
            }
            *(unsigned long long*)&Abf[0][arow][akh + q * 4] = pack4(h[0], h[1], h[2], h[3]);
            if (NS == 3) {
                *(unsigned long long*)&Abf[1][arow][akh + q * 4] = pack4(hm[0], hm[1], hm[2], hm[3]);
                *(unsigned long long*)&Abf[2][arow][akh + q * 4] = pack4(hl[0], hl[1], hl[2], hl[3]);
            }
        }
#pragma unroll
        for (int q = 0; q < 4; ++q) {
            float4 v = *(const float4*)(wptr + k0 + q * 4);
            float xs[4] = {v.x, v.y, v.z, v.w};
            unsigned short h[4], hm[4], hl[4];
#pragma unroll
            for (int e = 0; e < 4; ++e) {
                h[e] = bf16_rn(xs[e]);
                if (NS == 3) {
                    float r1 = xs[e] - bf16_to_f(h[e]);
                    hm[e] = bf16_rn(r1);
                    hl[e] = bf16_rn(r1 - bf16_to_f(hm[e]));
                }
            }
            *(unsigned long long*)&Bbf[0][arow][akh + q * 4] = pack4(h[0], h[1], h[2], h[3]);
            if (NS == 3) {
                *(unsigned long long*)&Bbf[1][arow][akh + q * 4] = pack4(hm[0], hm[1], hm[2], hm[3]);
                *(unsigned long long*)&Bbf[2][arow][akh + q * 4] = pack4(hl[0], hl[1], hl[2], hl[3]);
            }
        }
        __syncthreads();

        short8v a[NS][4], b[4];
#pragma unroll
        for (int p = 0; p < NS; ++p)
#pragma unroll
            for (int i = 0; i < 4; ++i)
                a[p][i] = *(const short8v*)&Abf[p][wr * 64 + i * 16 + lr][lk];
#pragma unroll
        for (int q = 0; q < NS; ++q) {
#pragma unroll
            for (int j = 0; j < 4; ++j)
                b[j] = *(const short8v*)&Bbf[q][wc * 64 + j * 16 + lr][lk];
            const int pmax = (NS == 1) ? 1 : (3 - q);
#pragma unroll
            for (int p = 0; p < 3; ++p) {
                if (p >= pmax) break;
#pragma unroll
                for (int i = 0; i < 4; ++i)
#pragma unroll
                    for (int j = 0; j < 4; ++j)
                        acc[i][j] = __builtin_amdgcn_mfma_f32_16x16x32_bf16(
                            a[p][i], b[j], acc[i][j], 0, 0, 0);
            }
        }
        __syncthreads();
    }

    const int crow = (lane >> 4) * 4;
#pragma unroll
    for (int i = 0; i < 4; ++i) {
        int mbase = m0 + wr * 64 + i * 16 + crow;
#pragma unroll
        for (int j = 0; j < 4; ++j) {
            int n = n0 + wc * 64 + j * 16 + lr;
            if (n < N) {
                float bv = bias[n];
#pragma unroll
                for (int r = 0; r < 4; ++r) {
                    int m = mbase + r;
                    if (m < M) C[(size_t)m * ldc + n] = acc[i][j][r] + bv;
                }
            }
        }
    }
}

__launch_bounds__(256)
__global__ void zero_f(float* __restrict__ p, int n)
{
    int i = blockIdx.x * 256 + threadIdx.x;
    if (i < n) p[i] = 0.f;
}

__launch_bounds__(256)
__global__ void vec_add2(const float* __restrict__ a, const float* __restrict__ b,
                         float* __restrict__ o, int n)
{
    int i = blockIdx.x * 256 + threadIdx.x;
    if (i < n) o[i] = a[i] + b[i];
}

__launch_bounds__(256)
__global__ void sample0_fill(const float* __restrict__ emW, const float* __restrict__ emb,
                             float* __restrict__ samples)
{
    int idx = blockIdx.x * 256 + threadIdx.x; // 65536
    int d = idx & 1023;
    samples[idx] = emW[(size_t)d * 20000 + 19998] + emb[d];
}

// stage one rg-chunk (96KB: 3 planes x 16384 shorts) of a 64-row frag buffer
__device__ __forceinline__ void stage_A(unsigned short* __restrict__ LDSA,
                                        const unsigned short* __restrict__ src,
                                        int rg, int tid)
{
#pragma unroll
    for (int p = 0; p < 3; ++p) {
        const unsigned short* sp = src + (size_t)(p * 4 + rg) * 16384;
        unsigned short* dp = LDSA + p * 16384;
#pragma unroll
        for (int it = 0; it < 4; ++it) {
            int idx = tid + it * 512;
            *(short8v*)&dp[idx * 8] = *(const short8v*)&sp[idx * 8];
        }
    }
}

// 16-kf half-GEMM: acc0/acc1 accumulate 6 split-pairs per kf.
__device__ __forceinline__ void gemm_half(f32x4& acc0, f32x4& acc1,
                                          const unsigned short* __restrict__ LDSA,
                                          const unsigned short* __restrict__ Wf,
                                          int wbase, int NRGW_W, int kh, int lane)
{
#pragma unroll
    for (int i = 0; i < 16; ++i) {
        int kf = kh * 16 + i;
        short8v a0 = *(const short8v*)&LDSA[(kf * 64 + lane) * 8];
        short8v a1 = *(const short8v*)&LDSA[16384 + (kf * 64 + lane) * 8];
        short8v a2 = *(const short8v*)&LDSA[32768 + (kf * 64 + lane) * 8];
        const unsigned short* wb = Wf + ((size_t)wbase * 32 + kf) * 512 + lane * 8;
        size_t wps = (size_t)NRGW_W * 16384;
        short8v b0 = *(const short8v*)&wb[0];
        short8v b1 = *(const short8v*)&wb[wps];
        short8v b2 = *(const short8v*)&wb[2 * wps];
        f32x4& A = (i & 1) ? acc1 : acc0;
        MFMA_(A, a0, b0); MFMA_(A, a0, b1); MFMA_(A, a1, b0);
        MFMA_(A, a1, b1); MFMA_(A, a0, b2); MFMA_(A, a2, b0);
    }
}

// ---------------------------------------------------------------------------
// Persistent encoder: 160 steps, 256 blocks x 512 threads.
// block: rg=bid>>6 (16 rows), cg=bid&63 (16 cols/gate); wave w: gate=w&3, kh=w>>2.
// ---------------------------------------------------------------------------
__launch_bounds__(512, 1)
__global__ void coop_enc(const unsigned short* __restrict__ WencF,  // frag [3][256][...]
                         const float* __restrict__ Xbig,            // [80][64][4096]
                         const float* __restrict__ benc,            // [4096]
                         unsigned short* __restrict__ hfrag,        // 2 bufs x 196608
                         float* __restrict__ enc_seq,
                         float* __restrict__ enc_pad,
                         unsigned* __restrict__ bar)
{
    __shared__ unsigned short LDSA[3 * 16384];
    __shared__ float gbuf[8][16][16];
    const int bid = blockIdx.x, tid = threadIdx.x;
    const int w = tid >> 6, lane = tid & 63;
    const int g = w & 3, kh = w >> 2;
    const int rg = bid >> 6, cg = bid & 63;
    const int wbase = g * 64 + cg;
    const int r_l = (tid & 255) >> 4, c_l = tid & 15;
    const int row = rg * 16 + r_l, col = cg * 16 + c_l;
    float cstate = 0.f;

    for (int s = 0; s < 160; ++s) {
        const unsigned short* hf = hfrag + (s & 1) * 196608;
        stage_A(LDSA, hf, rg, tid);
        __syncthreads();

        f32x4 acc0 = (f32x4){0.f,0.f,0.f,0.f}, acc1 = acc0;
        gemm_half(acc0, acc1, LDSA, WencF, wbase, 256, kh, lane);
        acc0 += acc1;
#pragma unroll
        for (int r = 0; r < 4; ++r)
            gbuf[w][(lane >> 4) * 4 + r][lane & 15] = acc0[r];
        __syncthreads();

        if (tid < 256) {
            const float* xb = (s < 80) ? (Xbig + ((size_t)s * 64 + row) * 4096) : benc;
            float gv[4];
#pragma unroll
            for (int g2 = 0; g2 < 4; ++g2) {
                float x = (s < 80) ? xb[g2 * 1024 + col] : benc[g2 * 1024 + col];
                gv[g2] = gbuf[g2][r_l][c_l] + gbuf[4 + g2][r_l][c_l] + x;
            }
            float cn = sigmf(gv[1]) * cstate + sigmf(gv[0]) * tanhf(gv[2]);
            float hn = sigmf(gv[3]) * tanhf(cn);
            cstate = cn;
            float* st = (s < 80) ? (enc_seq + (size_t)s * 65536)
                                 : (enc_pad + (size_t)(s - 80) * 65536);
            st[row * 1024 + col] = hn;
            write_frag3(hfrag + ((s + 1) & 1) * 196608, 4, row, col, hn);
        }
        grid_barrier(bar, 256);
    }
}

// ---------------------------------------------------------------------------
// Persistent decoder: 80 warm-up + 80 attention-decode steps.
// ---------------------------------------------------------------------------
__launch_bounds__(512, 1)
__global__ void coop_dec(const unsigned short* __restrict__ WhhF,   // frag [3][256]
                         const unsigned short* __restrict__ WihcF,  // frag [3][256]
                         const unsigned short* __restrict__ W2fF,   // frag [3][64]
                         const float* __restrict__ Xwarm,           // [80][64][4096]
                         const float* __restrict__ S_g,             // [80][64][4096]
                         const float* __restrict__ ctxS,            // [80][64][1024]
                         const float* __restrict__ S_log,           // [80][64][80]
                         const float* __restrict__ W1,              // [80][2048]
                         const float* __restrict__ enc_seq,         // [80][64][1024]
                         const float* __restrict__ enc_pad,         // [80][64][1024]
                         const float* __restrict__ prelu_w,
                         unsigned short* __restrict__ hfrag,        // 2 bufs
                         unsigned short* __restrict__ ffrag,        // 196608
                         unsigned short* __restrict__ ctxfrag,      // 196608
                         float* __restrict__ h_fp32,                // [64][1024]
                         float* __restrict__ h_all,                 // [80][64][1024]
                         unsigned* __restrict__ bar)
{
    __shared__ unsigned short LDSA[3 * 16384];
    __shared__ float gbuf[8][16][16];
    __shared__ float hsm[1024];
    __shared__ float wsm[80];
    __shared__ float rbuf[128];
    const int bid = blockIdx.x, tid = threadIdx.x;
    const int w = tid >> 6, lane = tid & 63;
    const int g = w & 3, kh = w >> 2;
    const int rg = bid >> 6, cg = bid & 63;
    const int wbase = g * 64 + cg;
    const int r_l = (tid & 255) >> 4, c_l = tid & 15;
    const int row = rg * 16 + r_l, col = cg * 16 + c_l;
    float cstate = 0.f;
    const float pw = prelu_w[0];

    for (int s = 0; s < 160; ++s) {
        const unsigned short* hf = hfrag + (s & 1) * 196608;
        const int t = s - 80;

        if (s >= 80) {
            // ---- Phase A: attention (blocks 0..63, batch=bid) ----
            if (bid < 64) {
                for (int i = tid; i < 1024; i += 512) hsm[i] = h_fp32[bid * 1024 + i];
                __syncthreads();
#pragma unroll
                for (int i = 0; i < 10; ++i) {
                    int sx = w * 10 + i;
                    float p = 0.f;
#pragma unroll
                    for (int q = 0; q < 16; ++q)
                        p = fmaf(hsm[lane + q * 64], W1[(size_t)sx * 2048 + lane + q * 64], p);
#pragma unroll
                    for (int off = 32; off; off >>= 1) p += __shfl_down(p, off, 64);
                    if (lane == 0) wsm[sx] = p + S_log[((size_t)t * 64 + bid) * 80 + sx];
                }
                __syncthreads();
                float v = (tid < 80) ? wsm[tid] : -3.4e38f;
                if (tid < 128) rbuf[tid] = v;
                __syncthreads();
                for (int off = 64; off >= 1; off >>= 1) {
                    if (tid < off) rbuf[tid] = fmaxf(rbuf[tid], rbuf[tid + off]);
                    __syncthreads();
                }
                float mx = rbuf[0];
                __syncthreads();
                float e = (tid < 80) ? __expf(wsm[tid] - mx) : 0.f;
                if (tid < 128) rbuf[tid] = e;
                __syncthreads();
                for (int off = 64; off >= 1; off >>= 1) {
                    if (tid < off) rbuf[tid] += rbuf[tid + off];
                    __syncthreads();
                }
                float inv = 1.f / rbuf[0];
                __syncthreads();
                if (tid < 80) wsm[tid] = e * inv;
                __syncthreads();
                {
                    int j = tid * 2;
                    float f0 = 0.f, f1 = 0.f;
                    for (int ss = 0; ss < 80; ++ss) {
                        float wv = wsm[ss];
                        float2 ev = *(const float2*)&enc_seq[((size_t)ss * 64 + bid) * 1024 + j];
                        f0 = fmaf(wv, ev.x, f0); f1 = fmaf(wv, ev.y, f1);
                    }
                    write_frag3(ffrag, 4, bid, j, f0);
                    write_frag3(ffrag, 4, bid, j + 1, f1);
                }
            }
            grid_barrier(bar, 256);

            // ---- Phase B: ctx GEMM (rows rg*16, cols cg*16, K=1024) ----
            stage_A(LDSA, ffrag, rg, tid);
            __syncthreads();
            {
                f32x4 acc = (f32x4){0.f,0.f,0.f,0.f};
#pragma unroll
                for (int i = 0; i < 4; ++i) {
                    int kf = w * 4 + i;
                    short8v a0 = *(const short8v*)&LDSA[(kf * 64 + lane) * 8];
                    short8v a1 = *(const short8v*)&LDSA[16384 + (kf * 64 + lane) * 8];
                    short8v a2 = *(const short8v*)&LDSA[32768 + (kf * 64 + lane) * 8];
                    const unsigned short* wb = W2fF + ((size_t)cg * 32 + kf) * 512 + lane * 8;
                    size_t wps = (size_t)64 * 16384;
                    short8v b0 = *(const short8v*)&wb[0];
                    short8v b1 = *(const short8v*)&wb[wps];
                    short8v b2 = *(const short8v*)&wb[2 * wps];
                    MFMA_(acc, a0, b0); MFMA_(acc, a0, b1); MFMA_(acc, a1, b0);
                    MFMA_(acc, a1, b1); MFMA_(acc, a0, b2); MFMA_(acc, a2, b0);
                }
#pragma unroll
                for (int r = 0; r < 4; ++r)
                    gbuf[w][(lane >> 4) * 4 + r][lane & 15] = acc[r];
            }
            __syncthreads();
            if (tid < 256) {
                float val = 0.f;
#pragma unroll
                for (int w2 = 0; w2 < 8; ++w2) val += gbuf[w2][r_l][c_l];
                val += ctxS[((size_t)t * 64 + row) * 1024 + col];
                val = (val >= 0.f) ? val : pw * val;
                val += enc_pad[((size_t)t * 64 + row) * 1024 + col];
                write_frag3(ctxfrag, 4, row, col, val);
            }
            grid_barrier(bar, 256);
        }

        // ---- Phase C: gate GEMM (+ ctx half when decoding) + gates ----
        f32x4 acc0 = (f32x4){0.f,0.f,0.f,0.f}, acc1 = acc0;
        if (s >= 80) {
            stage_A(LDSA, ctxfrag, rg, tid);
            __syncthreads();
            gemm_half(acc0, acc1, LDSA, WihcF, wbase, 256, kh, lane);
            __syncthreads();   // all waves done with LDSA before restage
        }
        stage_A(LDSA, hf, rg, tid);
        __syncthreads();
        gemm_half(acc0, acc1, LDSA, WhhF, wbase, 256, kh, lane);
        acc0 += acc1;
#pragma unroll
        for (int r = 0; r < 4; ++r)
            gbuf[w][(lane >> 4) * 4 + r][lane & 15] = acc0[r];
        __syncthreads();

        if (tid < 256) {
            const float* xb = (s < 80) ? (Xwarm + ((size_t)s * 64 + row) * 4096)
                                       : (S_g + ((size_t)t * 64 + row) * 4096);
            float gv[4];
#pragma unroll
            for (int g2 = 0; g2 < 4; ++g2)
                gv[g2] = gbuf[g2][r_l][c_l] + gbuf[4 + g2][r_l][c_l] + xb[g2 * 1024 + col];
            float cn = sigmf(gv[1]) * cstate + sigmf(gv[0]) * tanhf(gv[2]);
            float hn = sigmf(gv[3]) * tanhf(cn);
            cstate = cn;
            h_fp32[row * 1024 + col] = hn;
            if (s >= 80) h_all[((size_t)t * 64 + row) * 1024 + col] = hn;
            write_frag3(hfrag + ((s + 1) & 1) * 196608, 4, row, col, hn);
        }
        grid_barrier(bar, 256);
    }
}

// ---------------------------------------------------------------------------
extern "C" void kernel_launch(void* const* d_in, const int* in_sizes, int n_in,
                              void* d_out, int out_size, void* d_ws, size_t ws_size,
                              hipStream_t stream)
{
    (void)in_sizes; (void)n_in; (void)out_size; (void)ws_size;

    const float* input_data     = (const float*)d_in[0];
    const float* correct_answer = (const float*)d_in[1];
    const float* enc_W_ih = (const float*)d_in[2];
    const float* enc_W_hh = (const float*)d_in[3];
    const float* enc_b_ih = (const float*)d_in[4];
    const float* enc_b_hh = (const float*)d_in[5];
    const float* dec_W_ih = (const float*)d_in[6];
    const float* dec_W_hh = (const float*)d_in[7];
    const float* dec_b_ih = (const float*)d_in[8];
    const float* dec_b_hh = (const float*)d_in[9];
    const float* in_emb_W = (const float*)d_in[10];
    const float* in_emb_b = (const float*)d_in[11];
    const float* out_emb_W = (const float*)d_in[12];
    const float* out_emb_b = (const float*)d_in[13];
    const float* att_W1 = (const float*)d_in[14];
    const float* att_b1 = (const float*)d_in[15];
    const float* att_W2 = (const float*)d_in[16];
    const float* att_b2 = (const float*)d_in[17];
    const float* prelu_w = (const float*)d_in[18];

    float* out = (float*)d_out;
    char* ws = (char*)d_ws;

    // ---- d_out scratch (102.4M floats; all reads precede final vocab GEMM) ----
    float* Xbig    = out;                      // [80][64][4096]   20.97M
    float* S_g     = out + 20971520;           // [80][64][4096]   20.97M
    float* ctxS    = out + 41943040;           // [80][64][1024]    5.24M
    float* S_log   = out + 47185920;           // [80][64][80]      0.41M
    float* samples = out + 47595520;           // [80][64][1024]    5.24M
    unsigned short* WencF = (unsigned short*)(out + 52838400);  // 12.58M shorts
    unsigned short* WhhDF = (unsigned short*)(out + 59129856);
    unsigned short* WihcF = (unsigned short*)(out + 65421312);
    unsigned short* W2fF  = (unsigned short*)(out + 71712768);  //  3.15M shorts

    // ---- d_ws map ----
    size_t off = 0;
    auto alloc = [&](size_t nfloats) { float* p = (float*)(ws + off); off += nfloats * 4; return p; };
    float* enc_seq = alloc(80 * 64 * 1024);
    float* enc_pad = alloc(80 * 64 * 1024);
    float* h_all   = alloc(80 * 64 * 1024);
    float* benc    = alloc(4096);
    float* bdec    = alloc(4096);
    float* hfragE_f = alloc(196608);   // 2 bufs x 196608 shorts
    float* hfragD_f = alloc(196608);
    float* ffrag_f  = alloc(98304);    // 196608 shorts
    float* ctxfrag_f= alloc(98304);
    float* h_fp32   = alloc(65536);
    float* bar_f    = alloc(8);
    unsigned short* hfragE  = (unsigned short*)hfragE_f;
    unsigned short* hfragD  = (unsigned short*)hfragD_f;
    unsigned short* ffrag   = (unsigned short*)ffrag_f;
    unsigned short* ctxfrag = (unsigned short*)ctxfrag_f;
    unsigned* bar0 = (unsigned*)bar_f;
    unsigned* bar1 = ((unsigned*)bar_f) + 4;

    auto big3 = [&](const float* A, int lda, const float* W, int ldw,
                    float* C, int ldc, const float* bias, int M, int N, int K) {
        dim3 g((N + 127) / 128, (M + 127) / 128);
        hipLaunchKernelGGL((gemm_mfma_split<3>), g, dim3(256), 0, stream,
                           A, lda, W, ldw, C, ldc, bias, M, N, K);
    };

    // ---- setup ----
    hipLaunchKernelGGL(vec_add2, dim3(16), dim3(256), 0, stream, enc_b_ih, enc_b_hh, benc, 4096);
    hipLaunchKernelGGL(vec_add2, dim3(16), dim3(256), 0, stream, dec_b_ih, dec_b_hh, bdec, 4096);
    hipLaunchKernelGGL(zero_f, dim3(768), dim3(256), 0, stream, hfragE_f, 196608);
    hipLaunchKernelGGL(zero_f, dim3(768), dim3(256), 0, stream, hfragD_f, 196608);
    hipLaunchKernelGGL(zero_f, dim3(256), dim3(256), 0, stream, h_fp32, 65536);
    hipLaunchKernelGGL(zero_f, dim3(1), dim3(256), 0, stream, bar_f, 8);

    // ---- weight frag rearranges (one-time) ----
    hipLaunchKernelGGL(rearr_frag, dim3(2048), dim3(256), 0, stream, enc_W_hh, 1024, 0, WencF, 4096, 1024);
    hipLaunchKernelGGL(rearr_frag, dim3(2048), dim3(256), 0, stream, dec_W_hh, 1024, 0, WhhDF, 4096, 1024);
    hipLaunchKernelGGL(rearr_frag, dim3(2048), dim3(256), 0, stream, dec_W_ih, 2048, 1024, WihcF, 4096, 1024);
    hipLaunchKernelGGL(rearr_frag, dim3(512),  dim3(256), 0, stream, att_W2,  2048, 1024, W2fF, 1024, 1024);

    // ---- batched big GEMMs (NS=3, feed recurrences) ----
    big3(input_data, 4096, enc_W_ih, 4096, Xbig, 4096, benc, 5120, 4096, 4096);
    hipLaunchKernelGGL(sample0_fill, dim3(256), dim3(256), 0, stream, in_emb_W, in_emb_b, samples);
    big3(correct_answer + (size_t)64 * 20000, 20000, in_emb_W, 20000,
         samples + 65536, 1024, in_emb_b, 5056, 1024, 20000);
    big3(samples, 1024, dec_W_ih, 2048, S_g, 4096, bdec, 5120, 4096, 1024);
    big3(samples, 1024, att_W2, 2048, ctxS, 1024, att_b2, 5120, 1024, 1024);
    big3(samples, 1024, att_W1 + 1024, 2048, S_log, 80, att_b1, 5120, 80, 1024);

    // ---- persistent encoder (160 steps) ----
    hipLaunchKernelGGL(coop_enc, dim3(256), dim3(512), 0, stream,
                       WencF, Xbig, benc, hfragE, enc_seq, enc_pad, bar0);

    // ---- decoder warm-up input projection (reuses Xbig region) ----
    big3(enc_seq, 1024, dec_W_ih, 2048, Xbig, 4096, bdec, 5120, 4096, 1024);

    // ---- persistent decoder (80 warm-up + 80 decode) ----
    hipLaunchKernelGGL(coop_dec, dim3(256), dim3(512), 0, stream,
                       WhhDF, WihcF, W2fF, Xbig, S_g, ctxS, S_log,
                       att_W1, enc_seq, enc_pad, prelu_w,
                       hfragD, ffrag, ctxfrag, h_fp32, h_all, bar1);

    // ---- final vocab projection (NS=1, output-facing) ----
    {
        dim3 g((20000 + 127) / 128, (5120 + 127) / 128);
        hipLaunchKernelGGL((gemm_mfma_split<1>), g, dim3(256), 0, stream,
                           h_all, 1024, out_emb_W, 1024, out, 20000, out_emb_b, 5120, 20000, 1024);
    }
}

// Round 7
// 50250.122 us; speedup vs baseline: 1.0452x; 1.0123x over previous
//
#include <hip/hip_runtime.h>
#include <cstddef>
#include <cstdint>

typedef __attribute__((ext_vector_type(8))) short short8v;
typedef __attribute__((ext_vector_type(4))) float f32x4;

__device__ __forceinline__ float sigmf(float x) { return 1.0f / (1.0f + __expf(-x)); }

__device__ __forceinline__ unsigned short bf16_rn(float x) {
    union { float f; unsigned u; } v; v.f = x;
    unsigned r = v.u + 0x7FFF + ((v.u >> 16) & 1);
    return (unsigned short)(r >> 16);
}
__device__ __forceinline__ float bf16_to_f(unsigned short h) {
    union { unsigned u; float f; } v; v.u = ((unsigned)h) << 16; return v.f;
}
__device__ __forceinline__ unsigned long long pack4(unsigned short a, unsigned short b,
                                                    unsigned short c, unsigned short d) {
    return (unsigned long long)a | ((unsigned long long)b << 16)
         | ((unsigned long long)c << 32) | ((unsigned long long)d << 48);
}

#define MFMA_(d, va, vb) d = __builtin_amdgcn_mfma_f32_16x16x32_bf16(va, vb, d, 0, 0, 0)

// ---------------------------------------------------------------------------
// Fragment layout (A and W): F[p][rgw][kf][l][e]; rgw=r>>4, kf=k>>5,
// l=((k>>3)&3)*16+(r&15), e=k&7. Per-(p,rgw) chunk = 32*64*8 = 16384 shorts.
// ---------------------------------------------------------------------------
__device__ __forceinline__ void write_frag3(unsigned short* __restrict__ dst, int NRGW,
                                            int r, int k, float x)
{
    unsigned short hi = bf16_rn(x); float r1 = x - bf16_to_f(hi);
    unsigned short md = bf16_rn(r1);
    unsigned short lo = bf16_rn(r1 - bf16_to_f(md));
    int base = (((r >> 4) * 32 + (k >> 5)) * 64 + ((k >> 3) & 3) * 16 + (r & 15)) * 8 + (k & 7);
    int ps = NRGW * 16384;
    dst[base] = hi; dst[ps + base] = md; dst[2 * ps + base] = lo;
}

__launch_bounds__(256)
__global__ void rearr_frag(const float* __restrict__ src, int ld, int c0,
                           unsigned short* __restrict__ dst, int R, int K)
{
    int idx = blockIdx.x * 256 + threadIdx.x;
    int kpr = K >> 3;
    if (idx >= R * kpr) return;
    int r = idx / kpr, k = (idx % kpr) * 8;
    int NRGW = R >> 4;
    const float* s = src + (size_t)r * ld + c0 + k;
    float4 v0 = *(const float4*)s, v1 = *(const float4*)(s + 4);
    float xs[8] = {v0.x, v0.y, v0.z, v0.w, v1.x, v1.y, v1.z, v1.w};
    unsigned short hi[8], md[8], lo[8];
#pragma unroll
    for (int e = 0; e < 8; ++e) {
        hi[e] = bf16_rn(xs[e]); float r1 = xs[e] - bf16_to_f(hi[e]);
        md[e] = bf16_rn(r1);
        lo[e] = bf16_rn(r1 - bf16_to_f(md[e]));
    }
    int base = (((r >> 4) * 32 + (k >> 5)) * 64 + ((k >> 3) & 3) * 16 + (r & 15)) * 8;
    size_t ps = (size_t)NRGW * 16384;
    *(unsigned long long*)&dst[base]          = pack4(hi[0], hi[1], hi[2], hi[3]);
    *(unsigned long long*)&dst[base + 4]      = pack4(hi[4], hi[5], hi[6], hi[7]);
    *(unsigned long long*)&dst[ps + base]     = pack4(md[0], md[1], md[2], md[3]);
    *(unsigned long long*)&dst[ps + base + 4] = pack4(md[4], md[5], md[6], md[7]);
    *(unsigned long long*)&dst[2*ps + base]     = pack4(lo[0], lo[1], lo[2], lo[3]);
    *(unsigned long long*)&dst[2*ps + base + 4] = pack4(lo[4], lo[5], lo[6], lo[7]);
}

// ---------------------------------------------------------------------------
// Software grid barrier (R5/R6-proven). All blocks co-resident.
// ---------------------------------------------------------------------------
__device__ __forceinline__ void grid_barrier(unsigned* bar, int nblk)
{
    __syncthreads();
    if (threadIdx.x == 0) {
        __threadfence();
        unsigned my_gen = __hip_atomic_load(&bar[1], __ATOMIC_RELAXED, __HIP_MEMORY_SCOPE_AGENT);
        unsigned prev = __hip_atomic_fetch_add(&bar[0], 1u, __ATOMIC_ACQ_REL, __HIP_MEMORY_SCOPE_AGENT);
        if (prev == (unsigned)(nblk - 1)) {
            __hip_atomic_store(&bar[0], 0u, __ATOMIC_RELAXED, __HIP_MEMORY_SCOPE_AGENT);
            __hip_atomic_fetch_add(&bar[1], 1u, __ATOMIC_RELEASE, __HIP_MEMORY_SCOPE_AGENT);
        } else {
            unsigned g;
            do { g = __hip_atomic_load(&bar[1], __ATOMIC_ACQUIRE, __HIP_MEMORY_SCOPE_AGENT); }
            while (g == my_gen);
        }
        __threadfence();
    }
    __syncthreads();
}

// ---------------------------------------------------------------------------
// Batched fp32 GEMM via bf16-split MFMA (validated R3): C = A@W^T + bias.
// ---------------------------------------------------------------------------
template <int NS>
__launch_bounds__(256, 2)
__global__ void gemm_mfma_split(const float* __restrict__ A, int lda,
                                const float* __restrict__ W, int ldw,
                                float* __restrict__ C, int ldc,
                                const float* __restrict__ bias,
                                int M, int N, int K)
{
    __shared__ unsigned short Abf[NS][128][40];
    __shared__ unsigned short Bbf[NS][128][40];
    const int tid = threadIdx.x;
    const int m0 = blockIdx.y * 128, n0 = blockIdx.x * 128;
    const int wave = tid >> 6, lane = tid & 63;
    const int wr = wave >> 1, wc = wave & 1;
    const int lr = lane & 15, lk = (lane >> 4) * 8;

    f32x4 acc[4][4];
#pragma unroll
    for (int i = 0; i < 4; ++i)
#pragma unroll
        for (int j = 0; j < 4; ++j) acc[i][j] = (f32x4){0.f, 0.f, 0.f, 0.f};

    const int arow = tid >> 1;
    const int akh  = (tid & 1) * 16;
    int gr = m0 + arow; if (gr > M - 1) gr = M - 1;
    int gn = n0 + arow; if (gn > N - 1) gn = N - 1;
    const float* aptr = A + (size_t)gr * lda + akh;
    const float* wptr = W + (size_t)gn * ldw + akh;

    for (int k0 = 0; k0 < K; k0 += 32) {
#pragma unroll
        for (int q = 0; q < 4; ++q) {
            float4 v = *(const float4*)(aptr + k0 + q * 4);
            float xs[4] = {v.x, v.y, v.z, v.w};
            unsigned short h[4], hm[4], hl[4];
#pragma unroll
            for (int e = 0; e < 4; ++e) {
                h[e] = bf16_rn(xs[e]);
                if (NS == 3) {
                    float r1 = xs[e] - bf16_to_f(h[e]);
                    hm[e] = bf16_rn(r1);
                    hl[e] = bf16_rn(r1 - bf16_to_f(hm[e]));
                }
            }
            *(unsigned long long*)&Abf[0][arow][akh + q * 4] = pack4(h[0], h[1], h[2], h[3]);
            if (NS == 3) {
                *(unsigned long long*)&Abf[1][arow][akh + q * 4] = pack4(hm[0], hm[1], hm[2], hm[3]);
                *(unsigned long long*)&Abf[2][arow][akh + q * 4] = pack4(hl[0], hl[1], hl[2], hl[3]);
            }
        }
#pragma unroll
        for (int q = 0; q < 4; ++q) {
            float4 v = *(const float4*)(wptr + k0 + q * 4);
            float xs[4] = {v.x, v.y, v.z, v.w};
            unsigned short h[4], hm[4], hl[4];
#pragma unroll
            for (int e = 0; e < 4; ++e) {
                h[e] = bf16_rn(xs[e]);
                if (NS == 3) {
                    float r1 = xs[e] - bf16_to_f(h[e]);
                    hm[e] = bf16_rn(r1);
                    hl[e] = bf16_rn(r1 - bf16_to_f(hm[e]));
                }
            }
            *(unsigned long long*)&Bbf[0][arow][akh + q * 4] = pack4(h[0], h[1], h[2], h[3]);
            if (NS == 3) {
                *(unsigned long long*)&Bbf[1][arow][akh + q * 4] = pack4(hm[0], hm[1], hm[2], hm[3]);
                *(unsigned long long*)&Bbf[2][arow][akh + q * 4] = pack4(hl[0], hl[1], hl[2], hl[3]);
            }
        }
        __syncthreads();

        short8v a[NS][4], b[4];
#pragma unroll
        for (int p = 0; p < NS; ++p)
#pragma unroll
            for (int i = 0; i < 4; ++i)
                a[p][i] = *(const short8v*)&Abf[p][wr * 64 + i * 16 + lr][lk];
#pragma unroll
        for (int q = 0; q < NS; ++q) {
#pragma unroll
            for (int j = 0; j < 4; ++j)
                b[j] = *(const short8v*)&Bbf[q][wc * 64 + j * 16 + lr][lk];
            const int pmax = (NS == 1) ? 1 : (3 - q);
#pragma unroll
            for (int p = 0; p < 3; ++p) {
                if (p >= pmax) break;
#pragma unroll
                for (int i = 0; i < 4; ++i)
#pragma unroll
                    for (int j = 0; j < 4; ++j)
                        acc[i][j] = __builtin_amdgcn_mfma_f32_16x16x32_bf16(
                            a[p][i], b[j], acc[i][j], 0, 0, 0);
            }
        }
        __syncthreads();
    }

    const int crow = (lane >> 4) * 4;
#pragma unroll
    for (int i = 0; i < 4; ++i) {
        int mbase = m0 + wr * 64 + i * 16 + crow;
#pragma unroll
        for (int j = 0; j < 4; ++j) {
            int n = n0 + wc * 64 + j * 16 + lr;
            if (n < N) {
                float bv = bias[n];
#pragma unroll
                for (int r = 0; r < 4; ++r) {
                    int m = mbase + r;
                    if (m < M) C[(size_t)m * ldc + n] = acc[i][j][r] + bv;
                }
            }
        }
    }
}

__launch_bounds__(256)
__global__ void zero_f(float* __restrict__ p, int n)
{
    int i = blockIdx.x * 256 + threadIdx.x;
    if (i < n) p[i] = 0.f;
}

__launch_bounds__(256)
__global__ void vec_add2(const float* __restrict__ a, const float* __restrict__ b,
                         float* __restrict__ o, int n)
{
    int i = blockIdx.x * 256 + threadIdx.x;
    if (i < n) o[i] = a[i] + b[i];
}

__launch_bounds__(256)
__global__ void sample0_fill(const float* __restrict__ emW, const float* __restrict__ emb,
                             float* __restrict__ samples)
{
    int idx = blockIdx.x * 256 + threadIdx.x; // 65536
    int d = idx & 1023;
    samples[idx] = emW[(size_t)d * 20000 + 19998] + emb[d];
}

// stage one rg-chunk (96KB: 3 planes x 16384 shorts) of a 64-row frag buffer
__device__ __forceinline__ void stage_A(unsigned short* __restrict__ LDSA,
                                        const unsigned short* __restrict__ src,
                                        int rg, int tid)
{
#pragma unroll
    for (int p = 0; p < 3; ++p) {
        const unsigned short* sp = src + (size_t)(p * 4 + rg) * 16384;
        unsigned short* dp = LDSA + p * 16384;
#pragma unroll
        for (int it = 0; it < 4; ++it) {
            int idx = tid + it * 512;
            *(short8v*)&dp[idx * 8] = *(const short8v*)&sp[idx * 8];
        }
    }
}

// ---------------------------------------------------------------------------
// Persistent encoder: 160 steps, 256 blocks x 512 threads (8 waves).
// Block (rg=bid>>6, cg=bid&63); wave w: gate=w&3, kh=w>>2. Weights in VGPRs.
// ---------------------------------------------------------------------------
__launch_bounds__(512, 2)
__global__ void coop_enc(const unsigned short* __restrict__ WencF,  // frag [3][256][32][512]
                         const float* __restrict__ Xbig,
                         const float* __restrict__ benc,
                         unsigned short* __restrict__ hfrag,        // 2 bufs x 196608
                         float* __restrict__ enc_seq,
                         float* __restrict__ enc_pad,
                         unsigned* __restrict__ bar)
{
    __shared__ unsigned short LDSA[3 * 16384];
    __shared__ float gbuf[8][16][16];
    const int bid = blockIdx.x, tid = threadIdx.x;
    const int w = tid >> 6, lane = tid & 63;
    const int g = w & 3, kh = w >> 2;
    const int rg = bid >> 6, cg = bid & 63;
    const int wbase = g * 64 + cg;
    const int r_l = (tid & 255) >> 4, c_l = tid & 15;
    const int row = rg * 16 + r_l, col = cg * 16 + c_l;
    float cstate = 0.f;

    // ---- preload weight slice: 16 kf x 3 planes = 48 short8v = 192 VGPRs ----
    short8v wreg[48];
#pragma unroll
    for (int i = 0; i < 16; ++i) {
        int kf = kh * 16 + i;
#pragma unroll
        for (int p = 0; p < 3; ++p)
            wreg[i * 3 + p] = *(const short8v*)&WencF[((size_t)(p * 256 + wbase) * 32 + kf) * 512 + lane * 8];
    }

    for (int s = 0; s < 160; ++s) {
        const unsigned short* hf = hfrag + (s & 1) * 196608;
        stage_A(LDSA, hf, rg, tid);
        __syncthreads();

        f32x4 acc0 = (f32x4){0.f,0.f,0.f,0.f}, acc1 = acc0;
#pragma unroll
        for (int i = 0; i < 16; ++i) {
            int kf = kh * 16 + i;
            short8v a0 = *(const short8v*)&LDSA[(kf * 64 + lane) * 8];
            short8v a1 = *(const short8v*)&LDSA[16384 + (kf * 64 + lane) * 8];
            short8v a2 = *(const short8v*)&LDSA[32768 + (kf * 64 + lane) * 8];
            short8v b0 = wreg[i * 3 + 0], b1 = wreg[i * 3 + 1], b2 = wreg[i * 3 + 2];
            f32x4& A = (i & 1) ? acc1 : acc0;
            MFMA_(A, a0, b0); MFMA_(A, a0, b1); MFMA_(A, a1, b0);
            MFMA_(A, a1, b1); MFMA_(A, a0, b2); MFMA_(A, a2, b0);
        }
        acc0 += acc1;
#pragma unroll
        for (int r = 0; r < 4; ++r)
            gbuf[w][(lane >> 4) * 4 + r][lane & 15] = acc0[r];
        __syncthreads();

        if (tid < 256) {
            float gv[4];
#pragma unroll
            for (int g2 = 0; g2 < 4; ++g2) {
                float x = (s < 80) ? Xbig[((size_t)s * 64 + row) * 4096 + g2 * 1024 + col]
                                   : benc[g2 * 1024 + col];
                gv[g2] = gbuf[g2][r_l][c_l] + gbuf[4 + g2][r_l][c_l] + x;
            }
            float cn = sigmf(gv[1]) * cstate + sigmf(gv[0]) * tanhf(gv[2]);
            float hn = sigmf(gv[3]) * tanhf(cn);
            cstate = cn;
            float* st = (s < 80) ? (enc_seq + (size_t)s * 65536)
                                 : (enc_pad + (size_t)(s - 80) * 65536);
            st[row * 1024 + col] = hn;
            write_frag3(hfrag + ((s + 1) & 1) * 196608, 4, row, col, hn);
        }
        grid_barrier(bar, 256);
    }
}

// ---------------------------------------------------------------------------
// Persistent decoder: 80 warm-up + 80 decode steps. 256 blocks x 512 threads.
// Block (gg=bid>>6, cg=bid&63) = gate gg, cols cg*16..+16, all 64 rows.
// Wave kq=w owns 8 kf of combined K=2048 [ctx | h] in 96 VGPRs.
// ---------------------------------------------------------------------------
__launch_bounds__(512, 2)
__global__ void coop_dec(const unsigned short* __restrict__ WihcF,  // frag (ctx half)
                         const unsigned short* __restrict__ WhhF,   // frag (h half)
                         const float* __restrict__ Xwarm,
                         const float* __restrict__ S_g,
                         const float* __restrict__ ctxS,
                         const float* __restrict__ S_log,
                         const float* __restrict__ W1,               // [80][2048]
                         const float* __restrict__ EW2,              // [80][64][1024]
                         const float* __restrict__ enc_pad,
                         const float* __restrict__ prelu_w,
                         unsigned short* __restrict__ hfrag,         // 2 bufs
                         unsigned short* __restrict__ ctxfrag,
                         float* __restrict__ h_fp32,
                         float* __restrict__ h_all,
                         float* __restrict__ cglob,                  // [64][1024]
                         float* __restrict__ gsum,                   // [4][64][1024]
                         unsigned* __restrict__ bar)
{
    __shared__ float gred[8][1024];
    __shared__ float hsm[1024];
    __shared__ float wsm[80];
    __shared__ float rbuf[128];
    const int bid = blockIdx.x, tid = threadIdx.x;
    const int w = tid >> 6, lane = tid & 63;
    const int gg = bid >> 6, cg = bid & 63;
    const int wbase = gg * 64 + cg;
    const int kq = w;
    const float pw = prelu_w[0];

    // ---- preload weight slice: 8 kf x 3 planes = 24 short8v = 96 VGPRs ----
    const unsigned short* Wsrc = (kq < 4) ? WihcF : WhhF;
    const int kfbase = (kq & 3) * 8;
    short8v wreg[24];
#pragma unroll
    for (int i = 0; i < 8; ++i) {
#pragma unroll
        for (int p = 0; p < 3; ++p)
            wreg[i * 3 + p] = *(const short8v*)&Wsrc[((size_t)(p * 256 + wbase) * 32 + kfbase + i) * 512 + lane * 8];
    }

    for (int s = 0; s < 160; ++s) {
        const unsigned short* hf = hfrag + (s & 1) * 196608;
        const int t = s - 80;

        if (s >= 80) {
            // ---- Phase A: attention + ctx (blocks 0..63, batch=bid) ----
            if (bid < 64) {
                for (int i = tid; i < 1024; i += 512) hsm[i] = h_fp32[bid * 1024 + i];
                __syncthreads();
#pragma unroll
                for (int i = 0; i < 10; ++i) {
                    int sx = w * 10 + i;
                    float p = 0.f;
#pragma unroll
                    for (int q = 0; q < 16; ++q)
                        p = fmaf(hsm[lane + q * 64], W1[(size_t)sx * 2048 + lane + q * 64], p);
#pragma unroll
                    for (int off = 32; off; off >>= 1) p += __shfl_down(p, off, 64);
                    if (lane == 0) wsm[sx] = p + S_log[((size_t)t * 64 + bid) * 80 + sx];
                }
                __syncthreads();
                float v = (tid < 80) ? wsm[tid] : -3.4e38f;
                if (tid < 128) rbuf[tid] = v;
                __syncthreads();
                for (int off = 64; off >= 1; off >>= 1) {
                    if (tid < off) rbuf[tid] = fmaxf(rbuf[tid], rbuf[tid + off]);
                    __syncthreads();
                }
                float mx = rbuf[0];
                __syncthreads();
                float e = (tid < 80) ? __expf(wsm[tid] - mx) : 0.f;
                if (tid < 128) rbuf[tid] = e;
                __syncthreads();
                for (int off = 64; off >= 1; off >>= 1) {
                    if (tid < off) rbuf[tid] += rbuf[tid + off];
                    __syncthreads();
                }
                float inv = 1.f / rbuf[0];
                __syncthreads();
                if (tid < 80) wsm[tid] = e * inv;
                __syncthreads();
                {
                    int j = tid * 2;
                    float f0 = 0.f, f1 = 0.f;
                    for (int ss = 0; ss < 80; ++ss) {
                        float wv = wsm[ss];
                        float2 ev = *(const float2*)&EW2[((size_t)ss * 64 + bid) * 1024 + j];
                        f0 = fmaf(wv, ev.x, f0); f1 = fmaf(wv, ev.y, f1);
                    }
                    float2 cs = *(const float2*)&ctxS[((size_t)t * 64 + bid) * 1024 + j];
                    float2 ep = *(const float2*)&enc_pad[((size_t)t * 64 + bid) * 1024 + j];
                    float v0 = f0 + cs.x; v0 = (v0 >= 0.f) ? v0 : pw * v0; v0 += ep.x;
                    float v1 = f1 + cs.y; v1 = (v1 >= 0.f) ? v1 : pw * v1; v1 += ep.y;
                    write_frag3(ctxfrag, 4, bid, j, v0);
                    write_frag3(ctxfrag, 4, bid, j + 1, v1);
                }
            }
            grid_barrier(bar, 256);
        }

        // ---- Phase B: gate GEMM partials (all blocks) ----
        {
            f32x4 acc[4];
#pragma unroll
            for (int rg = 0; rg < 4; ++rg) acc[rg] = (f32x4){0.f,0.f,0.f,0.f};
            const bool active = (s >= 80) || (kq >= 4);
            if (active) {
                const unsigned short* asrc = (kq < 4) ? ctxfrag : hf;
#pragma unroll
                for (int i = 0; i < 8; ++i) {
                    int kfl = kfbase + i;
#pragma unroll
                    for (int rg = 0; rg < 4; ++rg) {
                        const unsigned short* ab = asrc + ((size_t)rg * 32 + kfl) * 512 + lane * 8;
                        short8v a0 = *(const short8v*)&ab[0];
                        short8v a1 = *(const short8v*)&ab[65536];
                        short8v a2 = *(const short8v*)&ab[131072];
                        short8v b0 = wreg[i * 3 + 0], b1 = wreg[i * 3 + 1], b2 = wreg[i * 3 + 2];
                        MFMA_(acc[rg], a0, b0); MFMA_(acc[rg], a0, b1); MFMA_(acc[rg], a1, b0);
                        MFMA_(acc[rg], a1, b1); MFMA_(acc[rg], a0, b2); MFMA_(acc[rg], a2, b0);
                    }
                }
            }
#pragma unroll
            for (int rg = 0; rg < 4; ++rg)
#pragma unroll
                for (int r = 0; r < 4; ++r)
                    gred[w][rg * 256 + lane * 4 + r] = acc[rg][r];
            __syncthreads();
#pragma unroll
            for (int e = 0; e < 2; ++e) {
                int slot = tid * 2 + e;
                int rg = slot >> 8, l = (slot >> 2) & 63, r = slot & 3;
                float sum = 0.f;
#pragma unroll
                for (int w2 = 0; w2 < 8; ++w2) sum += gred[w2][slot];
                int row = rg * 16 + (l >> 4) * 4 + r;
                int col = cg * 16 + (l & 15);
                gsum[((size_t)gg * 64 + row) * 1024 + col] = sum;
            }
        }
        grid_barrier(bar, 256);

        // ---- Phase C: pointwise gates (65536 elems over 128k threads) ----
        {
            int gtid = bid * 512 + tid;
            if (gtid < 65536) {
                int row = gtid >> 10, col = gtid & 1023;
                const float* xb = (s < 80) ? (Xwarm + ((size_t)s * 64 + row) * 4096)
                                           : (S_g + ((size_t)t * 64 + row) * 4096);
                float gv[4];
#pragma unroll
                for (int g2 = 0; g2 < 4; ++g2)
                    gv[g2] = gsum[((size_t)g2 * 64 + row) * 1024 + col] + xb[g2 * 1024 + col];
                float cv = cglob[gtid];
                float cn = sigmf(gv[1]) * cv + sigmf(gv[0]) * tanhf(gv[2]);
                float hn = sigmf(gv[3]) * tanhf(cn);
                cglob[gtid] = cn;
                h_fp32[gtid] = hn;
                if (s >= 80) h_all[(size_t)t * 65536 + gtid] = hn;
                write_frag3(hfrag + ((s + 1) & 1) * 196608, 4, row, col, hn);
            }
        }
        grid_barrier(bar, 256);
    }
}

// ---------------------------------------------------------------------------
extern "C" void kernel_launch(void* const* d_in, const int* in_sizes, int n_in,
                              void* d_out, int out_size, void* d_ws, size_t ws_size,
                              hipStream_t stream)
{
    (void)in_sizes; (void)n_in; (void)out_size; (void)ws_size;

    const float* input_data     = (const float*)d_in[0];
    const float* correct_answer = (const float*)d_in[1];
    const float* enc_W_ih = (const float*)d_in[2];
    const float* enc_W_hh = (const float*)d_in[3];
    const float* enc_b_ih = (const float*)d_in[4];
    const float* enc_b_hh = (const float*)d_in[5];
    const float* dec_W_ih = (const float*)d_in[6];
    const float* dec_W_hh = (const float*)d_in[7];
    const float* dec_b_ih = (const float*)d_in[8];
    const float* dec_b_hh = (const float*)d_in[9];
    const float* in_emb_W = (const float*)d_in[10];
    const float* in_emb_b = (const float*)d_in[11];
    const float* out_emb_W = (const float*)d_in[12];
    const float* out_emb_b = (const float*)d_in[13];
    const float* att_W1 = (const float*)d_in[14];
    const float* att_b1 = (const float*)d_in[15];
    const float* att_W2 = (const float*)d_in[16];
    const float* att_b2 = (const float*)d_in[17];
    const float* prelu_w = (const float*)d_in[18];

    float* out = (float*)d_out;
    char* ws = (char*)d_ws;

    // ---- d_out scratch (102.4M floats; all reads precede final vocab GEMM) ----
    float* Xbig    = out;                      // [80][64][4096]  20.97M
    float* S_g     = out + 20971520;           // [80][64][4096]  20.97M
    float* ctxS    = out + 41943040;           // [80][64][1024]   5.24M
    float* S_log   = out + 47185920;           // [80][64][80]     0.41M
    float* samples = out + 47595520;           // [80][64][1024]   5.24M
    float* EW2     = out + 52838400;           // [80][64][1024]   5.24M
    unsigned short* WencF = (unsigned short*)(out + 58081280);  // 12.58M shorts = 6.29M floats
    unsigned short* WhhDF = (unsigned short*)(out + 64372736);
    unsigned short* WihcF = (unsigned short*)(out + 70664192);  // ends 76.96M

    // ---- d_ws map ----
    size_t off = 0;
    auto alloc = [&](size_t nfloats) { float* p = (float*)(ws + off); off += nfloats * 4; return p; };
    float* enc_seq = alloc(80 * 64 * 1024);
    float* enc_pad = alloc(80 * 64 * 1024);
    float* h_all   = alloc(80 * 64 * 1024);
    float* benc    = alloc(4096);
    float* bdec    = alloc(4096);
    float* zb      = alloc(1024);
    float* hfragE_f = alloc(196608);   // 2 bufs x 196608 shorts
    float* hfragD_f = alloc(196608);
    float* ctxfrag_f= alloc(98304);    // 196608 shorts
    float* h_fp32   = alloc(65536);
    float* cglob    = alloc(65536);
    float* gsum     = alloc(262144);   // [4][64][1024]
    float* bar_f    = alloc(8);
    unsigned short* hfragE  = (unsigned short*)hfragE_f;
    unsigned short* hfragD  = (unsigned short*)hfragD_f;
    unsigned short* ctxfrag = (unsigned short*)ctxfrag_f;
    unsigned* bar0 = (unsigned*)bar_f;
    unsigned* bar1 = ((unsigned*)bar_f) + 4;

    auto big3 = [&](const float* A, int lda, const float* W, int ldw,
                    float* C, int ldc, const float* bias, int M, int N, int K) {
        dim3 g((N + 127) / 128, (M + 127) / 128);
        hipLaunchKernelGGL((gemm_mfma_split<3>), g, dim3(256), 0, stream,
                           A, lda, W, ldw, C, ldc, bias, M, N, K);
    };

    // ---- setup ----
    hipLaunchKernelGGL(vec_add2, dim3(16), dim3(256), 0, stream, enc_b_ih, enc_b_hh, benc, 4096);
    hipLaunchKernelGGL(vec_add2, dim3(16), dim3(256), 0, stream, dec_b_ih, dec_b_hh, bdec, 4096);
    hipLaunchKernelGGL(zero_f, dim3(4), dim3(256), 0, stream, zb, 1024);
    hipLaunchKernelGGL(zero_f, dim3(768), dim3(256), 0, stream, hfragE_f, 196608);
    hipLaunchKernelGGL(zero_f, dim3(768), dim3(256), 0, stream, hfragD_f, 196608);
    hipLaunchKernelGGL(zero_f, dim3(256), dim3(256), 0, stream, h_fp32, 65536);
    hipLaunchKernelGGL(zero_f, dim3(256), dim3(256), 0, stream, cglob, 65536);
    hipLaunchKernelGGL(zero_f, dim3(1), dim3(256), 0, stream, bar_f, 8);

    // ---- weight frag rearranges ----
    hipLaunchKernelGGL(rearr_frag, dim3(2048), dim3(256), 0, stream, enc_W_hh, 1024, 0, WencF, 4096, 1024);
    hipLaunchKernelGGL(rearr_frag, dim3(2048), dim3(256), 0, stream, dec_W_hh, 1024, 0, WhhDF, 4096, 1024);
    hipLaunchKernelGGL(rearr_frag, dim3(2048), dim3(256), 0, stream, dec_W_ih, 2048, 1024, WihcF, 4096, 1024);

    // ---- batched big GEMMs (NS=3, feed recurrences) ----
    big3(input_data, 4096, enc_W_ih, 4096, Xbig, 4096, benc, 5120, 4096, 4096);
    hipLaunchKernelGGL(sample0_fill, dim3(256), dim3(256), 0, stream, in_emb_W, in_emb_b, samples);
    big3(correct_answer + (size_t)64 * 20000, 20000, in_emb_W, 20000,
         samples + 65536, 1024, in_emb_b, 5056, 1024, 20000);
    big3(samples, 1024, dec_W_ih, 2048, S_g, 4096, bdec, 5120, 4096, 1024);
    big3(samples, 1024, att_W2, 2048, ctxS, 1024, att_b2, 5120, 1024, 1024);
    big3(samples, 1024, att_W1 + 1024, 2048, S_log, 80, att_b1, 5120, 80, 1024);

    // ---- persistent encoder (160 steps) ----
    hipLaunchKernelGGL(coop_enc, dim3(256), dim3(512), 0, stream,
                       WencF, Xbig, benc, hfragE, enc_seq, enc_pad, bar0);

    // ---- post-encoder projections: warm-up input + EW2 (linear attn fold) ----
    big3(enc_seq, 1024, dec_W_ih, 2048, Xbig, 4096, bdec, 5120, 4096, 1024);
    big3(enc_seq, 1024, att_W2 + 1024, 2048, EW2, 1024, zb, 5120, 1024, 1024);

    // ---- persistent decoder (80 warm-up + 80 decode) ----
    hipLaunchKernelGGL(coop_dec, dim3(256), dim3(512), 0, stream,
                       WihcF, WhhDF, Xbig, S_g, ctxS, S_log,
                       att_W1, EW2, enc_pad, prelu_w,
                       hfragD, ctxfrag, h_fp32, h_all, cglob, gsum, bar1);

    // ---- final vocab projection (NS=1, output-facing) ----
    {
        dim3 g((20000 + 127) / 128, (5120 + 127) / 128);
        hipLaunchKernelGGL((gemm_mfma_split<1>), g, dim3(256), 0, stream,
                           h_all, 1024, out_emb_W, 1024, out, 20000, out_emb_b, 5120, 20000, 1024);
    }
}

// Round 8
// 28288.034 us; speedup vs baseline: 1.8567x; 1.7764x over previous
//
#include <hip/hip_runtime.h>
#include <cstddef>
#include <cstdint>

typedef __attribute__((ext_vector_type(8))) short short8v;
typedef __attribute__((ext_vector_type(4))) float f32x4;

__device__ __forceinline__ float sigmf(float x) { return 1.0f / (1.0f + __expf(-x)); }

__device__ __forceinline__ unsigned short bf16_rn(float x) {
    union { float f; unsigned u; } v; v.f = x;
    unsigned r = v.u + 0x7FFF + ((v.u >> 16) & 1);
    return (unsigned short)(r >> 16);
}
__device__ __forceinline__ float bf16_to_f(unsigned short h) {
    union { unsigned u; float f; } v; v.u = ((unsigned)h) << 16; return v.f;
}
__device__ __forceinline__ unsigned long long pack4(unsigned short a, unsigned short b,
                                                    unsigned short c, unsigned short d) {
    return (unsigned long long)a | ((unsigned long long)b << 16)
         | ((unsigned long long)c << 32) | ((unsigned long long)d << 48);
}

#define MFMA_(d, va, vb) d = __builtin_amdgcn_mfma_f32_16x16x32_bf16(va, vb, d, 0, 0, 0)

// ---------------------------------------------------------------------------
// Fragment layout (A and W): F[p][rgw][kf][l][e]; rgw=r>>4, kf=k>>5,
// l=((k>>3)&3)*16+(r&15), e=k&7. Per-(p,rgw) chunk = 32*64*8 = 16384 shorts.
// ---------------------------------------------------------------------------
__device__ __forceinline__ void write_frag3(unsigned short* __restrict__ dst, int NRGW,
                                            int r, int k, float x)
{
    unsigned short hi = bf16_rn(x); float r1 = x - bf16_to_f(hi);
    unsigned short md = bf16_rn(r1);
    unsigned short lo = bf16_rn(r1 - bf16_to_f(md));
    int base = (((r >> 4) * 32 + (k >> 5)) * 64 + ((k >> 3) & 3) * 16 + (r & 15)) * 8 + (k & 7);
    int ps = NRGW * 16384;
    dst[base] = hi; dst[ps + base] = md; dst[2 * ps + base] = lo;
}

__launch_bounds__(256)
__global__ void rearr_frag(const float* __restrict__ src, int ld, int c0,
                           unsigned short* __restrict__ dst, int R, int K)
{
    int idx = blockIdx.x * 256 + threadIdx.x;
    int kpr = K >> 3;
    if (idx >= R * kpr) return;
    int r = idx / kpr, k = (idx % kpr) * 8;
    int NRGW = R >> 4;
    const float* s = src + (size_t)r * ld + c0 + k;
    float4 v0 = *(const float4*)s, v1 = *(const float4*)(s + 4);
    float xs[8] = {v0.x, v0.y, v0.z, v0.w, v1.x, v1.y, v1.z, v1.w};
    unsigned short hi[8], md[8], lo[8];
#pragma unroll
    for (int e = 0; e < 8; ++e) {
        hi[e] = bf16_rn(xs[e]); float r1 = xs[e] - bf16_to_f(hi[e]);
        md[e] = bf16_rn(r1);
        lo[e] = bf16_rn(r1 - bf16_to_f(md[e]));
    }
    int base = (((r >> 4) * 32 + (k >> 5)) * 64 + ((k >> 3) & 3) * 16 + (r & 15)) * 8;
    size_t ps = (size_t)NRGW * 16384;
    *(unsigned long long*)&dst[base]          = pack4(hi[0], hi[1], hi[2], hi[3]);
    *(unsigned long long*)&dst[base + 4]      = pack4(hi[4], hi[5], hi[6], hi[7]);
    *(unsigned long long*)&dst[ps + base]     = pack4(md[0], md[1], md[2], md[3]);
    *(unsigned long long*)&dst[ps + base + 4] = pack4(md[4], md[5], md[6], md[7]);
    *(unsigned long long*)&dst[2*ps + base]     = pack4(lo[0], lo[1], lo[2], lo[3]);
    *(unsigned long long*)&dst[2*ps + base + 4] = pack4(lo[4], lo[5], lo[6], lo[7]);
}

// ---------------------------------------------------------------------------
// Software grid barrier v2: ordering paid ONCE per barrier, not per probe.
// Arrival: release fence (wb) + RELAXED fetch_add (coherence-point RMW, no inv).
// Spin: RELAXED atomic loads (sc-bypass, no inv) + s_sleep backoff.
// Master: relaxed count reset, RELEASE generation bump (orders the reset).
// Exit: one acquire fence (single inv) then proceed.
// ---------------------------------------------------------------------------
__device__ __forceinline__ void grid_barrier(unsigned* bar, int nblk)
{
    __syncthreads();
    if (threadIdx.x == 0) {
        __threadfence();   // release: write back this block's stores
        unsigned my_gen = __hip_atomic_load(&bar[1], __ATOMIC_RELAXED, __HIP_MEMORY_SCOPE_AGENT);
        unsigned prev = __hip_atomic_fetch_add(&bar[0], 1u, __ATOMIC_RELAXED, __HIP_MEMORY_SCOPE_AGENT);
        if (prev == (unsigned)(nblk - 1)) {
            __hip_atomic_store(&bar[0], 0u, __ATOMIC_RELAXED, __HIP_MEMORY_SCOPE_AGENT);
            __hip_atomic_store(&bar[1], my_gen + 1u, __ATOMIC_RELEASE, __HIP_MEMORY_SCOPE_AGENT);
        } else {
            while (__hip_atomic_load(&bar[1], __ATOMIC_RELAXED, __HIP_MEMORY_SCOPE_AGENT) == my_gen)
                __builtin_amdgcn_s_sleep(8);
        }
        __threadfence();   // acquire: invalidate stale cache lines ONCE
    }
    __syncthreads();
}

// ---------------------------------------------------------------------------
// Batched fp32 GEMM via bf16-split MFMA (validated R3): C = A@W^T + bias.
// ---------------------------------------------------------------------------
template <int NS>
__launch_bounds__(256, 2)
__global__ void gemm_mfma_split(const float* __restrict__ A, int lda,
                                const float* __restrict__ W, int ldw,
                                float* __restrict__ C, int ldc,
                                const float* __restrict__ bias,
                                int M, int N, int K)
{
    __shared__ unsigned short Abf[NS][128][40];
    __shared__ unsigned short Bbf[NS][128][40];
    const int tid = threadIdx.x;
    const int m0 = blockIdx.y * 128, n0 = blockIdx.x * 128;
    const int wave = tid >> 6, lane = tid & 63;
    const int wr = wave >> 1, wc = wave & 1;
    const int lr = lane & 15, lk = (lane >> 4) * 8;

    f32x4 acc[4][4];
#pragma unroll
    for (int i = 0; i < 4; ++i)
#pragma unroll
        for (int j = 0; j < 4; ++j) acc[i][j] = (f32x4){0.f, 0.f, 0.f, 0.f};

    const int arow = tid >> 1;
    const int akh  = (tid & 1) * 16;
    int gr = m0 + arow; if (gr > M - 1) gr = M - 1;
    int gn = n0 + arow; if (gn > N - 1) gn = N - 1;
    const float* aptr = A + (size_t)gr * lda + akh;
    const float* wptr = W + (size_t)gn * ldw + akh;

    for (int k0 = 0; k0 < K; k0 += 32) {
#pragma unroll
        for (int q = 0; q < 4; ++q) {
            float4 v = *(const float4*)(aptr + k0 + q * 4);
            float xs[4] = {v.x, v.y, v.z, v.w};
            unsigned short h[4], hm[4], hl[4];
#pragma unroll
            for (int e = 0; e < 4; ++e) {
                h[e] = bf16_rn(xs[e]);
                if (NS == 3) {
                    float r1 = xs[e] - bf16_to_f(h[e]);
                    hm[e] = bf16_rn(r1);
                    hl[e] = bf16_rn(r1 - bf16_to_f(hm[e]));
                }
            }
            *(unsigned long long*)&Abf[0][arow][akh + q * 4] = pack4(h[0], h[1], h[2], h[3]);
            if (NS == 3) {
                *(unsigned long long*)&Abf[1][arow][akh + q * 4] = pack4(hm[0], hm[1], hm[2], hm[3]);
                *(unsigned long long*)&Abf[2][arow][akh + q * 4] = pack4(hl[0], hl[1], hl[2], hl[3]);
            }
        }
#pragma unroll
        for (int q = 0; q < 4; ++q) {
            float4 v = *(const float4*)(wptr + k0 + q * 4);
            float xs[4] = {v.x, v.y, v.z, v.w};
            unsigned short h[4], hm[4], hl[4];
#pragma unroll
            for (int e = 0; e < 4; ++e) {
                h[e] = bf16_rn(xs[e]);
                if (NS == 3) {
                    float r1 = xs[e] - bf16_to_f(h[e]);
                    hm[e] = bf16_rn(r1);
                    hl[e] = bf16_rn(r1 - bf16_to_f(hm[e]));
                }
            }
            *(unsigned long long*)&Bbf[0][arow][akh + q * 4] = pack4(h[0], h[1], h[2], h[3]);
            if (NS == 3) {
                *(unsigned long long*)&Bbf[1][arow][akh + q * 4] = pack4(hm[0], hm[1], hm[2], hm[3]);
                *(unsigned long long*)&Bbf[2][arow][akh + q * 4] = pack4(hl[0], hl[1], hl[2], hl[3]);
            }
        }
        __syncthreads();

        short8v a[NS][4], b[4];
#pragma unroll
        for (int p = 0; p < NS; ++p)
#pragma unroll
            for (int i = 0; i < 4; ++i)
                a[p][i] = *(const short8v*)&Abf[p][wr * 64 + i * 16 + lr][lk];
#pragma unroll
        for (int q = 0; q < NS; ++q) {
#pragma unroll
            for (int j = 0; j < 4; ++j)
                b[j] = *(const short8v*)&Bbf[q][wc * 64 + j * 16 + lr][lk];
            const int pmax = (NS == 1) ? 1 : (3 - q);
#pragma unroll
            for (int p = 0; p < 3; ++p) {
                if (p >= pmax) break;
#pragma unroll
                for (int i = 0; i < 4; ++i)
#pragma unroll
                    for (int j = 0; j < 4; ++j)
                        acc[i][j] = __builtin_amdgcn_mfma_f32_16x16x32_bf16(
                            a[p][i], b[j], acc[i][j], 0, 0, 0);
            }
        }
        __syncthreads();
    }

    const int crow = (lane >> 4) * 4;
#pragma unroll
    for (int i = 0; i < 4; ++i) {
        int mbase = m0 + wr * 64 + i * 16 + crow;
#pragma unroll
        for (int j = 0; j < 4; ++j) {
            int n = n0 + wc * 64 + j * 16 + lr;
            if (n < N) {
                float bv = bias[n];
#pragma unroll
                for (int r = 0; r < 4; ++r) {
                    int m = mbase + r;
                    if (m < M) C[(size_t)m * ldc + n] = acc[i][j][r] + bv;
                }
            }
        }
    }
}

__launch_bounds__(256)
__global__ void zero_f(float* __restrict__ p, int n)
{
    int i = blockIdx.x * 256 + threadIdx.x;
    if (i < n) p[i] = 0.f;
}

__launch_bounds__(256)
__global__ void vec_add2(const float* __restrict__ a, const float* __restrict__ b,
                         float* __restrict__ o, int n)
{
    int i = blockIdx.x * 256 + threadIdx.x;
    if (i < n) o[i] = a[i] + b[i];
}

__launch_bounds__(256)
__global__ void sample0_fill(const float* __restrict__ emW, const float* __restrict__ emb,
                             float* __restrict__ samples)
{
    int idx = blockIdx.x * 256 + threadIdx.x; // 65536
    int d = idx & 1023;
    samples[idx] = emW[(size_t)d * 20000 + 19998] + emb[d];
}

// stage one rg-chunk (96KB: 3 planes x 16384 shorts) of a 64-row frag buffer
__device__ __forceinline__ void stage_A(unsigned short* __restrict__ LDSA,
                                        const unsigned short* __restrict__ src,
                                        int rg, int tid)
{
#pragma unroll
    for (int p = 0; p < 3; ++p) {
        const unsigned short* sp = src + (size_t)(p * 4 + rg) * 16384;
        unsigned short* dp = LDSA + p * 16384;
#pragma unroll
        for (int it = 0; it < 4; ++it) {
            int idx = tid + it * 512;
            *(short8v*)&dp[idx * 8] = *(const short8v*)&sp[idx * 8];
        }
    }
}

// ---------------------------------------------------------------------------
// Persistent encoder: 160 steps, 256 blocks x 512 threads (8 waves).
// Block (rg=bid>>6, cg=bid&63); wave w: gate=w&3, kh=w>>2. Weights in VGPRs.
// ---------------------------------------------------------------------------
__launch_bounds__(512, 2)
__global__ void coop_enc(const unsigned short* __restrict__ WencF,  // frag [3][256][32][512]
                         const float* __restrict__ Xbig,
                         const float* __restrict__ benc,
                         unsigned short* __restrict__ hfrag,        // 2 bufs x 196608
                         float* __restrict__ enc_seq,
                         float* __restrict__ enc_pad,
                         unsigned* __restrict__ bar)
{
    __shared__ unsigned short LDSA[3 * 16384];
    __shared__ float gbuf[8][16][16];
    const int bid = blockIdx.x, tid = threadIdx.x;
    const int w = tid >> 6, lane = tid & 63;
    const int g = w & 3, kh = w >> 2;
    const int rg = bid >> 6, cg = bid & 63;
    const int wbase = g * 64 + cg;
    const int r_l = (tid & 255) >> 4, c_l = tid & 15;
    const int row = rg * 16 + r_l, col = cg * 16 + c_l;
    float cstate = 0.f;

    // ---- preload weight slice: 16 kf x 3 planes = 48 short8v = 192 VGPRs ----
    short8v wreg[48];
#pragma unroll
    for (int i = 0; i < 16; ++i) {
        int kf = kh * 16 + i;
#pragma unroll
        for (int p = 0; p < 3; ++p)
            wreg[i * 3 + p] = *(const short8v*)&WencF[((size_t)(p * 256 + wbase) * 32 + kf) * 512 + lane * 8];
    }

    for (int s = 0; s < 160; ++s) {
        const unsigned short* hf = hfrag + (s & 1) * 196608;
        stage_A(LDSA, hf, rg, tid);
        __syncthreads();

        f32x4 acc0 = (f32x4){0.f,0.f,0.f,0.f}, acc1 = acc0;
#pragma unroll
        for (int i = 0; i < 16; ++i) {
            int kf = kh * 16 + i;
            short8v a0 = *(const short8v*)&LDSA[(kf * 64 + lane) * 8];
            short8v a1 = *(const short8v*)&LDSA[16384 + (kf * 64 + lane) * 8];
            short8v a2 = *(const short8v*)&LDSA[32768 + (kf * 64 + lane) * 8];
            short8v b0 = wreg[i * 3 + 0], b1 = wreg[i * 3 + 1], b2 = wreg[i * 3 + 2];
            f32x4& A = (i & 1) ? acc1 : acc0;
            MFMA_(A, a0, b0); MFMA_(A, a0, b1); MFMA_(A, a1, b0);
            MFMA_(A, a1, b1); MFMA_(A, a0, b2); MFMA_(A, a2, b0);
        }
        acc0 += acc1;
#pragma unroll
        for (int r = 0; r < 4; ++r)
            gbuf[w][(lane >> 4) * 4 + r][lane & 15] = acc0[r];
        __syncthreads();

        if (tid < 256) {
            float gv[4];
#pragma unroll
            for (int g2 = 0; g2 < 4; ++g2) {
                float x = (s < 80) ? Xbig[((size_t)s * 64 + row) * 4096 + g2 * 1024 + col]
                                   : benc[g2 * 1024 + col];
                gv[g2] = gbuf[g2][r_l][c_l] + gbuf[4 + g2][r_l][c_l] + x;
            }
            float cn = sigmf(gv[1]) * cstate + sigmf(gv[0]) * tanhf(gv[2]);
            float hn = sigmf(gv[3]) * tanhf(cn);
            cstate = cn;
            float* st = (s < 80) ? (enc_seq + (size_t)s * 65536)
                                 : (enc_pad + (size_t)(s - 80) * 65536);
            st[row * 1024 + col] = hn;
            write_frag3(hfrag + ((s + 1) & 1) * 196608, 4, row, col, hn);
        }
        grid_barrier(bar, 256);
    }
}

// ---------------------------------------------------------------------------
// Persistent decoder: 80 warm-up + 80 decode steps. 256 blocks x 512 threads.
// Block (gg=bid>>6, cg=bid&63) = gate gg, cols cg*16..+16, all 64 rows.
// Wave kq=w owns 8 kf of combined K=2048 [ctx | h] in 96 VGPRs.
// ---------------------------------------------------------------------------
__launch_bounds__(512, 2)
__global__ void coop_dec(const unsigned short* __restrict__ WihcF,  // frag (ctx half)
                         const unsigned short* __restrict__ WhhF,   // frag (h half)
                         const float* __restrict__ Xwarm,
                         const float* __restrict__ S_g,
                         const float* __restrict__ ctxS,
                         const float* __restrict__ S_log,
                         const float* __restrict__ W1,               // [80][2048]
                         const float* __restrict__ EW2,              // [80][64][1024]
                         const float* __restrict__ enc_pad,
                         const float* __restrict__ prelu_w,
                         unsigned short* __restrict__ hfrag,         // 2 bufs
                         unsigned short* __restrict__ ctxfrag,
                         float* __restrict__ h_fp32,
                         float* __restrict__ h_all,
                         float* __restrict__ cglob,                  // [64][1024]
                         float* __restrict__ gsum,                   // [4][64][1024]
                         unsigned* __restrict__ bar)
{
    __shared__ float gred[8][1024];
    __shared__ float hsm[1024];
    __shared__ float wsm[80];
    __shared__ float rbuf[128];
    const int bid = blockIdx.x, tid = threadIdx.x;
    const int w = tid >> 6, lane = tid & 63;
    const int gg = bid >> 6, cg = bid & 63;
    const int wbase = gg * 64 + cg;
    const int kq = w;
    const float pw = prelu_w[0];

    // ---- preload weight slice: 8 kf x 3 planes = 24 short8v = 96 VGPRs ----
    const unsigned short* Wsrc = (kq < 4) ? WihcF : WhhF;
    const int kfbase = (kq & 3) * 8;
    short8v wreg[24];
#pragma unroll
    for (int i = 0; i < 8; ++i) {
#pragma unroll
        for (int p = 0; p < 3; ++p)
            wreg[i * 3 + p] = *(const short8v*)&Wsrc[((size_t)(p * 256 + wbase) * 32 + kfbase + i) * 512 + lane * 8];
    }

    for (int s = 0; s < 160; ++s) {
        const unsigned short* hf = hfrag + (s & 1) * 196608;
        const int t = s - 80;

        if (s >= 80) {
            // ---- Phase A: attention + ctx (blocks 0..63, batch=bid) ----
            if (bid < 64) {
                for (int i = tid; i < 1024; i += 512) hsm[i] = h_fp32[bid * 1024 + i];
                __syncthreads();
#pragma unroll
                for (int i = 0; i < 10; ++i) {
                    int sx = w * 10 + i;
                    float p = 0.f;
#pragma unroll
                    for (int q = 0; q < 16; ++q)
                        p = fmaf(hsm[lane + q * 64], W1[(size_t)sx * 2048 + lane + q * 64], p);
#pragma unroll
                    for (int off = 32; off; off >>= 1) p += __shfl_down(p, off, 64);
                    if (lane == 0) wsm[sx] = p + S_log[((size_t)t * 64 + bid) * 80 + sx];
                }
                __syncthreads();
                float v = (tid < 80) ? wsm[tid] : -3.4e38f;
                if (tid < 128) rbuf[tid] = v;
                __syncthreads();
                for (int off = 64; off >= 1; off >>= 1) {
                    if (tid < off) rbuf[tid] = fmaxf(rbuf[tid], rbuf[tid + off]);
                    __syncthreads();
                }
                float mx = rbuf[0];
                __syncthreads();
                float e = (tid < 80) ? __expf(wsm[tid] - mx) : 0.f;
                if (tid < 128) rbuf[tid] = e;
                __syncthreads();
                for (int off = 64; off >= 1; off >>= 1) {
                    if (tid < off) rbuf[tid] += rbuf[tid + off];
                    __syncthreads();
                }
                float inv = 1.f / rbuf[0];
                __syncthreads();
                if (tid < 80) wsm[tid] = e * inv;
                __syncthreads();
                {
                    int j = tid * 2;
                    float f0 = 0.f, f1 = 0.f;
                    for (int ss = 0; ss < 80; ++ss) {
                        float wv = wsm[ss];
                        float2 ev = *(const float2*)&EW2[((size_t)ss * 64 + bid) * 1024 + j];
                        f0 = fmaf(wv, ev.x, f0); f1 = fmaf(wv, ev.y, f1);
                    }
                    float2 cs = *(const float2*)&ctxS[((size_t)t * 64 + bid) * 1024 + j];
                    float2 ep = *(const float2*)&enc_pad[((size_t)t * 64 + bid) * 1024 + j];
                    float v0 = f0 + cs.x; v0 = (v0 >= 0.f) ? v0 : pw * v0; v0 += ep.x;
                    float v1 = f1 + cs.y; v1 = (v1 >= 0.f) ? v1 : pw * v1; v1 += ep.y;
                    write_frag3(ctxfrag, 4, bid, j, v0);
                    write_frag3(ctxfrag, 4, bid, j + 1, v1);
                }
            }
            grid_barrier(bar, 256);
        }

        // ---- Phase B: gate GEMM partials (all blocks) ----
        {
            f32x4 acc[4];
#pragma unroll
            for (int rg = 0; rg < 4; ++rg) acc[rg] = (f32x4){0.f,0.f,0.f,0.f};
            const bool active = (s >= 80) || (kq >= 4);
            if (active) {
                const unsigned short* asrc = (kq < 4) ? ctxfrag : hf;
#pragma unroll
                for (int i = 0; i < 8; ++i) {
                    int kfl = kfbase + i;
#pragma unroll
                    for (int rg = 0; rg < 4; ++rg) {
                        const unsigned short* ab = asrc + ((size_t)rg * 32 + kfl) * 512 + lane * 8;
                        short8v a0 = *(const short8v*)&ab[0];
                        short8v a1 = *(const short8v*)&ab[65536];
                        short8v a2 = *(const short8v*)&ab[131072];
                        short8v b0 = wreg[i * 3 + 0], b1 = wreg[i * 3 + 1], b2 = wreg[i * 3 + 2];
                        MFMA_(acc[rg], a0, b0); MFMA_(acc[rg], a0, b1); MFMA_(acc[rg], a1, b0);
                        MFMA_(acc[rg], a1, b1); MFMA_(acc[rg], a0, b2); MFMA_(acc[rg], a2, b0);
                    }
                }
            }
#pragma unroll
            for (int rg = 0; rg < 4; ++rg)
#pragma unroll
                for (int r = 0; r < 4; ++r)
                    gred[w][rg * 256 + lane * 4 + r] = acc[rg][r];
            __syncthreads();
#pragma unroll
            for (int e = 0; e < 2; ++e) {
                int slot = tid * 2 + e;
                int rg = slot >> 8, l = (slot >> 2) & 63, r = slot & 3;
                float sum = 0.f;
#pragma unroll
                for (int w2 = 0; w2 < 8; ++w2) sum += gred[w2][slot];
                int row = rg * 16 + (l >> 4) * 4 + r;
                int col = cg * 16 + (l & 15);
                gsum[((size_t)gg * 64 + row) * 1024 + col] = sum;
            }
        }
        grid_barrier(bar, 256);

        // ---- Phase C: pointwise gates (65536 elems over 128k threads) ----
        {
            int gtid = bid * 512 + tid;
            if (gtid < 65536) {
                int row = gtid >> 10, col = gtid & 1023;
                const float* xb = (s < 80) ? (Xwarm + ((size_t)s * 64 + row) * 4096)
                                           : (S_g + ((size_t)t * 64 + row) * 4096);
                float gv[4];
#pragma unroll
                for (int g2 = 0; g2 < 4; ++g2)
                    gv[g2] = gsum[((size_t)g2 * 64 + row) * 1024 + col] + xb[g2 * 1024 + col];
                float cv = cglob[gtid];
                float cn = sigmf(gv[1]) * cv + sigmf(gv[0]) * tanhf(gv[2]);
                float hn = sigmf(gv[3]) * tanhf(cn);
                cglob[gtid] = cn;
                h_fp32[gtid] = hn;
                if (s >= 80) h_all[(size_t)t * 65536 + gtid] = hn;
                write_frag3(hfrag + ((s + 1) & 1) * 196608, 4, row, col, hn);
            }
        }
        grid_barrier(bar, 256);
    }
}

// ---------------------------------------------------------------------------
extern "C" void kernel_launch(void* const* d_in, const int* in_sizes, int n_in,
                              void* d_out, int out_size, void* d_ws, size_t ws_size,
                              hipStream_t stream)
{
    (void)in_sizes; (void)n_in; (void)out_size; (void)ws_size;

    const float* input_data     = (const float*)d_in[0];
    const float* correct_answer = (const float*)d_in[1];
    const float* enc_W_ih = (const float*)d_in[2];
    const float* enc_W_hh = (const float*)d_in[3];
    const float* enc_b_ih = (const float*)d_in[4];
    const float* enc_b_hh = (const float*)d_in[5];
    const float* dec_W_ih = (const float*)d_in[6];
    const float* dec_W_hh = (const float*)d_in[7];
    const float* dec_b_ih = (const float*)d_in[8];
    const float* dec_b_hh = (const float*)d_in[9];
    const float* in_emb_W = (const float*)d_in[10];
    const float* in_emb_b = (const float*)d_in[11];
    const float* out_emb_W = (const float*)d_in[12];
    const float* out_emb_b = (const float*)d_in[13];
    const float* att_W1 = (const float*)d_in[14];
    const float* att_b1 = (const float*)d_in[15];
    const float* att_W2 = (const float*)d_in[16];
    const float* att_b2 = (const float*)d_in[17];
    const float* prelu_w = (const float*)d_in[18];

    float* out = (float*)d_out;
    char* ws = (char*)d_ws;

    // ---- d_out scratch (102.4M floats; all reads precede final vocab GEMM) ----
    float* Xbig    = out;                      // [80][64][4096]  20.97M
    float* S_g     = out + 20971520;           // [80][64][4096]  20.97M
    float* ctxS    = out + 41943040;           // [80][64][1024]   5.24M
    float* S_log   = out + 47185920;           // [80][64][80]     0.41M
    float* samples = out + 47595520;           // [80][64][1024]   5.24M
    float* EW2     = out + 52838400;           // [80][64][1024]   5.24M
    unsigned short* WencF = (unsigned short*)(out + 58081280);  // 12.58M shorts = 6.29M floats
    unsigned short* WhhDF = (unsigned short*)(out + 64372736);
    unsigned short* WihcF = (unsigned short*)(out + 70664192);  // ends 76.96M

    // ---- d_ws map ----
    size_t off = 0;
    auto alloc = [&](size_t nfloats) { float* p = (float*)(ws + off); off += nfloats * 4; return p; };
    float* enc_seq = alloc(80 * 64 * 1024);
    float* enc_pad = alloc(80 * 64 * 1024);
    float* h_all   = alloc(80 * 64 * 1024);
    float* benc    = alloc(4096);
    float* bdec    = alloc(4096);
    float* zb      = alloc(1024);
    float* hfragE_f = alloc(196608);   // 2 bufs x 196608 shorts
    float* hfragD_f = alloc(196608);
    float* ctxfrag_f= alloc(98304);    // 196608 shorts
    float* h_fp32   = alloc(65536);
    float* cglob    = alloc(65536);
    float* gsum     = alloc(262144);   // [4][64][1024]
    float* bar_f    = alloc(8);
    unsigned short* hfragE  = (unsigned short*)hfragE_f;
    unsigned short* hfragD  = (unsigned short*)hfragD_f;
    unsigned short* ctxfrag = (unsigned short*)ctxfrag_f;
    unsigned* bar0 = (unsigned*)bar_f;
    unsigned* bar1 = ((unsigned*)bar_f) + 4;

    auto big3 = [&](const float* A, int lda, const float* W, int ldw,
                    float* C, int ldc, const float* bias, int M, int N, int K) {
        dim3 g((N + 127) / 128, (M + 127) / 128);
        hipLaunchKernelGGL((gemm_mfma_split<3>), g, dim3(256), 0, stream,
                           A, lda, W, ldw, C, ldc, bias, M, N, K);
    };

    // ---- setup ----
    hipLaunchKernelGGL(vec_add2, dim3(16), dim3(256), 0, stream, enc_b_ih, enc_b_hh, benc, 4096);
    hipLaunchKernelGGL(vec_add2, dim3(16), dim3(256), 0, stream, dec_b_ih, dec_b_hh, bdec, 4096);
    hipLaunchKernelGGL(zero_f, dim3(4), dim3(256), 0, stream, zb, 1024);
    hipLaunchKernelGGL(zero_f, dim3(768), dim3(256), 0, stream, hfragE_f, 196608);
    hipLaunchKernelGGL(zero_f, dim3(768), dim3(256), 0, stream, hfragD_f, 196608);
    hipLaunchKernelGGL(zero_f, dim3(256), dim3(256), 0, stream, h_fp32, 65536);
    hipLaunchKernelGGL(zero_f, dim3(256), dim3(256), 0, stream, cglob, 65536);
    hipLaunchKernelGGL(zero_f, dim3(1), dim3(256), 0, stream, bar_f, 8);

    // ---- weight frag rearranges ----
    hipLaunchKernelGGL(rearr_frag, dim3(2048), dim3(256), 0, stream, enc_W_hh, 1024, 0, WencF, 4096, 1024);
    hipLaunchKernelGGL(rearr_frag, dim3(2048), dim3(256), 0, stream, dec_W_hh, 1024, 0, WhhDF, 4096, 1024);
    hipLaunchKernelGGL(rearr_frag, dim3(2048), dim3(256), 0, stream, dec_W_ih, 2048, 1024, WihcF, 4096, 1024);

    // ---- batched big GEMMs (NS=3, feed recurrences) ----
    big3(input_data, 4096, enc_W_ih, 4096, Xbig, 4096, benc, 5120, 4096, 4096);
    hipLaunchKernelGGL(sample0_fill, dim3(256), dim3(256), 0, stream, in_emb_W, in_emb_b, samples);
    big3(correct_answer + (size_t)64 * 20000, 20000, in_emb_W, 20000,
         samples + 65536, 1024, in_emb_b, 5056, 1024, 20000);
    big3(samples, 1024, dec_W_ih, 2048, S_g, 4096, bdec, 5120, 4096, 1024);
    big3(samples, 1024, att_W2, 2048, ctxS, 1024, att_b2, 5120, 1024, 1024);
    big3(samples, 1024, att_W1 + 1024, 2048, S_log, 80, att_b1, 5120, 80, 1024);

    // ---- persistent encoder (160 steps) ----
    hipLaunchKernelGGL(coop_enc, dim3(256), dim3(512), 0, stream,
                       WencF, Xbig, benc, hfragE, enc_seq, enc_pad, bar0);

    // ---- post-encoder projections: warm-up input + EW2 (linear attn fold) ----
    big3(enc_seq, 1024, dec_W_ih, 2048, Xbig, 4096, bdec, 5120, 4096, 1024);
    big3(enc_seq, 1024, att_W2 + 1024, 2048, EW2, 1024, zb, 5120, 1024, 1024);

    // ---- persistent decoder (80 warm-up + 80 decode) ----
    hipLaunchKernelGGL(coop_dec, dim3(256), dim3(512), 0, stream,
                       WihcF, WhhDF, Xbig, S_g, ctxS, S_log,
                       att_W1, EW2, enc_pad, prelu_w,
                       hfragD, ctxfrag, h_fp32, h_all, cglob, gsum, bar1);

    // ---- final vocab projection (NS=1, output-facing) ----
    {
        dim3 g((20000 + 127) / 128, (5120 + 127) / 128);
        hipLaunchKernelGGL((gemm_mfma_split<1>), g, dim3(256), 0, stream,
                           h_all, 1024, out_emb_W, 1024, out, 20000, out_emb_b, 5120, 20000, 1024);
    }
}

// Round 9
// 24045.952 us; speedup vs baseline: 2.1842x; 1.1764x over previous
//
#include <hip/hip_runtime.h>
#include <cstddef>
#include <cstdint>

typedef __attribute__((ext_vector_type(8))) short short8v;
typedef __attribute__((ext_vector_type(4))) float f32x4;

__device__ __forceinline__ float sigmf(float x) { return 1.0f / (1.0f + __expf(-x)); }

__device__ __forceinline__ unsigned short bf16_rn(float x) {
    union { float f; unsigned u; } v; v.f = x;
    unsigned r = v.u + 0x7FFF + ((v.u >> 16) & 1);
    return (unsigned short)(r >> 16);
}
__device__ __forceinline__ float bf16_to_f(unsigned short h) {
    union { unsigned u; float f; } v; v.u = ((unsigned)h) << 16; return v.f;
}
__device__ __forceinline__ unsigned long long pack4(unsigned short a, unsigned short b,
                                                    unsigned short c, unsigned short d) {
    return (unsigned long long)a | ((unsigned long long)b << 16)
         | ((unsigned long long)c << 32) | ((unsigned long long)d << 48);
}

#define MFMA_(d, va, vb) d = __builtin_amdgcn_mfma_f32_16x16x32_bf16(va, vb, d, 0, 0, 0)

// ---------------------------------------------------------------------------
// Fragment layout (A and W): F[p][rgw][kf][l][e]; rgw=r>>4, kf=k>>5,
// l=((k>>3)&3)*16+(r&15), e=k&7. Per-(p,rgw) chunk = 32*64*8 = 16384 shorts.
// ---------------------------------------------------------------------------
__device__ __forceinline__ void write_frag3(unsigned short* __restrict__ dst, int NRGW,
                                            int r, int k, float x)
{
    unsigned short hi = bf16_rn(x); float r1 = x - bf16_to_f(hi);
    unsigned short md = bf16_rn(r1);
    unsigned short lo = bf16_rn(r1 - bf16_to_f(md));
    int base = (((r >> 4) * 32 + (k >> 5)) * 64 + ((k >> 3) & 3) * 16 + (r & 15)) * 8 + (k & 7);
    int ps = NRGW * 16384;
    dst[base] = hi; dst[ps + base] = md; dst[2 * ps + base] = lo;
}

__launch_bounds__(256)
__global__ void rearr_frag(const float* __restrict__ src, int ld, int c0,
                           unsigned short* __restrict__ dst, int R, int K)
{
    int idx = blockIdx.x * 256 + threadIdx.x;
    int kpr = K >> 3;
    if (idx >= R * kpr) return;
    int r = idx / kpr, k = (idx % kpr) * 8;
    int NRGW = R >> 4;
    const float* s = src + (size_t)r * ld + c0 + k;
    float4 v0 = *(const float4*)s, v1 = *(const float4*)(s + 4);
    float xs[8] = {v0.x, v0.y, v0.z, v0.w, v1.x, v1.y, v1.z, v1.w};
    unsigned short hi[8], md[8], lo[8];
#pragma unroll
    for (int e = 0; e < 8; ++e) {
        hi[e] = bf16_rn(xs[e]); float r1 = xs[e] - bf16_to_f(hi[e]);
        md[e] = bf16_rn(r1);
        lo[e] = bf16_rn(r1 - bf16_to_f(md[e]));
    }
    int base = (((r >> 4) * 32 + (k >> 5)) * 64 + ((k >> 3) & 3) * 16 + (r & 15)) * 8;
    size_t ps = (size_t)NRGW * 16384;
    *(unsigned long long*)&dst[base]          = pack4(hi[0], hi[1], hi[2], hi[3]);
    *(unsigned long long*)&dst[base + 4]      = pack4(hi[4], hi[5], hi[6], hi[7]);
    *(unsigned long long*)&dst[ps + base]     = pack4(md[0], md[1], md[2], md[3]);
    *(unsigned long long*)&dst[ps + base + 4] = pack4(md[4], md[5], md[6], md[7]);
    *(unsigned long long*)&dst[2*ps + base]     = pack4(lo[0], lo[1], lo[2], lo[3]);
    *(unsigned long long*)&dst[2*ps + base + 4] = pack4(lo[4], lo[5], lo[6], lo[7]);
}

// ---------------------------------------------------------------------------
// Software grid barrier v2 (R8-proven).
// ---------------------------------------------------------------------------
__device__ __forceinline__ void grid_barrier(unsigned* bar, int nblk)
{
    __syncthreads();
    if (threadIdx.x == 0) {
        __threadfence();
        unsigned my_gen = __hip_atomic_load(&bar[1], __ATOMIC_RELAXED, __HIP_MEMORY_SCOPE_AGENT);
        unsigned prev = __hip_atomic_fetch_add(&bar[0], 1u, __ATOMIC_RELAXED, __HIP_MEMORY_SCOPE_AGENT);
        if (prev == (unsigned)(nblk - 1)) {
            __hip_atomic_store(&bar[0], 0u, __ATOMIC_RELAXED, __HIP_MEMORY_SCOPE_AGENT);
            __hip_atomic_store(&bar[1], my_gen + 1u, __ATOMIC_RELEASE, __HIP_MEMORY_SCOPE_AGENT);
        } else {
            while (__hip_atomic_load(&bar[1], __ATOMIC_RELAXED, __HIP_MEMORY_SCOPE_AGENT) == my_gen)
                __builtin_amdgcn_s_sleep(8);
        }
        __threadfence();
    }
    __syncthreads();
}

// ---------------------------------------------------------------------------
// Batched fp32 GEMM via bf16-split MFMA (validated R3): C = A@W^T + bias.
// ---------------------------------------------------------------------------
template <int NS>
__launch_bounds__(256, 2)
__global__ void gemm_mfma_split(const float* __restrict__ A, int lda,
                                const float* __restrict__ W, int ldw,
                                float* __restrict__ C, int ldc,
                                const float* __restrict__ bias,
                                int M, int N, int K)
{
    __shared__ unsigned short Abf[NS][128][40];
    __shared__ unsigned short Bbf[NS][128][40];
    const int tid = threadIdx.x;
    const int m0 = blockIdx.y * 128, n0 = blockIdx.x * 128;
    const int wave = tid >> 6, lane = tid & 63;
    const int wr = wave >> 1, wc = wave & 1;
    const int lr = lane & 15, lk = (lane >> 4) * 8;

    f32x4 acc[4][4];
#pragma unroll
    for (int i = 0; i < 4; ++i)
#pragma unroll
        for (int j = 0; j < 4; ++j) acc[i][j] = (f32x4){0.f, 0.f, 0.f, 0.f};

    const int arow = tid >> 1;
    const int akh  = (tid & 1) * 16;
    int gr = m0 + arow; if (gr > M - 1) gr = M - 1;
    int gn = n0 + arow; if (gn > N - 1) gn = N - 1;
    const float* aptr = A + (size_t)gr * lda + akh;
    const float* wptr = W + (size_t)gn * ldw + akh;

    for (int k0 = 0; k0 < K; k0 += 32) {
#pragma unroll
        for (int q = 0; q < 4; ++q) {
            float4 v = *(const float4*)(aptr + k0 + q * 4);
            float xs[4] = {v.x, v.y, v.z, v.w};
            unsigned short h[4], hm[4], hl[4];
#pragma unroll
            for (int e = 0; e < 4; ++e) {
                h[e] = bf16_rn(xs[e]);
                if (NS == 3) {
                    float r1 = xs[e] - bf16_to_f(h[e]);
                    hm[e] = bf16_rn(r1);
                    hl[e] = bf16_rn(r1 - bf16_to_f(hm[e]));
                }
            }
            *(unsigned long long*)&Abf[0][arow][akh + q * 4] = pack4(h[0], h[1], h[2], h[3]);
            if (NS == 3) {
                *(unsigned long long*)&Abf[1][arow][akh + q * 4] = pack4(hm[0], hm[1], hm[2], hm[3]);
                *(unsigned long long*)&Abf[2][arow][akh + q * 4] = pack4(hl[0], hl[1], hl[2], hl[3]);
            }
        }
#pragma unroll
        for (int q = 0; q < 4; ++q) {
            float4 v = *(const float4*)(wptr + k0 + q * 4);
            float xs[4] = {v.x, v.y, v.z, v.w};
            unsigned short h[4], hm[4], hl[4];
#pragma unroll
            for (int e = 0; e < 4; ++e) {
                h[e] = bf16_rn(xs[e]);
                if (NS == 3) {
                    float r1 = xs[e] - bf16_to_f(h[e]);
                    hm[e] = bf16_rn(r1);
                    hl[e] = bf16_rn(r1 - bf16_to_f(hm[e]));
                }
            }
            *(unsigned long long*)&Bbf[0][arow][akh + q * 4] = pack4(h[0], h[1], h[2], h[3]);
            if (NS == 3) {
                *(unsigned long long*)&Bbf[1][arow][akh + q * 4] = pack4(hm[0], hm[1], hm[2], hm[3]);
                *(unsigned long long*)&Bbf[2][arow][akh + q * 4] = pack4(hl[0], hl[1], hl[2], hl[3]);
            }
        }
        __syncthreads();

        short8v a[NS][4], b[4];
#pragma unroll
        for (int p = 0; p < NS; ++p)
#pragma unroll
            for (int i = 0; i < 4; ++i)
                a[p][i] = *(const short8v*)&Abf[p][wr * 64 + i * 16 + lr][lk];
#pragma unroll
        for (int q = 0; q < NS; ++q) {
#pragma unroll
            for (int j = 0; j < 4; ++j)
                b[j] = *(const short8v*)&Bbf[q][wc * 64 + j * 16 + lr][lk];
            const int pmax = (NS == 1) ? 1 : (3 - q);
#pragma unroll
            for (int p = 0; p < 3; ++p) {
                if (p >= pmax) break;
#pragma unroll
                for (int i = 0; i < 4; ++i)
#pragma unroll
                    for (int j = 0; j < 4; ++j)
                        acc[i][j] = __builtin_amdgcn_mfma_f32_16x16x32_bf16(
                            a[p][i], b[j], acc[i][j], 0, 0, 0);
            }
        }
        __syncthreads();
    }

    const int crow = (lane >> 4) * 4;
#pragma unroll
    for (int i = 0; i < 4; ++i) {
        int mbase = m0 + wr * 64 + i * 16 + crow;
#pragma unroll
        for (int j = 0; j < 4; ++j) {
            int n = n0 + wc * 64 + j * 16 + lr;
            if (n < N) {
                float bv = bias[n];
#pragma unroll
                for (int r = 0; r < 4; ++r) {
                    int m = mbase + r;
                    if (m < M) C[(size_t)m * ldc + n] = acc[i][j][r] + bv;
                }
            }
        }
    }
}

__launch_bounds__(256)
__global__ void zero_f(float* __restrict__ p, int n)
{
    int i = blockIdx.x * 256 + threadIdx.x;
    if (i < n) p[i] = 0.f;
}

__launch_bounds__(256)
__global__ void vec_add2(const float* __restrict__ a, const float* __restrict__ b,
                         float* __restrict__ o, int n)
{
    int i = blockIdx.x * 256 + threadIdx.x;
    if (i < n) o[i] = a[i] + b[i];
}

__launch_bounds__(256)
__global__ void sample0_fill(const float* __restrict__ emW, const float* __restrict__ emb,
                             float* __restrict__ samples)
{
    int idx = blockIdx.x * 256 + threadIdx.x; // 65536
    int d = idx & 1023;
    samples[idx] = emW[(size_t)d * 20000 + 19998] + emb[d];
}

// stage one rg-chunk (96KB) of a 64-row frag buffer into LDS
__device__ __forceinline__ void stage_A(unsigned short* __restrict__ LDSA,
                                        const unsigned short* __restrict__ src,
                                        int rg, int tid)
{
#pragma unroll
    for (int p = 0; p < 3; ++p) {
        const unsigned short* sp = src + (size_t)(p * 4 + rg) * 16384;
        unsigned short* dp = LDSA + p * 16384;
#pragma unroll
        for (int it = 0; it < 4; ++it) {
            int idx = tid + it * 512;
            *(short8v*)&dp[idx * 8] = *(const short8v*)&sp[idx * 8];
        }
    }
}

// ---------------------------------------------------------------------------
// Persistent encoder: 160 steps, 256 blocks x 512 threads. Weights in VGPRs,
// Xbig/benc gate-adds prefetched to registers across the barrier.
// ---------------------------------------------------------------------------
__launch_bounds__(512, 2)
__global__ void coop_enc(const unsigned short* __restrict__ WencF,
                         const float* __restrict__ Xbig,
                         const float* __restrict__ benc,
                         unsigned short* __restrict__ hfrag,   // 2 bufs x 196608
                         float* __restrict__ enc_seq,
                         float* __restrict__ enc_pad,
                         unsigned* __restrict__ bar)
{
    __shared__ unsigned short LDSA[3 * 16384];
    __shared__ float gbuf[8][16][16];
    const int bid = blockIdx.x, tid = threadIdx.x;
    const int w = tid >> 6, lane = tid & 63;
    const int g = w & 3, kh = w >> 2;
    const int rg = bid >> 6, cg = bid & 63;
    const int wbase = g * 64 + cg;
    const int r_l = (tid & 255) >> 4, c_l = tid & 15;
    const int row = rg * 16 + r_l, col = cg * 16 + c_l;
    float cstate = 0.f;

    short8v wreg[48];
#pragma unroll
    for (int i = 0; i < 16; ++i) {
        int kf = kh * 16 + i;
#pragma unroll
        for (int p = 0; p < 3; ++p)
            wreg[i * 3 + p] = *(const short8v*)&WencF[((size_t)(p * 256 + wbase) * 32 + kf) * 512 + lane * 8];
    }

    float pf[4];
    if (tid < 256) {
#pragma unroll
        for (int g2 = 0; g2 < 4; ++g2)
            pf[g2] = Xbig[((size_t)0 * 64 + row) * 4096 + g2 * 1024 + col];
    }

    for (int s = 0; s < 160; ++s) {
        const unsigned short* hf = hfrag + (s & 1) * 196608;
        stage_A(LDSA, hf, rg, tid);
        __syncthreads();

        f32x4 acc0 = (f32x4){0.f,0.f,0.f,0.f}, acc1 = acc0;
#pragma unroll
        for (int i = 0; i < 16; ++i) {
            int kf = kh * 16 + i;
            short8v a0 = *(const short8v*)&LDSA[(kf * 64 + lane) * 8];
            short8v a1 = *(const short8v*)&LDSA[16384 + (kf * 64 + lane) * 8];
            short8v a2 = *(const short8v*)&LDSA[32768 + (kf * 64 + lane) * 8];
            short8v b0 = wreg[i * 3 + 0], b1 = wreg[i * 3 + 1], b2 = wreg[i * 3 + 2];
            f32x4& A = (i & 1) ? acc1 : acc0;
            MFMA_(A, a0, b0); MFMA_(A, a0, b1); MFMA_(A, a1, b0);
            MFMA_(A, a1, b1); MFMA_(A, a0, b2); MFMA_(A, a2, b0);
        }
        acc0 += acc1;
#pragma unroll
        for (int r = 0; r < 4; ++r)
            gbuf[w][(lane >> 4) * 4 + r][lane & 15] = acc0[r];
        __syncthreads();

        if (tid < 256) {
            float gv[4];
#pragma unroll
            for (int g2 = 0; g2 < 4; ++g2)
                gv[g2] = gbuf[g2][r_l][c_l] + gbuf[4 + g2][r_l][c_l] + pf[g2];
            float cn = sigmf(gv[1]) * cstate + sigmf(gv[0]) * tanhf(gv[2]);
            float hn = sigmf(gv[3]) * tanhf(cn);
            cstate = cn;
            float* st = (s < 80) ? (enc_seq + (size_t)s * 65536)
                                 : (enc_pad + (size_t)(s - 80) * 65536);
            st[row * 1024 + col] = hn;
            write_frag3(hfrag + ((s + 1) & 1) * 196608, 4, row, col, hn);
            // prefetch next step's gate-adds (read-only -> survives fence)
            if (s + 1 < 160) {
#pragma unroll
                for (int g2 = 0; g2 < 4; ++g2)
                    pf[g2] = (s + 1 < 80)
                        ? Xbig[((size_t)(s + 1) * 64 + row) * 4096 + g2 * 1024 + col]
                        : benc[g2 * 1024 + col];
            }
        }
        grid_barrier(bar, 256);
    }
}

// ---------------------------------------------------------------------------
// Persistent decoder: 80 warm-up + 80 decode. 256 blocks x 512 threads.
// Roles: Phase B (GEMM): (gg=bid>>6, cg=bid&63); Phases A'/C: (b=bid>>2, jc=bid&3).
// EW2 slice [80][256] resident in LDS for entire kernel (fence-immune).
// Logit partials computed in Phase C from register-resident h.
// ---------------------------------------------------------------------------
__launch_bounds__(512, 2)
__global__ void coop_dec(const unsigned short* __restrict__ WihcF,
                         const unsigned short* __restrict__ WhhF,
                         const float* __restrict__ W1,       // [80][2048] (h half = cols 0..1024)
                         const float* __restrict__ EW2,      // [80][64][1024]
                         const float* __restrict__ Xwarm,
                         const float* __restrict__ S_g,
                         const float* __restrict__ ctxS,
                         const float* __restrict__ S_log,
                         const float* __restrict__ enc_pad,
                         const float* __restrict__ prelu_w,
                         unsigned short* __restrict__ hfrag,  // 2 bufs
                         unsigned short* __restrict__ ctxfrag,
                         float* __restrict__ plog,            // [64][4][80]
                         float* __restrict__ h_all,
                         float* __restrict__ gsum,            // [4][64][1024]
                         unsigned* __restrict__ bar)
{
    __shared__ float EW2T[80 * 256];
    __shared__ float gred[8][1024];
    __shared__ float hq[256];
    __shared__ float wsm[80];
    __shared__ float rbuf[128];
    const int bid = blockIdx.x, tid = threadIdx.x;
    const int w = tid >> 6, lane = tid & 63;
    const int gg = bid >> 6, cg = bid & 63;
    const int wbase = gg * 64 + cg;
    const int kq = w;
    const int b = bid >> 2, jc = bid & 3;
    const float pw = prelu_w[0];
    float cstate = 0.f;

    // ---- weight slice: 8 kf x 3 planes = 96 VGPRs ----
    const unsigned short* Wsrc = (kq < 4) ? WihcF : WhhF;
    const int kfbase = (kq & 3) * 8;
    short8v wreg[24];
#pragma unroll
    for (int i = 0; i < 8; ++i) {
#pragma unroll
        for (int p = 0; p < 3; ++p)
            wreg[i * 3 + p] = *(const short8v*)&Wsrc[((size_t)(p * 256 + wbase) * 32 + kfbase + i) * 512 + lane * 8];
    }

    // ---- one-time EW2 slice -> LDS (80 KB, never invalidated) ----
    for (int i = tid; i < 80 * 256; i += 512) {
        int ss = i >> 8, j = i & 255;
        EW2T[i] = EW2[((size_t)ss * 64 + b) * 1024 + jc * 256 + j];
    }
    __syncthreads();

    for (int s = 0; s < 160; ++s) {
        unsigned short* hout = hfrag + ((s + 1) & 1) * 196608;
        const unsigned short* hf = hfrag + (s & 1) * 196608;
        const int t = s - 80;

        if (s >= 80) {
            // ---- Phase A': logits sum + softmax + f (from LDS) + ctx ----
            if (tid < 80) {
                float l4 = plog[(b * 4 + 0) * 80 + tid] + plog[(b * 4 + 1) * 80 + tid]
                         + plog[(b * 4 + 2) * 80 + tid] + plog[(b * 4 + 3) * 80 + tid];
                wsm[tid] = l4 + S_log[((size_t)t * 64 + b) * 80 + tid];
            }
            __syncthreads();
            float v = (tid < 80) ? wsm[tid] : -3.4e38f;
            if (tid < 128) rbuf[tid] = v;
            __syncthreads();
            for (int off = 64; off >= 1; off >>= 1) {
                if (tid < off) rbuf[tid] = fmaxf(rbuf[tid], rbuf[tid + off]);
                __syncthreads();
            }
            float mx = rbuf[0];
            __syncthreads();
            float e = (tid < 80) ? __expf(wsm[tid] - mx) : 0.f;
            if (tid < 128) rbuf[tid] = e;
            __syncthreads();
            for (int off = 64; off >= 1; off >>= 1) {
                if (tid < off) rbuf[tid] += rbuf[tid + off];
                __syncthreads();
            }
            float inv = 1.f / rbuf[0];
            __syncthreads();
            if (tid < 80) wsm[tid] = e * inv;
            __syncthreads();
            if (tid < 256) {
                float f = 0.f;
#pragma unroll 8
                for (int ss = 0; ss < 80; ++ss)
                    f = fmaf(wsm[ss], EW2T[ss * 256 + tid], f);
                int col = jc * 256 + tid;
                float val = f + ctxS[((size_t)t * 64 + b) * 1024 + col];
                val = (val >= 0.f) ? val : pw * val;
                val += enc_pad[((size_t)t * 64 + b) * 1024 + col];
                write_frag3(ctxfrag, 4, b, col, val);
            }
            grid_barrier(bar, 256);
        }

        // ---- prefetch Phase-C gate-adds (read-only) ----
        float pf[4];
        if (tid < 256) {
            const float* xb = (s < 80) ? (Xwarm + ((size_t)s * 64 + b) * 4096)
                                       : (S_g + ((size_t)t * 64 + b) * 4096);
            int col = jc * 256 + tid;
#pragma unroll
            for (int g2 = 0; g2 < 4; ++g2) pf[g2] = xb[g2 * 1024 + col];
        }

        // ---- Phase B: gate GEMM partials ----
        {
            f32x4 acc[4];
#pragma unroll
            for (int rg = 0; rg < 4; ++rg) acc[rg] = (f32x4){0.f,0.f,0.f,0.f};
            const bool active = (s >= 80) || (kq >= 4);
            if (active) {
                const unsigned short* asrc = (kq < 4) ? ctxfrag : hf;
#pragma unroll
                for (int i = 0; i < 8; ++i) {
                    int kfl = kfbase + i;
#pragma unroll
                    for (int rg = 0; rg < 4; ++rg) {
                        const unsigned short* ab = asrc + ((size_t)rg * 32 + kfl) * 512 + lane * 8;
                        short8v a0 = *(const short8v*)&ab[0];
                        short8v a1 = *(const short8v*)&ab[65536];
                        short8v a2 = *(const short8v*)&ab[131072];
                        short8v b0 = wreg[i * 3 + 0], b1 = wreg[i * 3 + 1], b2 = wreg[i * 3 + 2];
                        MFMA_(acc[rg], a0, b0); MFMA_(acc[rg], a0, b1); MFMA_(acc[rg], a1, b0);
                        MFMA_(acc[rg], a1, b1); MFMA_(acc[rg], a0, b2); MFMA_(acc[rg], a2, b0);
                    }
                }
            }
#pragma unroll
            for (int rg = 0; rg < 4; ++rg)
#pragma unroll
                for (int r = 0; r < 4; ++r)
                    gred[w][rg * 256 + lane * 4 + r] = acc[rg][r];
            __syncthreads();
#pragma unroll
            for (int e2 = 0; e2 < 2; ++e2) {
                int slot = tid * 2 + e2;
                int rg = slot >> 8, l = (slot >> 2) & 63, r = slot & 3;
                float sum = 0.f;
#pragma unroll
                for (int w2 = 0; w2 < 8; ++w2) sum += gred[w2][slot];
                int row = rg * 16 + (l >> 4) * 4 + r;
                int col = cg * 16 + (l & 15);
                gsum[((size_t)gg * 64 + row) * 1024 + col] = sum;
            }
        }
        grid_barrier(bar, 256);

        // ---- Phase C: pointwise gates + h-frag + logit partials ----
        if (tid < 256) {
            int col = jc * 256 + tid;
            float gv[4];
#pragma unroll
            for (int g2 = 0; g2 < 4; ++g2)
                gv[g2] = gsum[((size_t)g2 * 64 + b) * 1024 + col] + pf[g2];
            float cn = sigmf(gv[1]) * cstate + sigmf(gv[0]) * tanhf(gv[2]);
            float hn = sigmf(gv[3]) * tanhf(cn);
            cstate = cn;
            if (s >= 80) h_all[((size_t)t * 64 + b) * 1024 + col] = hn;
            write_frag3(hout, 4, b, col, hn);
            hq[tid] = hn;
        }
        __syncthreads();
        if (s >= 79) {
            // logit partials for next step: plog[b][jc][sx] = sum_k hq[k]*W1[sx][jc*256+k]
#pragma unroll
            for (int i = 0; i < 10; ++i) {
                int sx = w * 10 + i;
                float p = 0.f;
#pragma unroll
                for (int q = 0; q < 4; ++q)
                    p = fmaf(hq[lane + q * 64], W1[(size_t)sx * 2048 + jc * 256 + lane + q * 64], p);
#pragma unroll
                for (int off = 32; off; off >>= 1) p += __shfl_down(p, off, 64);
                if (lane == 0) plog[(b * 4 + jc) * 80 + sx] = p;
            }
        }
        grid_barrier(bar, 256);
    }
}

// ---------------------------------------------------------------------------
extern "C" void kernel_launch(void* const* d_in, const int* in_sizes, int n_in,
                              void* d_out, int out_size, void* d_ws, size_t ws_size,
                              hipStream_t stream)
{
    (void)in_sizes; (void)n_in; (void)out_size; (void)ws_size;

    const float* input_data     = (const float*)d_in[0];
    const float* correct_answer = (const float*)d_in[1];
    const float* enc_W_ih = (const float*)d_in[2];
    const float* enc_W_hh = (const float*)d_in[3];
    const float* enc_b_ih = (const float*)d_in[4];
    const float* enc_b_hh = (const float*)d_in[5];
    const float* dec_W_ih = (const float*)d_in[6];
    const float* dec_W_hh = (const float*)d_in[7];
    const float* dec_b_ih = (const float*)d_in[8];
    const float* dec_b_hh = (const float*)d_in[9];
    const float* in_emb_W = (const float*)d_in[10];
    const float* in_emb_b = (const float*)d_in[11];
    const float* out_emb_W = (const float*)d_in[12];
    const float* out_emb_b = (const float*)d_in[13];
    const float* att_W1 = (const float*)d_in[14];
    const float* att_b1 = (const float*)d_in[15];
    const float* att_W2 = (const float*)d_in[16];
    const float* att_b2 = (const float*)d_in[17];
    const float* prelu_w = (const float*)d_in[18];

    float* out = (float*)d_out;
    char* ws = (char*)d_ws;

    // ---- d_out scratch (102.4M floats; all reads precede final vocab GEMM) ----
    float* Xbig    = out;                      // [80][64][4096]  20.97M
    float* S_g     = out + 20971520;           // [80][64][4096]  20.97M
    float* ctxS    = out + 41943040;           // [80][64][1024]   5.24M
    float* S_log   = out + 47185920;           // [80][64][80]     0.41M
    float* samples = out + 47595520;           // [80][64][1024]   5.24M
    float* EW2     = out + 52838400;           // [80][64][1024]   5.24M
    unsigned short* WencF = (unsigned short*)(out + 58081280);
    unsigned short* WhhDF = (unsigned short*)(out + 64372736);
    unsigned short* WihcF = (unsigned short*)(out + 70664192);

    // ---- d_ws map ----
    size_t off = 0;
    auto alloc = [&](size_t nfloats) { float* p = (float*)(ws + off); off += nfloats * 4; return p; };
    float* enc_seq = alloc(80 * 64 * 1024);
    float* enc_pad = alloc(80 * 64 * 1024);
    float* h_all   = alloc(80 * 64 * 1024);
    float* benc    = alloc(4096);
    float* bdec    = alloc(4096);
    float* zb      = alloc(1024);
    float* hfragE_f = alloc(196608);
    float* hfragD_f = alloc(196608);
    float* ctxfrag_f= alloc(98304);
    float* plog     = alloc(64 * 4 * 80);
    float* gsum     = alloc(262144);
    float* bar_f    = alloc(8);
    unsigned short* hfragE  = (unsigned short*)hfragE_f;
    unsigned short* hfragD  = (unsigned short*)hfragD_f;
    unsigned short* ctxfrag = (unsigned short*)ctxfrag_f;
    unsigned* bar0 = (unsigned*)bar_f;
    unsigned* bar1 = ((unsigned*)bar_f) + 4;

    auto big3 = [&](const float* A, int lda, const float* W, int ldw,
                    float* C, int ldc, const float* bias, int M, int N, int K) {
        dim3 g((N + 127) / 128, (M + 127) / 128);
        hipLaunchKernelGGL((gemm_mfma_split<3>), g, dim3(256), 0, stream,
                           A, lda, W, ldw, C, ldc, bias, M, N, K);
    };

    // ---- setup ----
    hipLaunchKernelGGL(vec_add2, dim3(16), dim3(256), 0, stream, enc_b_ih, enc_b_hh, benc, 4096);
    hipLaunchKernelGGL(vec_add2, dim3(16), dim3(256), 0, stream, dec_b_ih, dec_b_hh, bdec, 4096);
    hipLaunchKernelGGL(zero_f, dim3(4), dim3(256), 0, stream, zb, 1024);
    hipLaunchKernelGGL(zero_f, dim3(768), dim3(256), 0, stream, hfragE_f, 196608);
    hipLaunchKernelGGL(zero_f, dim3(768), dim3(256), 0, stream, hfragD_f, 196608);
    hipLaunchKernelGGL(zero_f, dim3(1), dim3(256), 0, stream, bar_f, 8);

    // ---- weight frag rearranges ----
    hipLaunchKernelGGL(rearr_frag, dim3(2048), dim3(256), 0, stream, enc_W_hh, 1024, 0, WencF, 4096, 1024);
    hipLaunchKernelGGL(rearr_frag, dim3(2048), dim3(256), 0, stream, dec_W_hh, 1024, 0, WhhDF, 4096, 1024);
    hipLaunchKernelGGL(rearr_frag, dim3(2048), dim3(256), 0, stream, dec_W_ih, 2048, 1024, WihcF, 4096, 1024);

    // ---- batched big GEMMs (NS=3, feed recurrences) ----
    big3(input_data, 4096, enc_W_ih, 4096, Xbig, 4096, benc, 5120, 4096, 4096);
    hipLaunchKernelGGL(sample0_fill, dim3(256), dim3(256), 0, stream, in_emb_W, in_emb_b, samples);
    big3(correct_answer + (size_t)64 * 20000, 20000, in_emb_W, 20000,
         samples + 65536, 1024, in_emb_b, 5056, 1024, 20000);
    big3(samples, 1024, dec_W_ih, 2048, S_g, 4096, bdec, 5120, 4096, 1024);
    big3(samples, 1024, att_W2, 2048, ctxS, 1024, att_b2, 5120, 1024, 1024);
    big3(samples, 1024, att_W1 + 1024, 2048, S_log, 80, att_b1, 5120, 80, 1024);

    // ---- persistent encoder (160 steps) ----
    hipLaunchKernelGGL(coop_enc, dim3(256), dim3(512), 0, stream,
                       WencF, Xbig, benc, hfragE, enc_seq, enc_pad, bar0);

    // ---- post-encoder projections: warm-up input + EW2 (linear attn fold) ----
    big3(enc_seq, 1024, dec_W_ih, 2048, Xbig, 4096, bdec, 5120, 4096, 1024);
    big3(enc_seq, 1024, att_W2 + 1024, 2048, EW2, 1024, zb, 5120, 1024, 1024);

    // ---- persistent decoder (80 warm-up + 80 decode) ----
    hipLaunchKernelGGL(coop_dec, dim3(256), dim3(512), 0, stream,
                       WihcF, WhhDF, att_W1, EW2, Xbig, S_g, ctxS, S_log,
                       enc_pad, prelu_w, hfragD, ctxfrag, plog, h_all, gsum, bar1);

    // ---- final vocab projection (NS=1, output-facing) ----
    {
        dim3 g((20000 + 127) / 128, (5120 + 127) / 128);
        hipLaunchKernelGGL((gemm_mfma_split<1>), g, dim3(256), 0, stream,
                           h_all, 1024, out_emb_W, 1024, out, 20000, out_emb_b, 5120, 20000, 1024);
    }
}

// Round 10
// 18540.617 us; speedup vs baseline: 2.8328x; 1.2969x over previous
//
#include <hip/hip_runtime.h>
#include <cstddef>
#include <cstdint>

typedef __attribute__((ext_vector_type(8))) short short8v;
typedef __attribute__((ext_vector_type(4))) float f32x4;

__device__ __forceinline__ float sigmf(float x) { return 1.0f / (1.0f + __expf(-x)); }

__device__ __forceinline__ unsigned short bf16_rn(float x) {
    union { float f; unsigned u; } v; v.f = x;
    unsigned r = v.u + 0x7FFF + ((v.u >> 16) & 1);
    return (unsigned short)(r >> 16);
}
__device__ __forceinline__ float bf16_to_f(unsigned short h) {
    union { unsigned u; float f; } v; v.u = ((unsigned)h) << 16; return v.f;
}
__device__ __forceinline__ unsigned long long pack4(unsigned short a, unsigned short b,
                                                    unsigned short c, unsigned short d) {
    return (unsigned long long)a | ((unsigned long long)b << 16)
         | ((unsigned long long)c << 32) | ((unsigned long long)d << 48);
}

#define MFMA_(d, va, vb) d = __builtin_amdgcn_mfma_f32_16x16x32_bf16(va, vb, d, 0, 0, 0)

#define AT_LD(p)      __hip_atomic_load((p), __ATOMIC_RELAXED, __HIP_MEMORY_SCOPE_AGENT)
#define AT_ST(p, v)   __hip_atomic_store((p), (v), __ATOMIC_RELAXED, __HIP_MEMORY_SCOPE_AGENT)
#define AT_ST_REL(p, v) __hip_atomic_store((p), (v), __ATOMIC_RELEASE, __HIP_MEMORY_SCOPE_AGENT)
#define AT_ADD(p, v)  __hip_atomic_fetch_add((p), (v), __ATOMIC_RELAXED, __HIP_MEMORY_SCOPE_AGENT)

// ---------------------------------------------------------------------------
// Fragment layout (A and W): F[p][rgw][kf][l][e]; rgw=r>>4, kf=k>>5,
// l=((k>>3)&3)*16+(r&15), e=k&7. Per-(p,rgw) chunk = 32*64*8 = 16384 shorts.
// ---------------------------------------------------------------------------
__device__ __forceinline__ void write_frag3(unsigned short* __restrict__ dst, int NRGW,
                                            int r, int k, float x)
{
    unsigned short hi = bf16_rn(x); float r1 = x - bf16_to_f(hi);
    unsigned short md = bf16_rn(r1);
    unsigned short lo = bf16_rn(r1 - bf16_to_f(md));
    int base = (((r >> 4) * 32 + (k >> 5)) * 64 + ((k >> 3) & 3) * 16 + (r & 15)) * 8 + (k & 7);
    int ps = NRGW * 16384;
    dst[base] = hi; dst[ps + base] = md; dst[2 * ps + base] = lo;
}

__launch_bounds__(256)
__global__ void rearr_frag(const float* __restrict__ src, int ld, int c0,
                           unsigned short* __restrict__ dst, int R, int K)
{
    int idx = blockIdx.x * 256 + threadIdx.x;
    int kpr = K >> 3;
    if (idx >= R * kpr) return;
    int r = idx / kpr, k = (idx % kpr) * 8;
    int NRGW = R >> 4;
    const float* s = src + (size_t)r * ld + c0 + k;
    float4 v0 = *(const float4*)s, v1 = *(const float4*)(s + 4);
    float xs[8] = {v0.x, v0.y, v0.z, v0.w, v1.x, v1.y, v1.z, v1.w};
    unsigned short hi[8], md[8], lo[8];
#pragma unroll
    for (int e = 0; e < 8; ++e) {
        hi[e] = bf16_rn(xs[e]); float r1 = xs[e] - bf16_to_f(hi[e]);
        md[e] = bf16_rn(r1);
        lo[e] = bf16_rn(r1 - bf16_to_f(md[e]));
    }
    int base = (((r >> 4) * 32 + (k >> 5)) * 64 + ((k >> 3) & 3) * 16 + (r & 15)) * 8;
    size_t ps = (size_t)NRGW * 16384;
    *(unsigned long long*)&dst[base]          = pack4(hi[0], hi[1], hi[2], hi[3]);
    *(unsigned long long*)&dst[base + 4]      = pack4(hi[4], hi[5], hi[6], hi[7]);
    *(unsigned long long*)&dst[ps + base]     = pack4(md[0], md[1], md[2], md[3]);
    *(unsigned long long*)&dst[ps + base + 4] = pack4(md[4], md[5], md[6], md[7]);
    *(unsigned long long*)&dst[2*ps + base]     = pack4(lo[0], lo[1], lo[2], lo[3]);
    *(unsigned long long*)&dst[2*ps + base + 4] = pack4(lo[4], lo[5], lo[6], lo[7]);
}

// ---------------------------------------------------------------------------
// Two-level tree grid barrier: 8 groups x 32 blocks. Per-group arrive counter
// on its own 128B line (32-way RMW contention, not 256), leaders join an
// 8-way root, release fans out root-gen -> group-gen -> members.
// bar layout (unsigned): grp g count at g*32, gen at g*32+1; root at 8*32/+1.
// ---------------------------------------------------------------------------
__device__ __forceinline__ void grid_barrier(unsigned* bar, int nblk)
{
    (void)nblk;
    __syncthreads();
    if (threadIdx.x == 0) {
        const int g = blockIdx.x >> 5;          // 32 blocks per group
        unsigned* gcnt = bar + g * 32;
        unsigned* ggen = bar + g * 32 + 1;
        unsigned* rcnt = bar + 8 * 32;
        unsigned* rgen = bar + 8 * 32 + 1;
        __threadfence();   // release: write back this block's stores
        unsigned mygen = AT_LD(ggen);
        unsigned prev = AT_ADD(gcnt, 1u);
        if (prev == 31u) {                      // group leader
            AT_ST(gcnt, 0u);
            unsigned rg = AT_LD(rgen);
            unsigned rprev = AT_ADD(rcnt, 1u);
            if (rprev == 7u) {                  // root leader
                AT_ST(rcnt, 0u);
                AT_ST_REL(rgen, rg + 1u);
            } else {
                while (AT_LD(rgen) == rg) __builtin_amdgcn_s_sleep(4);
            }
            AT_ST_REL(ggen, mygen + 1u);
        } else {
            while (AT_LD(ggen) == mygen) __builtin_amdgcn_s_sleep(4);
        }
        __threadfence();   // acquire: invalidate stale cache lines once
    }
    __syncthreads();
}

// ---------------------------------------------------------------------------
// Batched fp32 GEMM via bf16-split MFMA (validated R3): C = A@W^T + bias.
// ---------------------------------------------------------------------------
template <int NS>
__launch_bounds__(256, 2)
__global__ void gemm_mfma_split(const float* __restrict__ A, int lda,
                                const float* __restrict__ W, int ldw,
                                float* __restrict__ C, int ldc,
                                const float* __restrict__ bias,
                                int M, int N, int K)
{
    __shared__ unsigned short Abf[NS][128][40];
    __shared__ unsigned short Bbf[NS][128][40];
    const int tid = threadIdx.x;
    const int m0 = blockIdx.y * 128, n0 = blockIdx.x * 128;
    const int wave = tid >> 6, lane = tid & 63;
    const int wr = wave >> 1, wc = wave & 1;
    const int lr = lane & 15, lk = (lane >> 4) * 8;

    f32x4 acc[4][4];
#pragma unroll
    for (int i = 0; i < 4; ++i)
#pragma unroll
        for (int j = 0; j < 4; ++j) acc[i][j] = (f32x4){0.f, 0.f, 0.f, 0.f};

    const int arow = tid >> 1;
    const int akh  = (tid & 1) * 16;
    int gr = m0 + arow; if (gr > M - 1) gr = M - 1;
    int gn = n0 + arow; if (gn > N - 1) gn = N - 1;
    const float* aptr = A + (size_t)gr * lda + akh;
    const float* wptr = W + (size_t)gn * ldw + akh;

    for (int k0 = 0; k0 < K; k0 += 32) {
#pragma unroll
        for (int q = 0; q < 4; ++q) {
            float4 v = *(const float4*)(aptr + k0 + q * 4);
            float xs[4] = {v.x, v.y, v.z, v.w};
            unsigned short h[4], hm[4], hl[4];
#pragma unroll
            for (int e = 0; e < 4; ++e) {
                h[e] = bf16_rn(xs[e]);
                if (NS == 3) {
                    float r1 = xs[e] - bf16_to_f(h[e]);
                    hm[e] = bf16_rn(r1);
                    hl[e] = bf16_rn(r1 - bf16_to_f(hm[e]));
                }
            }
            *(unsigned long long*)&Abf[0][arow][akh + q * 4] = pack4(h[0], h[1], h[2], h[3]);
            if (NS == 3) {
                *(unsigned long long*)&Abf[1][arow][akh + q * 4] = pack4(hm[0], hm[1], hm[2], hm[3]);
                *(unsigned long long*)&Abf[2][arow][akh + q * 4] = pack4(hl[0], hl[1], hl[2], hl[3]);
            }
        }
#pragma unroll
        for (int q = 0; q < 4; ++q) {
            float4 v = *(const float4*)(wptr + k0 + q * 4);
            float xs[4] = {v.x, v.y, v.z, v.w};
            unsigned short h[4], hm[4], hl[4];
#pragma unroll
            for (int e = 0; e < 4; ++e) {
                h[e] = bf16_rn(xs[e]);
                if (NS == 3) {
                    float r1 = xs[e] - bf16_to_f(h[e]);
                    hm[e] = bf16_rn(r1);
                    hl[e] = bf16_rn(r1 - bf16_to_f(hm[e]));
                }
            }
            *(unsigned long long*)&Bbf[0][arow][akh + q * 4] = pack4(h[0], h[1], h[2], h[3]);
            if (NS == 3) {
                *(unsigned long long*)&Bbf[1][arow][akh + q * 4] = pack4(hm[0], hm[1], hm[2], hm[3]);
                *(unsigned long long*)&Bbf[2][arow][akh + q * 4] = pack4(hl[0], hl[1], hl[2], hl[3]);
            }
        }
        __syncthreads();

        short8v a[NS][4], b[4];
#pragma unroll
        for (int p = 0; p < NS; ++p)
#pragma unroll
            for (int i = 0; i < 4; ++i)
                a[p][i] = *(const short8v*)&Abf[p][wr * 64 + i * 16 + lr][lk];
#pragma unroll
        for (int q = 0; q < NS; ++q) {
#pragma unroll
            for (int j = 0; j < 4; ++j)
                b[j] = *(const short8v*)&Bbf[q][wc * 64 + j * 16 + lr][lk];
            const int pmax = (NS == 1) ? 1 : (3 - q);
#pragma unroll
            for (int p = 0; p < 3; ++p) {
                if (p >= pmax) break;
#pragma unroll
                for (int i = 0; i < 4; ++i)
#pragma unroll
                    for (int j = 0; j < 4; ++j)
                        acc[i][j] = __builtin_amdgcn_mfma_f32_16x16x32_bf16(
                            a[p][i], b[j], acc[i][j], 0, 0, 0);
            }
        }
        __syncthreads();
    }

    const int crow = (lane >> 4) * 4;
#pragma unroll
    for (int i = 0; i < 4; ++i) {
        int mbase = m0 + wr * 64 + i * 16 + crow;
#pragma unroll
        for (int j = 0; j < 4; ++j) {
            int n = n0 + wc * 64 + j * 16 + lr;
            if (n < N) {
                float bv = bias[n];
#pragma unroll
                for (int r = 0; r < 4; ++r) {
                    int m = mbase + r;
                    if (m < M) C[(size_t)m * ldc + n] = acc[i][j][r] + bv;
                }
            }
        }
    }
}

__launch_bounds__(256)
__global__ void zero_f(float* __restrict__ p, int n)
{
    int i = blockIdx.x * 256 + threadIdx.x;
    if (i < n) p[i] = 0.f;
}

__launch_bounds__(256)
__global__ void vec_add2(const float* __restrict__ a, const float* __restrict__ b,
                         float* __restrict__ o, int n)
{
    int i = blockIdx.x * 256 + threadIdx.x;
    if (i < n) o[i] = a[i] + b[i];
}

__launch_bounds__(256)
__global__ void sample0_fill(const float* __restrict__ emW, const float* __restrict__ emb,
                             float* __restrict__ samples)
{
    int idx = blockIdx.x * 256 + threadIdx.x; // 65536
    int d = idx & 1023;
    samples[idx] = emW[(size_t)d * 20000 + 19998] + emb[d];
}

// stage one rg-chunk (96KB) of a 64-row frag buffer into LDS
__device__ __forceinline__ void stage_A(unsigned short* __restrict__ LDSA,
                                        const unsigned short* __restrict__ src,
                                        int rg, int tid)
{
#pragma unroll
    for (int p = 0; p < 3; ++p) {
        const unsigned short* sp = src + (size_t)(p * 4 + rg) * 16384;
        unsigned short* dp = LDSA + p * 16384;
#pragma unroll
        for (int it = 0; it < 4; ++it) {
            int idx = tid + it * 512;
            *(short8v*)&dp[idx * 8] = *(const short8v*)&sp[idx * 8];
        }
    }
}

// ---------------------------------------------------------------------------
// Persistent encoder: 160 steps, 256 blocks x 512 threads. Weights in VGPRs,
// Xbig/benc gate-adds prefetched to registers across the barrier.
// ---------------------------------------------------------------------------
__launch_bounds__(512, 2)
__global__ void coop_enc(const unsigned short* __restrict__ WencF,
                         const float* __restrict__ Xbig,
                         const float* __restrict__ benc,
                         unsigned short* __restrict__ hfrag,   // 2 bufs x 196608
                         float* __restrict__ enc_seq,
                         float* __restrict__ enc_pad,
                         unsigned* __restrict__ bar)
{
    __shared__ unsigned short LDSA[3 * 16384];
    __shared__ float gbuf[8][16][16];
    const int bid = blockIdx.x, tid = threadIdx.x;
    const int w = tid >> 6, lane = tid & 63;
    const int g = w & 3, kh = w >> 2;
    const int rg = bid >> 6, cg = bid & 63;
    const int wbase = g * 64 + cg;
    const int r_l = (tid & 255) >> 4, c_l = tid & 15;
    const int row = rg * 16 + r_l, col = cg * 16 + c_l;
    float cstate = 0.f;

    short8v wreg[48];
#pragma unroll
    for (int i = 0; i < 16; ++i) {
        int kf = kh * 16 + i;
#pragma unroll
        for (int p = 0; p < 3; ++p)
            wreg[i * 3 + p] = *(const short8v*)&WencF[((size_t)(p * 256 + wbase) * 32 + kf) * 512 + lane * 8];
    }

    float pf[4];
    if (tid < 256) {
#pragma unroll
        for (int g2 = 0; g2 < 4; ++g2)
            pf[g2] = Xbig[((size_t)0 * 64 + row) * 4096 + g2 * 1024 + col];
    }

    for (int s = 0; s < 160; ++s) {
        const unsigned short* hf = hfrag + (s & 1) * 196608;
        stage_A(LDSA, hf, rg, tid);
        __syncthreads();

        f32x4 acc0 = (f32x4){0.f,0.f,0.f,0.f}, acc1 = acc0;
#pragma unroll
        for (int i = 0; i < 16; ++i) {
            int kf = kh * 16 + i;
            short8v a0 = *(const short8v*)&LDSA[(kf * 64 + lane) * 8];
            short8v a1 = *(const short8v*)&LDSA[16384 + (kf * 64 + lane) * 8];
            short8v a2 = *(const short8v*)&LDSA[32768 + (kf * 64 + lane) * 8];
            short8v b0 = wreg[i * 3 + 0], b1 = wreg[i * 3 + 1], b2 = wreg[i * 3 + 2];
            f32x4& A = (i & 1) ? acc1 : acc0;
            MFMA_(A, a0, b0); MFMA_(A, a0, b1); MFMA_(A, a1, b0);
            MFMA_(A, a1, b1); MFMA_(A, a0, b2); MFMA_(A, a2, b0);
        }
        acc0 += acc1;
#pragma unroll
        for (int r = 0; r < 4; ++r)
            gbuf[w][(lane >> 4) * 4 + r][lane & 15] = acc0[r];
        __syncthreads();

        if (tid < 256) {
            float gv[4];
#pragma unroll
            for (int g2 = 0; g2 < 4; ++g2)
                gv[g2] = gbuf[g2][r_l][c_l] + gbuf[4 + g2][r_l][c_l] + pf[g2];
            float cn = sigmf(gv[1]) * cstate + sigmf(gv[0]) * tanhf(gv[2]);
            float hn = sigmf(gv[3]) * tanhf(cn);
            cstate = cn;
            float* st = (s < 80) ? (enc_seq + (size_t)s * 65536)
                                 : (enc_pad + (size_t)(s - 80) * 65536);
            st[row * 1024 + col] = hn;
            write_frag3(hfrag + ((s + 1) & 1) * 196608, 4, row, col, hn);
            if (s + 1 < 160) {
#pragma unroll
                for (int g2 = 0; g2 < 4; ++g2)
                    pf[g2] = (s + 1 < 80)
                        ? Xbig[((size_t)(s + 1) * 64 + row) * 4096 + g2 * 1024 + col]
                        : benc[g2 * 1024 + col];
            }
        }
        grid_barrier(bar, 256);
    }
}

// ---------------------------------------------------------------------------
// Persistent decoder: 80 warm-up + 80 decode. 256 blocks x 512 threads.
// Roles: Phase B (GEMM): (gg=bid>>6, cg=bid&63); Phases A'/C: (b=bid>>2, jc=bid&3).
// EW2 slice [80][256] resident in LDS for entire kernel (fence-immune).
// Logit partials computed in Phase C from register-resident h.
// ---------------------------------------------------------------------------
__launch_bounds__(512, 2)
__global__ void coop_dec(const unsigned short* __restrict__ WihcF,
                         const unsigned short* __restrict__ WhhF,
                         const float* __restrict__ W1,       // [80][2048] (h half = cols 0..1024)
                         const float* __restrict__ EW2,      // [80][64][1024]
                         const float* __restrict__ Xwarm,
                         const float* __restrict__ S_g,
                         const float* __restrict__ ctxS,
                         const float* __restrict__ S_log,
                         const float* __restrict__ enc_pad,
                         const float* __restrict__ prelu_w,
                         unsigned short* __restrict__ hfrag,  // 2 bufs
                         unsigned short* __restrict__ ctxfrag,
                         float* __restrict__ plog,            // [64][4][80]
                         float* __restrict__ h_all,
                         float* __restrict__ gsum,            // [4][64][1024]
                         unsigned* __restrict__ bar)
{
    __shared__ float EW2T[80 * 256];
    __shared__ float gred[8][1024];
    __shared__ float hq[256];
    __shared__ float wsm[80];
    __shared__ float rbuf[128];
    const int bid = blockIdx.x, tid = threadIdx.x;
    const int w = tid >> 6, lane = tid & 63;
    const int gg = bid >> 6, cg = bid & 63;
    const int wbase = gg * 64 + cg;
    const int kq = w;
    const int b = bid >> 2, jc = bid & 3;
    const float pw = prelu_w[0];
    float cstate = 0.f;

    const unsigned short* Wsrc = (kq < 4) ? WihcF : WhhF;
    const int kfbase = (kq & 3) * 8;
    short8v wreg[24];
#pragma unroll
    for (int i = 0; i < 8; ++i) {
#pragma unroll
        for (int p = 0; p < 3; ++p)
            wreg[i * 3 + p] = *(const short8v*)&Wsrc[((size_t)(p * 256 + wbase) * 32 + kfbase + i) * 512 + lane * 8];
    }

    for (int i = tid; i < 80 * 256; i += 512) {
        int ss = i >> 8, j = i & 255;
        EW2T[i] = EW2[((size_t)ss * 64 + b) * 1024 + jc * 256 + j];
    }
    __syncthreads();

    for (int s = 0; s < 160; ++s) {
        unsigned short* hout = hfrag + ((s + 1) & 1) * 196608;
        const unsigned short* hf = hfrag + (s & 1) * 196608;
        const int t = s - 80;

        if (s >= 80) {
            // ---- Phase A': logits sum + softmax + f (from LDS) + ctx ----
            if (tid < 80) {
                float l4 = plog[(b * 4 + 0) * 80 + tid] + plog[(b * 4 + 1) * 80 + tid]
                         + plog[(b * 4 + 2) * 80 + tid] + plog[(b * 4 + 3) * 80 + tid];
                wsm[tid] = l4 + S_log[((size_t)t * 64 + b) * 80 + tid];
            }
            __syncthreads();
            float v = (tid < 80) ? wsm[tid] : -3.4e38f;
            if (tid < 128) rbuf[tid] = v;
            __syncthreads();
            for (int off = 64; off >= 1; off >>= 1) {
                if (tid < off) rbuf[tid] = fmaxf(rbuf[tid], rbuf[tid + off]);
                __syncthreads();
            }
            float mx = rbuf[0];
            __syncthreads();
            float e = (tid < 80) ? __expf(wsm[tid] - mx) : 0.f;
            if (tid < 128) rbuf[tid] = e;
            __syncthreads();
            for (int off = 64; off >= 1; off >>= 1) {
                if (tid < off) rbuf[tid] += rbuf[tid + off];
                __syncthreads();
            }
            float inv = 1.f / rbuf[0];
            __syncthreads();
            if (tid < 80) wsm[tid] = e * inv;
            __syncthreads();
            if (tid < 256) {
                float f = 0.f;
#pragma unroll 8
                for (int ss = 0; ss < 80; ++ss)
                    f = fmaf(wsm[ss], EW2T[ss * 256 + tid], f);
                int col = jc * 256 + tid;
                float val = f + ctxS[((size_t)t * 64 + b) * 1024 + col];
                val = (val >= 0.f) ? val : pw * val;
                val += enc_pad[((size_t)t * 64 + b) * 1024 + col];
                write_frag3(ctxfrag, 4, b, col, val);
            }
            grid_barrier(bar, 256);
        }

        // ---- prefetch Phase-C gate-adds (read-only) ----
        float pf[4];
        if (tid < 256) {
            const float* xb = (s < 80) ? (Xwarm + ((size_t)s * 64 + b) * 4096)
                                       : (S_g + ((size_t)t * 64 + b) * 4096);
            int col = jc * 256 + tid;
#pragma unroll
            for (int g2 = 0; g2 < 4; ++g2) pf[g2] = xb[g2 * 1024 + col];
        }

        // ---- Phase B: gate GEMM partials ----
        {
            f32x4 acc[4];
#pragma unroll
            for (int rg = 0; rg < 4; ++rg) acc[rg] = (f32x4){0.f,0.f,0.f,0.f};
            const bool active = (s >= 80) || (kq >= 4);
            if (active) {
                const unsigned short* asrc = (kq < 4) ? ctxfrag : hf;
#pragma unroll
                for (int i = 0; i < 8; ++i) {
                    int kfl = kfbase + i;
#pragma unroll
                    for (int rg = 0; rg < 4; ++rg) {
                        const unsigned short* ab = asrc + ((size_t)rg * 32 + kfl) * 512 + lane * 8;
                        short8v a0 = *(const short8v*)&ab[0];
                        short8v a1 = *(const short8v*)&ab[65536];
                        short8v a2 = *(const short8v*)&ab[131072];
                        short8v b0 = wreg[i * 3 + 0], b1 = wreg[i * 3 + 1], b2 = wreg[i * 3 + 2];
                        MFMA_(acc[rg], a0, b0); MFMA_(acc[rg], a0, b1); MFMA_(acc[rg], a1, b0);
                        MFMA_(acc[rg], a1, b1); MFMA_(acc[rg], a0, b2); MFMA_(acc[rg], a2, b0);
                    }
                }
            }
#pragma unroll
            for (int rg = 0; rg < 4; ++rg)
#pragma unroll
                for (int r = 0; r < 4; ++r)
                    gred[w][rg * 256 + lane * 4 + r] = acc[rg][r];
            __syncthreads();
#pragma unroll
            for (int e2 = 0; e2 < 2; ++e2) {
                int slot = tid * 2 + e2;
                int rg = slot >> 8, l = (slot >> 2) & 63, r = slot & 3;
                float sum = 0.f;
#pragma unroll
                for (int w2 = 0; w2 < 8; ++w2) sum += gred[w2][slot];
                int row = rg * 16 + (l >> 4) * 4 + r;
                int col = cg * 16 + (l & 15);
                gsum[((size_t)gg * 64 + row) * 1024 + col] = sum;
            }
        }
        grid_barrier(bar, 256);

        // ---- Phase C: pointwise gates + h-frag + logit partials ----
        if (tid < 256) {
            int col = jc * 256 + tid;
            float gv[4];
#pragma unroll
            for (int g2 = 0; g2 < 4; ++g2)
                gv[g2] = gsum[((size_t)g2 * 64 + b) * 1024 + col] + pf[g2];
            float cn = sigmf(gv[1]) * cstate + sigmf(gv[0]) * tanhf(gv[2]);
            float hn = sigmf(gv[3]) * tanhf(cn);
            cstate = cn;
            if (s >= 80) h_all[((size_t)t * 64 + b) * 1024 + col] = hn;
            write_frag3(hout, 4, b, col, hn);
            hq[tid] = hn;
        }
        __syncthreads();
        if (s >= 79) {
#pragma unroll
            for (int i = 0; i < 10; ++i) {
                int sx = w * 10 + i;
                float p = 0.f;
#pragma unroll
                for (int q = 0; q < 4; ++q)
                    p = fmaf(hq[lane + q * 64], W1[(size_t)sx * 2048 + jc * 256 + lane + q * 64], p);
#pragma unroll
                for (int off = 32; off; off >>= 1) p += __shfl_down(p, off, 64);
                if (lane == 0) plog[(b * 4 + jc) * 80 + sx] = p;
            }
        }
        grid_barrier(bar, 256);
    }
}

// ---------------------------------------------------------------------------
extern "C" void kernel_launch(void* const* d_in, const int* in_sizes, int n_in,
                              void* d_out, int out_size, void* d_ws, size_t ws_size,
                              hipStream_t stream)
{
    (void)in_sizes; (void)n_in; (void)out_size; (void)ws_size;

    const float* input_data     = (const float*)d_in[0];
    const float* correct_answer = (const float*)d_in[1];
    const float* enc_W_ih = (const float*)d_in[2];
    const float* enc_W_hh = (const float*)d_in[3];
    const float* enc_b_ih = (const float*)d_in[4];
    const float* enc_b_hh = (const float*)d_in[5];
    const float* dec_W_ih = (const float*)d_in[6];
    const float* dec_W_hh = (const float*)d_in[7];
    const float* dec_b_ih = (const float*)d_in[8];
    const float* dec_b_hh = (const float*)d_in[9];
    const float* in_emb_W = (const float*)d_in[10];
    const float* in_emb_b = (const float*)d_in[11];
    const float* out_emb_W = (const float*)d_in[12];
    const float* out_emb_b = (const float*)d_in[13];
    const float* att_W1 = (const float*)d_in[14];
    const float* att_b1 = (const float*)d_in[15];
    const float* att_W2 = (const float*)d_in[16];
    const float* att_b2 = (const float*)d_in[17];
    const float* prelu_w = (const float*)d_in[18];

    float* out = (float*)d_out;
    char* ws = (char*)d_ws;

    // ---- d_out scratch (102.4M floats; all reads precede final vocab GEMM) ----
    float* Xbig    = out;                      // [80][64][4096]  20.97M
    float* S_g     = out + 20971520;           // [80][64][4096]  20.97M
    float* ctxS    = out + 41943040;           // [80][64][1024]   5.24M
    float* S_log   = out + 47185920;           // [80][64][80]     0.41M
    float* samples = out + 47595520;           // [80][64][1024]   5.24M
    float* EW2     = out + 52838400;           // [80][64][1024]   5.24M
    unsigned short* WencF = (unsigned short*)(out + 58081280);
    unsigned short* WhhDF = (unsigned short*)(out + 64372736);
    unsigned short* WihcF = (unsigned short*)(out + 70664192);

    // ---- d_ws map ----
    size_t off = 0;
    auto alloc = [&](size_t nfloats) { float* p = (float*)(ws + off); off += nfloats * 4; return p; };
    float* enc_seq = alloc(80 * 64 * 1024);
    float* enc_pad = alloc(80 * 64 * 1024);
    float* h_all   = alloc(80 * 64 * 1024);
    float* benc    = alloc(4096);
    float* bdec    = alloc(4096);
    float* zb      = alloc(1024);
    float* hfragE_f = alloc(196608);
    float* hfragD_f = alloc(196608);
    float* ctxfrag_f= alloc(98304);
    float* plog     = alloc(64 * 4 * 80);
    float* gsum     = alloc(262144);
    float* bar_f    = alloc(1024);     // 2 tree-barrier states (258 u32 each, padded)
    unsigned short* hfragE  = (unsigned short*)hfragE_f;
    unsigned short* hfragD  = (unsigned short*)hfragD_f;
    unsigned short* ctxfrag = (unsigned short*)ctxfrag_f;
    unsigned* bar0 = (unsigned*)bar_f;
    unsigned* bar1 = ((unsigned*)bar_f) + 512;

    auto big3 = [&](const float* A, int lda, const float* W, int ldw,
                    float* C, int ldc, const float* bias, int M, int N, int K) {
        dim3 g((N + 127) / 128, (M + 127) / 128);
        hipLaunchKernelGGL((gemm_mfma_split<3>), g, dim3(256), 0, stream,
                           A, lda, W, ldw, C, ldc, bias, M, N, K);
    };

    // ---- setup ----
    hipLaunchKernelGGL(vec_add2, dim3(16), dim3(256), 0, stream, enc_b_ih, enc_b_hh, benc, 4096);
    hipLaunchKernelGGL(vec_add2, dim3(16), dim3(256), 0, stream, dec_b_ih, dec_b_hh, bdec, 4096);
    hipLaunchKernelGGL(zero_f, dim3(4), dim3(256), 0, stream, zb, 1024);
    hipLaunchKernelGGL(zero_f, dim3(768), dim3(256), 0, stream, hfragE_f, 196608);
    hipLaunchKernelGGL(zero_f, dim3(768), dim3(256), 0, stream, hfragD_f, 196608);
    hipLaunchKernelGGL(zero_f, dim3(4), dim3(256), 0, stream, bar_f, 1024);

    // ---- weight frag rearranges ----
    hipLaunchKernelGGL(rearr_frag, dim3(2048), dim3(256), 0, stream, enc_W_hh, 1024, 0, WencF, 4096, 1024);
    hipLaunchKernelGGL(rearr_frag, dim3(2048), dim3(256), 0, stream, dec_W_hh, 1024, 0, WhhDF, 4096, 1024);
    hipLaunchKernelGGL(rearr_frag, dim3(2048), dim3(256), 0, stream, dec_W_ih, 2048, 1024, WihcF, 4096, 1024);

    // ---- batched big GEMMs (NS=3, feed recurrences) ----
    big3(input_data, 4096, enc_W_ih, 4096, Xbig, 4096, benc, 5120, 4096, 4096);
    hipLaunchKernelGGL(sample0_fill, dim3(256), dim3(256), 0, stream, in_emb_W, in_emb_b, samples);
    big3(correct_answer + (size_t)64 * 20000, 20000, in_emb_W, 20000,
         samples + 65536, 1024, in_emb_b, 5056, 1024, 20000);
    big3(samples, 1024, dec_W_ih, 2048, S_g, 4096, bdec, 5120, 4096, 1024);
    big3(samples, 1024, att_W2, 2048, ctxS, 1024, att_b2, 5120, 1024, 1024);
    big3(samples, 1024, att_W1 + 1024, 2048, S_log, 80, att_b1, 5120, 80, 1024);

    // ---- persistent encoder (160 steps) ----
    hipLaunchKernelGGL(coop_enc, dim3(256), dim3(512), 0, stream,
                       WencF, Xbig, benc, hfragE, enc_seq, enc_pad, bar0);

    // ---- post-encoder projections: warm-up input + EW2 (linear attn fold) ----
    big3(enc_seq, 1024, dec_W_ih, 2048, Xbig, 4096, bdec, 5120, 4096, 1024);
    big3(enc_seq, 1024, att_W2 + 1024, 2048, EW2, 1024, zb, 5120, 1024, 1024);

    // ---- persistent decoder (80 warm-up + 80 decode) ----
    hipLaunchKernelGGL(coop_dec, dim3(256), dim3(512), 0, stream,
                       WihcF, WhhDF, att_W1, EW2, Xbig, S_g, ctxS, S_log,
                       enc_pad, prelu_w, hfragD, ctxfrag, plog, h_all, gsum, bar1);

    // ---- final vocab projection (NS=1, output-facing) ----
    {
        dim3 g((20000 + 127) / 128, (5120 + 127) / 128);
        hipLaunchKernelGGL((gemm_mfma_split<1>), g, dim3(256), 0, stream,
                           h_all, 1024, out_emb_W, 1024, out, 20000, out_emb_b, 5120, 20000, 1024);
    }
}

// Round 11
// 15000.580 us; speedup vs baseline: 3.5013x; 1.2360x over previous
//
#include <hip/hip_runtime.h>
#include <cstddef>
#include <cstdint>

typedef __attribute__((ext_vector_type(8))) short short8v;
typedef __attribute__((ext_vector_type(4))) float f32x4;

__device__ __forceinline__ float sigmf(float x) { return 1.0f / (1.0f + __expf(-x)); }

__device__ __forceinline__ unsigned short bf16_rn(float x) {
    union { float f; unsigned u; } v; v.f = x;
    unsigned r = v.u + 0x7FFF + ((v.u >> 16) & 1);
    return (unsigned short)(r >> 16);
}
__device__ __forceinline__ float bf16_to_f(unsigned short h) {
    union { unsigned u; float f; } v; v.u = ((unsigned)h) << 16; return v.f;
}
__device__ __forceinline__ unsigned long long pack4(unsigned short a, unsigned short b,
                                                    unsigned short c, unsigned short d) {
    return (unsigned long long)a | ((unsigned long long)b << 16)
         | ((unsigned long long)c << 32) | ((unsigned long long)d << 48);
}

#define MFMA_(d, va, vb) d = __builtin_amdgcn_mfma_f32_16x16x32_bf16(va, vb, d, 0, 0, 0)

#define AT_LD(p)        __hip_atomic_load((p), __ATOMIC_RELAXED, __HIP_MEMORY_SCOPE_AGENT)
#define AT_ST(p, v)     __hip_atomic_store((p), (v), __ATOMIC_RELAXED, __HIP_MEMORY_SCOPE_AGENT)
#define AT_ST_REL(p, v) __hip_atomic_store((p), (v), __ATOMIC_RELEASE, __HIP_MEMORY_SCOPE_AGENT)
#define AT_ADD(p, v)    __hip_atomic_fetch_add((p), (v), __ATOMIC_RELAXED, __HIP_MEMORY_SCOPE_AGENT)

// ---------------------------------------------------------------------------
// Fragment layout (A and W): F[p][rgw][kf][l][e]; rgw=r>>4, kf=k>>5,
// l=((k>>3)&3)*16+(r&15), e=k&7. Per-(p,rgw) chunk = 32*64*8 = 16384 shorts.
// ---------------------------------------------------------------------------
__device__ __forceinline__ void write_frag3_nt(unsigned short* __restrict__ dst, int NRGW,
                                               int r, int k, float x)
{
    unsigned short hi = bf16_rn(x); float r1 = x - bf16_to_f(hi);
    unsigned short md = bf16_rn(r1);
    unsigned short lo = bf16_rn(r1 - bf16_to_f(md));
    int base = (((r >> 4) * 32 + (k >> 5)) * 64 + ((k >> 3) & 3) * 16 + (r & 15)) * 8 + (k & 7);
    int ps = NRGW * 16384;
    __builtin_nontemporal_store(hi, &dst[base]);
    __builtin_nontemporal_store(md, &dst[ps + base]);
    __builtin_nontemporal_store(lo, &dst[2 * ps + base]);
}

__launch_bounds__(256)
__global__ void rearr_frag(const float* __restrict__ src, int ld, int c0,
                           unsigned short* __restrict__ dst, int R, int K)
{
    int idx = blockIdx.x * 256 + threadIdx.x;
    int kpr = K >> 3;
    if (idx >= R * kpr) return;
    int r = idx / kpr, k = (idx % kpr) * 8;
    int NRGW = R >> 4;
    const float* s = src + (size_t)r * ld + c0 + k;
    float4 v0 = *(const float4*)s, v1 = *(const float4*)(s + 4);
    float xs[8] = {v0.x, v0.y, v0.z, v0.w, v1.x, v1.y, v1.z, v1.w};
    unsigned short hi[8], md[8], lo[8];
#pragma unroll
    for (int e = 0; e < 8; ++e) {
        hi[e] = bf16_rn(xs[e]); float r1 = xs[e] - bf16_to_f(hi[e]);
        md[e] = bf16_rn(r1);
        lo[e] = bf16_rn(r1 - bf16_to_f(md[e]));
    }
    int base = (((r >> 4) * 32 + (k >> 5)) * 64 + ((k >> 3) & 3) * 16 + (r & 15)) * 8;
    size_t ps = (size_t)NRGW * 16384;
    *(unsigned long long*)&dst[base]          = pack4(hi[0], hi[1], hi[2], hi[3]);
    *(unsigned long long*)&dst[base + 4]      = pack4(hi[4], hi[5], hi[6], hi[7]);
    *(unsigned long long*)&dst[ps + base]     = pack4(md[0], md[1], md[2], md[3]);
    *(unsigned long long*)&dst[ps + base + 4] = pack4(md[4], md[5], md[6], md[7]);
    *(unsigned long long*)&dst[2*ps + base]     = pack4(lo[0], lo[1], lo[2], lo[3]);
    *(unsigned long long*)&dst[2*ps + base + 4] = pack4(lo[4], lo[5], lo[6], lo[7]);
}

// ---------------------------------------------------------------------------
// Two-level tree barrier; gidx = this block's group, ng groups, bpg blocks ea.
// Per-group counters on separate 128B lines; root at bar[ng*32].
// ---------------------------------------------------------------------------
__device__ __forceinline__ void tree_barrier(unsigned* bar, int gidx, int ng, int bpg)
{
    __syncthreads();
    if (threadIdx.x == 0) {
        unsigned* gcnt = bar + gidx * 32;
        unsigned* ggen = bar + gidx * 32 + 1;
        unsigned* rcnt = bar + ng * 32;
        unsigned* rgen = bar + ng * 32 + 1;
        __threadfence();   // release
        unsigned mygen = AT_LD(ggen);
        unsigned prev = AT_ADD(gcnt, 1u);
        if (prev == (unsigned)(bpg - 1)) {
            AT_ST(gcnt, 0u);
            unsigned rg = AT_LD(rgen);
            unsigned rprev = AT_ADD(rcnt, 1u);
            if (rprev == (unsigned)(ng - 1)) {
                AT_ST(rcnt, 0u);
                AT_ST_REL(rgen, rg + 1u);
            } else {
                while (AT_LD(rgen) == rg) __builtin_amdgcn_s_sleep(1);
            }
            AT_ST_REL(ggen, mygen + 1u);
        } else {
            while (AT_LD(ggen) == mygen) __builtin_amdgcn_s_sleep(1);
        }
        __threadfence();   // acquire
    }
    __syncthreads();
}

// ---------------------------------------------------------------------------
// Batched fp32 GEMM via bf16-split MFMA (validated R3): C = A@W^T + bias.
// ---------------------------------------------------------------------------
template <int NS>
__launch_bounds__(256, 2)
__global__ void gemm_mfma_split(const float* __restrict__ A, int lda,
                                const float* __restrict__ W, int ldw,
                                float* __restrict__ C, int ldc,
                                const float* __restrict__ bias,
                                int M, int N, int K)
{
    __shared__ unsigned short Abf[NS][128][40];
    __shared__ unsigned short Bbf[NS][128][40];
    const int tid = threadIdx.x;
    const int m0 = blockIdx.y * 128, n0 = blockIdx.x * 128;
    const int wave = tid >> 6, lane = tid & 63;
    const int wr = wave >> 1, wc = wave & 1;
    const int lr = lane & 15, lk = (lane >> 4) * 8;

    f32x4 acc[4][4];
#pragma unroll
    for (int i = 0; i < 4; ++i)
#pragma unroll
        for (int j = 0; j < 4; ++j) acc[i][j] = (f32x4){0.f, 0.f, 0.f, 0.f};

    const int arow = tid >> 1;
    const int akh  = (tid & 1) * 16;
    int gr = m0 + arow; if (gr > M - 1) gr = M - 1;
    int gn = n0 + arow; if (gn > N - 1) gn = N - 1;
    const float* aptr = A + (size_t)gr * lda + akh;
    const float* wptr = W + (size_t)gn * ldw + akh;

    for (int k0 = 0; k0 < K; k0 += 32) {
#pragma unroll
        for (int q = 0; q < 4; ++q) {
            float4 v = *(const float4*)(aptr + k0 + q * 4);
            float xs[4] = {v.x, v.y, v.z, v.w};
            unsigned short h[4], hm[4], hl[4];
#pragma unroll
            for (int e = 0; e < 4; ++e) {
                h[e] = bf16_rn(xs[e]);
                if (NS == 3) {
                    float r1 = xs[e] - bf16_to_f(h[e]);
                    hm[e] = bf16_rn(r1);
                    hl[e] = bf16_rn(r1 - bf16_to_f(hm[e]));
                }
            }
            *(unsigned long long*)&Abf[0][arow][akh + q * 4] = pack4(h[0], h[1], h[2], h[3]);
            if (NS == 3) {
                *(unsigned long long*)&Abf[1][arow][akh + q * 4] = pack4(hm[0], hm[1], hm[2], hm[3]);
                *(unsigned long long*)&Abf[2][arow][akh + q * 4] = pack4(hl[0], hl[1], hl[2], hl[3]);
            }
        }
#pragma unroll
        for (int q = 0; q < 4; ++q) {
            float4 v = *(const float4*)(wptr + k0 + q * 4);
            float xs[4] = {v.x, v.y, v.z, v.w};
            unsigned short h[4], hm[4], hl[4];
#pragma unroll
            for (int e = 0; e < 4; ++e) {
                h[e] = bf16_rn(xs[e]);
                if (NS == 3) {
                    float r1 = xs[e] - bf16_to_f(h[e]);
                    hm[e] = bf16_rn(r1);
                    hl[e] = bf16_rn(r1 - bf16_to_f(hm[e]));
                }
            }
            *(unsigned long long*)&Bbf[0][arow][akh + q * 4] = pack4(h[0], h[1], h[2], h[3]);
            if (NS == 3) {
                *(unsigned long long*)&Bbf[1][arow][akh + q * 4] = pack4(hm[0], hm[1], hm[2], hm[3]);
                *(unsigned long long*)&Bbf[2][arow][akh + q * 4] = pack4(hl[0], hl[1], hl[2], hl[3]);
            }
        }
        __syncthreads();

        short8v a[NS][4], b[4];
#pragma unroll
        for (int p = 0; p < NS; ++p)
#pragma unroll
            for (int i = 0; i < 4; ++i)
                a[p][i] = *(const short8v*)&Abf[p][wr * 64 + i * 16 + lr][lk];
#pragma unroll
        for (int q = 0; q < NS; ++q) {
#pragma unroll
            for (int j = 0; j < 4; ++j)
                b[j] = *(const short8v*)&Bbf[q][wc * 64 + j * 16 + lr][lk];
            const int pmax = (NS == 1) ? 1 : (3 - q);
#pragma unroll
            for (int p = 0; p < 3; ++p) {
                if (p >= pmax) break;
#pragma unroll
                for (int i = 0; i < 4; ++i)
#pragma unroll
                    for (int j = 0; j < 4; ++j)
                        acc[i][j] = __builtin_amdgcn_mfma_f32_16x16x32_bf16(
                            a[p][i], b[j], acc[i][j], 0, 0, 0);
            }
        }
        __syncthreads();
    }

    const int crow = (lane >> 4) * 4;
#pragma unroll
    for (int i = 0; i < 4; ++i) {
        int mbase = m0 + wr * 64 + i * 16 + crow;
#pragma unroll
        for (int j = 0; j < 4; ++j) {
            int n = n0 + wc * 64 + j * 16 + lr;
            if (n < N) {
                float bv = bias[n];
#pragma unroll
                for (int r = 0; r < 4; ++r) {
                    int m = mbase + r;
                    if (m < M) C[(size_t)m * ldc + n] = acc[i][j][r] + bv;
                }
            }
        }
    }
}

__launch_bounds__(256)
__global__ void zero_f(float* __restrict__ p, int n)
{
    int i = blockIdx.x * 256 + threadIdx.x;
    if (i < n) p[i] = 0.f;
}

__launch_bounds__(256)
__global__ void vec_add2(const float* __restrict__ a, const float* __restrict__ b,
                         float* __restrict__ o, int n)
{
    int i = blockIdx.x * 256 + threadIdx.x;
    if (i < n) o[i] = a[i] + b[i];
}

__launch_bounds__(256)
__global__ void sample0_fill(const float* __restrict__ emW, const float* __restrict__ emb,
                             float* __restrict__ samples)
{
    int idx = blockIdx.x * 256 + threadIdx.x; // 65536
    int d = idx & 1023;
    samples[idx] = emW[(size_t)d * 20000 + 19998] + emb[d];
}

// stage one rg-chunk (96KB) of a 64-row frag buffer into LDS
__device__ __forceinline__ void stage_A(unsigned short* __restrict__ LDSA,
                                        const unsigned short* __restrict__ src,
                                        int rg, int tid)
{
#pragma unroll
    for (int p = 0; p < 3; ++p) {
        const unsigned short* sp = src + (size_t)(p * 4 + rg) * 16384;
        unsigned short* dp = LDSA + p * 16384;
#pragma unroll
        for (int it = 0; it < 4; ++it) {
            int idx = tid + it * 512;
            *(short8v*)&dp[idx * 8] = *(const short8v*)&sp[idx * 8];
        }
    }
}

// 16-kf MFMA block from LDSA rg-chunk vs wreg (encoder-style, in-block gates)
__device__ __forceinline__ f32x4 mfma16(const unsigned short* __restrict__ LDSA,
                                        const short8v* __restrict__ wreg,
                                        int kh, int lane)
{
    f32x4 acc0 = (f32x4){0.f,0.f,0.f,0.f}, acc1 = acc0;
#pragma unroll
    for (int i = 0; i < 16; ++i) {
        int kf = kh * 16 + i;
        short8v a0 = *(const short8v*)&LDSA[(kf * 64 + lane) * 8];
        short8v a1 = *(const short8v*)&LDSA[16384 + (kf * 64 + lane) * 8];
        short8v a2 = *(const short8v*)&LDSA[32768 + (kf * 64 + lane) * 8];
        short8v b0 = wreg[i * 3 + 0], b1 = wreg[i * 3 + 1], b2 = wreg[i * 3 + 2];
        f32x4& A = (i & 1) ? acc1 : acc0;
        MFMA_(A, a0, b0); MFMA_(A, a0, b1); MFMA_(A, a1, b0);
        MFMA_(A, a1, b1); MFMA_(A, a0, b2); MFMA_(A, a2, b0);
    }
    return acc0 + acc1;
}

// ---------------------------------------------------------------------------
// k1: encoder real steps 0..79. 256 blocks x 512. 1 barrier/step.
// Dumps c-state to cglobE at s==79.
// ---------------------------------------------------------------------------
__launch_bounds__(512, 1)
__global__ void coop_enc80(const unsigned short* __restrict__ WencF,
                           const float* __restrict__ Xbig,
                           unsigned short* __restrict__ hfrag,   // 2 bufs x 196608
                           float* __restrict__ enc_seq,
                           float* __restrict__ cglobE,
                           unsigned* __restrict__ bar)
{
    __shared__ unsigned short LDSA[3 * 16384];
    __shared__ float gbuf[8][16][16];
    const int bid = blockIdx.x, tid = threadIdx.x;
    const int w = tid >> 6, lane = tid & 63;
    const int g = w & 3, kh = w >> 2;
    const int rg = bid >> 6, cg = bid & 63;
    const int wbase = g * 64 + cg;
    const int r_l = (tid & 255) >> 4, c_l = tid & 15;
    const int row = rg * 16 + r_l, col = cg * 16 + c_l;
    float cstate = 0.f;

    short8v wreg[48];
#pragma unroll
    for (int i = 0; i < 16; ++i) {
        int kf = kh * 16 + i;
#pragma unroll
        for (int p = 0; p < 3; ++p)
            wreg[i * 3 + p] = *(const short8v*)&WencF[((size_t)(p * 256 + wbase) * 32 + kf) * 512 + lane * 8];
    }

    float pf[4];
    if (tid < 256) {
#pragma unroll
        for (int g2 = 0; g2 < 4; ++g2)
            pf[g2] = Xbig[(size_t)row * 4096 + g2 * 1024 + col];
    }

    for (int s = 0; s < 80; ++s) {
        const unsigned short* hf = hfrag + (s & 1) * 196608;
        stage_A(LDSA, hf, rg, tid);
        __syncthreads();
        f32x4 acc = mfma16(LDSA, wreg, kh, lane);
#pragma unroll
        for (int r = 0; r < 4; ++r)
            gbuf[w][(lane >> 4) * 4 + r][lane & 15] = acc[r];
        __syncthreads();

        if (tid < 256) {
            float gv[4];
#pragma unroll
            for (int g2 = 0; g2 < 4; ++g2)
                gv[g2] = gbuf[g2][r_l][c_l] + gbuf[4 + g2][r_l][c_l] + pf[g2];
            float cn = sigmf(gv[1]) * cstate + sigmf(gv[0]) * tanhf(gv[2]);
            float hn = sigmf(gv[3]) * tanhf(cn);
            cstate = cn;
            __builtin_nontemporal_store(hn, &enc_seq[(size_t)s * 65536 + row * 1024 + col]);
            write_frag3_nt(hfrag + ((s + 1) & 1) * 196608, 4, row, col, hn);
            if (s == 79) __builtin_nontemporal_store(cstate, &cglobE[row * 1024 + col]);
            else {
#pragma unroll
                for (int g2 = 0; g2 < 4; ++g2)
                    pf[g2] = Xbig[((size_t)(s + 1) * 64 + row) * 4096 + g2 * 1024 + col];
            }
        }
        tree_barrier(bar, bid >> 5, 8, 32);
    }
}

// ---------------------------------------------------------------------------
// k3: enc-pad (blocks 0..127) CONCURRENT WITH dec warm-up (blocks 128..255).
// Each half: 128 blocks, encoder-style in-block gates, own tree barrier,
// 80 steps, block covers 32 rows (2 rg chunks sequential) x 16 cols.
// ---------------------------------------------------------------------------
__launch_bounds__(512, 1)
__global__ void coop_padwarm(const unsigned short* __restrict__ WencF,
                             const unsigned short* __restrict__ WdecF,
                             const float* __restrict__ benc,
                             const float* __restrict__ Xwarm,
                             const float* __restrict__ cglobE,
                             unsigned short* __restrict__ hfragE,
                             unsigned short* __restrict__ hfragD,
                             float* __restrict__ enc_pad,
                             float* __restrict__ cglobD,
                             float* __restrict__ h_fp32,
                             unsigned* __restrict__ barE,
                             unsigned* __restrict__ barW)
{
    __shared__ unsigned short LDSA[3 * 16384];
    __shared__ float gbuf[8][16][16];
    const int bid = blockIdx.x, tid = threadIdx.x;
    const int w = tid >> 6, lane = tid & 63;
    const int g = w & 3, kh = w >> 2;
    const bool isW = bid >= 128;
    const int lb = bid & 127;
    const int rg2 = lb >> 6, cg = lb & 63;
    const int wbase = g * 64 + cg;
    const int r_l = (tid & 255) >> 4, c_l = tid & 15;
    const int col = cg * 16 + c_l;
    const unsigned short* Wf = isW ? WdecF : WencF;
    unsigned short* hfrag = isW ? hfragD : hfragE;
    unsigned* bar = isW ? barW : barE;

    short8v wreg[48];
#pragma unroll
    for (int i = 0; i < 16; ++i) {
        int kf = kh * 16 + i;
#pragma unroll
        for (int p = 0; p < 3; ++p)
            wreg[i * 3 + p] = *(const short8v*)&Wf[((size_t)(p * 256 + wbase) * 32 + kf) * 512 + lane * 8];
    }

    float cst[2] = {0.f, 0.f};
    float pfx[2][4];
    if (tid < 256) {
#pragma unroll
        for (int l = 0; l < 2; ++l) {
            int row = rg2 * 32 + l * 16 + r_l;
            if (!isW) cst[l] = cglobE[row * 1024 + col];
#pragma unroll
            for (int g2 = 0; g2 < 4; ++g2)
                pfx[l][g2] = isW ? Xwarm[(size_t)row * 4096 + g2 * 1024 + col]
                                 : benc[g2 * 1024 + col];
        }
    }

    for (int s = 0; s < 80; ++s) {
        const unsigned short* hf = hfrag + (s & 1) * 196608;
        unsigned short* hout = hfrag + ((s + 1) & 1) * 196608;
#pragma unroll
        for (int l = 0; l < 2; ++l) {
            const int rgi = rg2 * 2 + l;
            stage_A(LDSA, hf, rgi, tid);
            __syncthreads();
            f32x4 acc = mfma16(LDSA, wreg, kh, lane);
#pragma unroll
            for (int r = 0; r < 4; ++r)
                gbuf[w][(lane >> 4) * 4 + r][lane & 15] = acc[r];
            __syncthreads();
            if (tid < 256) {
                const int row = rgi * 16 + r_l;
                float gv[4];
#pragma unroll
                for (int g2 = 0; g2 < 4; ++g2)
                    gv[g2] = gbuf[g2][r_l][c_l] + gbuf[4 + g2][r_l][c_l] + pfx[l][g2];
                float cn = sigmf(gv[1]) * cst[l] + sigmf(gv[0]) * tanhf(gv[2]);
                float hn = sigmf(gv[3]) * tanhf(cn);
                cst[l] = cn;
                if (!isW)
                    __builtin_nontemporal_store(hn, &enc_pad[(size_t)s * 65536 + row * 1024 + col]);
                write_frag3_nt(hout, 4, row, col, hn);
                if (isW) {
                    if (s == 79) {
                        __builtin_nontemporal_store(hn, &h_fp32[row * 1024 + col]);
                        __builtin_nontemporal_store(cn, &cglobD[row * 1024 + col]);
                    } else {
#pragma unroll
                        for (int g2 = 0; g2 < 4; ++g2)
                            pfx[l][g2] = Xwarm[((size_t)(s + 1) * 64 + row) * 4096 + g2 * 1024 + col];
                    }
                }
            }
            __syncthreads();
        }
        tree_barrier(bar, (lb >> 5), 4, 32);
    }
}

// ---------------------------------------------------------------------------
// k4: attention-decode only, s=80..159. 256 blocks x 512. 3 barriers/step.
// Phase B role (gg,cg); Phase A'/C role (b,jc). EW2 slice LDS-resident.
// First step computes full logits from h_fp32 (no plog yet).
// ---------------------------------------------------------------------------
__launch_bounds__(512, 2)
__global__ void coop_dec80(const unsigned short* __restrict__ WihcF,
                           const unsigned short* __restrict__ WhhF,
                           const float* __restrict__ W1,       // [80][2048]
                           const float* __restrict__ EW2,      // [80][64][1024]
                           const float* __restrict__ S_g,
                           const float* __restrict__ ctxS,
                           const float* __restrict__ S_log,
                           const float* __restrict__ enc_pad,
                           const float* __restrict__ prelu_w,
                           const float* __restrict__ h_fp32,
                           const float* __restrict__ cglobD,
                           unsigned short* __restrict__ hfrag,  // 2 bufs (parity: step 80 reads buf0)
                           unsigned short* __restrict__ ctxfrag,
                           float* __restrict__ plog,            // [64][4][80]
                           float* __restrict__ h_all,
                           float* __restrict__ gsum,            // [4][64][1024]
                           unsigned* __restrict__ bar)
{
    __shared__ float EW2T[80 * 256];
    __shared__ float gred[8][1024];
    __shared__ float hq[256];
    __shared__ float wsm[80];
    __shared__ float rbuf[128];
    const int bid = blockIdx.x, tid = threadIdx.x;
    const int w = tid >> 6, lane = tid & 63;
    const int gg = bid >> 6, cg = bid & 63;
    const int wbase = gg * 64 + cg;
    const int kq = w;
    const int b = bid >> 2, jc = bid & 3;
    const float pw = prelu_w[0];

    const unsigned short* Wsrc = (kq < 4) ? WihcF : WhhF;
    const int kfbase = (kq & 3) * 8;
    short8v wreg[24];
#pragma unroll
    for (int i = 0; i < 8; ++i) {
#pragma unroll
        for (int p = 0; p < 3; ++p)
            wreg[i * 3 + p] = *(const short8v*)&Wsrc[((size_t)(p * 256 + wbase) * 32 + kfbase + i) * 512 + lane * 8];
    }

    float cstate = (tid < 256) ? cglobD[b * 1024 + jc * 256 + tid] : 0.f;

    for (int i = tid; i < 80 * 256; i += 512) {
        int ss = i >> 8, j = i & 255;
        EW2T[i] = EW2[((size_t)ss * 64 + b) * 1024 + jc * 256 + j];
    }
    __syncthreads();

    for (int s = 80; s < 160; ++s) {
        unsigned short* hout = hfrag + ((s + 1) & 1) * 196608;
        const unsigned short* hf = hfrag + (s & 1) * 196608;
        const int t = s - 80;

        // ---- Phase A': logits + softmax + f + ctx ----
        if (s == 80) {
            float* hsm_ = (float*)gred;
            for (int i = tid; i < 1024; i += 512) hsm_[i] = h_fp32[b * 1024 + i];
            __syncthreads();
#pragma unroll
            for (int i = 0; i < 10; ++i) {
                int sx = w * 10 + i;
                float p = 0.f;
#pragma unroll
                for (int q = 0; q < 16; ++q)
                    p = fmaf(hsm_[lane + q * 64], W1[(size_t)sx * 2048 + lane + q * 64], p);
#pragma unroll
                for (int off = 32; off; off >>= 1) p += __shfl_down(p, off, 64);
                if (lane == 0) wsm[sx] = p + S_log[((size_t)t * 64 + b) * 80 + sx];
            }
            __syncthreads();
        } else {
            if (tid < 80) {
                float l4 = plog[(b * 4 + 0) * 80 + tid] + plog[(b * 4 + 1) * 80 + tid]
                         + plog[(b * 4 + 2) * 80 + tid] + plog[(b * 4 + 3) * 80 + tid];
                wsm[tid] = l4 + S_log[((size_t)t * 64 + b) * 80 + tid];
            }
            __syncthreads();
        }
        float v = (tid < 80) ? wsm[tid] : -3.4e38f;
        if (tid < 128) rbuf[tid] = v;
        __syncthreads();
        for (int off = 64; off >= 1; off >>= 1) {
            if (tid < off) rbuf[tid] = fmaxf(rbuf[tid], rbuf[tid + off]);
            __syncthreads();
        }
        float mx = rbuf[0];
        __syncthreads();
        float e = (tid < 80) ? __expf(wsm[tid] - mx) : 0.f;
        if (tid < 128) rbuf[tid] = e;
        __syncthreads();
        for (int off = 64; off >= 1; off >>= 1) {
            if (tid < off) rbuf[tid] += rbuf[tid + off];
            __syncthreads();
        }
        float inv = 1.f / rbuf[0];
        __syncthreads();
        if (tid < 80) wsm[tid] = e * inv;
        __syncthreads();
        if (tid < 256) {
            float f = 0.f;
#pragma unroll 8
            for (int ss = 0; ss < 80; ++ss)
                f = fmaf(wsm[ss], EW2T[ss * 256 + tid], f);
            int col = jc * 256 + tid;
            float val = f + ctxS[((size_t)t * 64 + b) * 1024 + col];
            val = (val >= 0.f) ? val : pw * val;
            val += enc_pad[((size_t)t * 64 + b) * 1024 + col];
            write_frag3_nt(ctxfrag, 4, b, col, val);
        }
        tree_barrier(bar, bid >> 5, 8, 32);

        // ---- prefetch Phase-C gate-adds ----
        float pf[4];
        if (tid < 256) {
            const float* xb = S_g + ((size_t)t * 64 + b) * 4096;
            int col = jc * 256 + tid;
#pragma unroll
            for (int g2 = 0; g2 < 4; ++g2) pf[g2] = xb[g2 * 1024 + col];
        }

        // ---- Phase B: gate GEMM partials ----
        {
            f32x4 acc[4];
#pragma unroll
            for (int rg = 0; rg < 4; ++rg) acc[rg] = (f32x4){0.f,0.f,0.f,0.f};
            const unsigned short* asrc = (kq < 4) ? ctxfrag : hf;
#pragma unroll
            for (int i = 0; i < 8; ++i) {
                int kfl = kfbase + i;
#pragma unroll
                for (int rg = 0; rg < 4; ++rg) {
                    const unsigned short* ab = asrc + ((size_t)rg * 32 + kfl) * 512 + lane * 8;
                    short8v a0 = *(const short8v*)&ab[0];
                    short8v a1 = *(const short8v*)&ab[65536];
                    short8v a2 = *(const short8v*)&ab[131072];
                    short8v b0 = wreg[i * 3 + 0], b1 = wreg[i * 3 + 1], b2 = wreg[i * 3 + 2];
                    MFMA_(acc[rg], a0, b0); MFMA_(acc[rg], a0, b1); MFMA_(acc[rg], a1, b0);
                    MFMA_(acc[rg], a1, b1); MFMA_(acc[rg], a0, b2); MFMA_(acc[rg], a2, b0);
                }
            }
#pragma unroll
            for (int rg = 0; rg < 4; ++rg)
#pragma unroll
                for (int r = 0; r < 4; ++r)
                    gred[w][rg * 256 + lane * 4 + r] = acc[rg][r];
            __syncthreads();
#pragma unroll
            for (int e2 = 0; e2 < 2; ++e2) {
                int slot = tid * 2 + e2;
                int rg = slot >> 8, l = (slot >> 2) & 63, r = slot & 3;
                float sum = 0.f;
#pragma unroll
                for (int w2 = 0; w2 < 8; ++w2) sum += gred[w2][slot];
                int row = rg * 16 + (l >> 4) * 4 + r;
                int col = cg * 16 + (l & 15);
                __builtin_nontemporal_store(sum, &gsum[((size_t)gg * 64 + row) * 1024 + col]);
            }
        }
        tree_barrier(bar, bid >> 5, 8, 32);

        // ---- Phase C: pointwise gates + h + plog partials ----
        if (tid < 256) {
            int col = jc * 256 + tid;
            float gv[4];
#pragma unroll
            for (int g2 = 0; g2 < 4; ++g2)
                gv[g2] = gsum[((size_t)g2 * 64 + b) * 1024 + col] + pf[g2];
            float cn = sigmf(gv[1]) * cstate + sigmf(gv[0]) * tanhf(gv[2]);
            float hn = sigmf(gv[3]) * tanhf(cn);
            cstate = cn;
            __builtin_nontemporal_store(hn, &h_all[((size_t)t * 64 + b) * 1024 + col]);
            write_frag3_nt(hout, 4, b, col, hn);
            hq[tid] = hn;
        }
        __syncthreads();
        if (s < 159) {
#pragma unroll
            for (int i = 0; i < 10; ++i) {
                int sx = w * 10 + i;
                float p = 0.f;
#pragma unroll
                for (int q = 0; q < 4; ++q)
                    p = fmaf(hq[lane + q * 64], W1[(size_t)sx * 2048 + jc * 256 + lane + q * 64], p);
#pragma unroll
                for (int off = 32; off; off >>= 1) p += __shfl_down(p, off, 64);
                if (lane == 0) __builtin_nontemporal_store(p, &plog[(b * 4 + jc) * 80 + sx]);
            }
        }
        tree_barrier(bar, bid >> 5, 8, 32);
    }
}

// ---------------------------------------------------------------------------
extern "C" void kernel_launch(void* const* d_in, const int* in_sizes, int n_in,
                              void* d_out, int out_size, void* d_ws, size_t ws_size,
                              hipStream_t stream)
{
    (void)in_sizes; (void)n_in; (void)out_size; (void)ws_size;

    const float* input_data     = (const float*)d_in[0];
    const float* correct_answer = (const float*)d_in[1];
    const float* enc_W_ih = (const float*)d_in[2];
    const float* enc_W_hh = (const float*)d_in[3];
    const float* enc_b_ih = (const float*)d_in[4];
    const float* enc_b_hh = (const float*)d_in[5];
    const float* dec_W_ih = (const float*)d_in[6];
    const float* dec_W_hh = (const float*)d_in[7];
    const float* dec_b_ih = (const float*)d_in[8];
    const float* dec_b_hh = (const float*)d_in[9];
    const float* in_emb_W = (const float*)d_in[10];
    const float* in_emb_b = (const float*)d_in[11];
    const float* out_emb_W = (const float*)d_in[12];
    const float* out_emb_b = (const float*)d_in[13];
    const float* att_W1 = (const float*)d_in[14];
    const float* att_b1 = (const float*)d_in[15];
    const float* att_W2 = (const float*)d_in[16];
    const float* att_b2 = (const float*)d_in[17];
    const float* prelu_w = (const float*)d_in[18];

    float* out = (float*)d_out;
    char* ws = (char*)d_ws;

    // ---- d_out scratch (all reads precede final vocab GEMM) ----
    float* Xbig    = out;                      // [80][64][4096] (enc X, then reused as Xwarm)
    float* S_g     = out + 20971520;
    float* ctxS    = out + 41943040;
    float* S_log   = out + 47185920;
    float* samples = out + 47595520;
    float* EW2     = out + 52838400;
    unsigned short* WencF = (unsigned short*)(out + 58081280);
    unsigned short* WhhDF = (unsigned short*)(out + 64372736);
    unsigned short* WihcF = (unsigned short*)(out + 70664192);

    // ---- d_ws map ----
    size_t off = 0;
    auto alloc = [&](size_t nfloats) { float* p = (float*)(ws + off); off += nfloats * 4; return p; };
    float* enc_seq = alloc(80 * 64 * 1024);
    float* enc_pad = alloc(80 * 64 * 1024);
    float* h_all   = alloc(80 * 64 * 1024);
    float* benc    = alloc(4096);
    float* bdec    = alloc(4096);
    float* zb      = alloc(1024);
    float* hfragE_f = alloc(196608);
    float* hfragD_f = alloc(196608);
    float* ctxfrag_f= alloc(98304);
    float* plog     = alloc(64 * 4 * 80);
    float* gsum     = alloc(262144);
    float* cglobE   = alloc(65536);
    float* cglobD   = alloc(65536);
    float* h_fp32   = alloc(65536);
    float* bar_f    = alloc(2048);
    unsigned short* hfragE  = (unsigned short*)hfragE_f;
    unsigned short* hfragD  = (unsigned short*)hfragD_f;
    unsigned short* ctxfrag = (unsigned short*)ctxfrag_f;
    unsigned* barE1 = (unsigned*)bar_f;          // k1 (8 groups)
    unsigned* barPE = ((unsigned*)bar_f) + 512;  // k3 enc-pad half (4 groups)
    unsigned* barPW = ((unsigned*)bar_f) + 1024; // k3 warm-up half (4 groups)
    unsigned* barD  = ((unsigned*)bar_f) + 1536; // k4 (8 groups)

    auto big3 = [&](const float* A, int lda, const float* W, int ldw,
                    float* C, int ldc, const float* bias, int M, int N, int K) {
        dim3 g((N + 127) / 128, (M + 127) / 128);
        hipLaunchKernelGGL((gemm_mfma_split<3>), g, dim3(256), 0, stream,
                           A, lda, W, ldw, C, ldc, bias, M, N, K);
    };

    // ---- setup ----
    hipLaunchKernelGGL(vec_add2, dim3(16), dim3(256), 0, stream, enc_b_ih, enc_b_hh, benc, 4096);
    hipLaunchKernelGGL(vec_add2, dim3(16), dim3(256), 0, stream, dec_b_ih, dec_b_hh, bdec, 4096);
    hipLaunchKernelGGL(zero_f, dim3(4), dim3(256), 0, stream, zb, 1024);
    hipLaunchKernelGGL(zero_f, dim3(768), dim3(256), 0, stream, hfragE_f, 196608);
    hipLaunchKernelGGL(zero_f, dim3(768), dim3(256), 0, stream, hfragD_f, 196608);
    hipLaunchKernelGGL(zero_f, dim3(8), dim3(256), 0, stream, bar_f, 2048);

    // ---- weight frag rearranges ----
    hipLaunchKernelGGL(rearr_frag, dim3(2048), dim3(256), 0, stream, enc_W_hh, 1024, 0, WencF, 4096, 1024);
    hipLaunchKernelGGL(rearr_frag, dim3(2048), dim3(256), 0, stream, dec_W_hh, 1024, 0, WhhDF, 4096, 1024);
    hipLaunchKernelGGL(rearr_frag, dim3(2048), dim3(256), 0, stream, dec_W_ih, 2048, 1024, WihcF, 4096, 1024);

    // ---- batched big GEMMs (NS=3) ----
    big3(input_data, 4096, enc_W_ih, 4096, Xbig, 4096, benc, 5120, 4096, 4096);
    hipLaunchKernelGGL(sample0_fill, dim3(256), dim3(256), 0, stream, in_emb_W, in_emb_b, samples);
    big3(correct_answer + (size_t)64 * 20000, 20000, in_emb_W, 20000,
         samples + 65536, 1024, in_emb_b, 5056, 1024, 20000);
    big3(samples, 1024, dec_W_ih, 2048, S_g, 4096, bdec, 5120, 4096, 1024);
    big3(samples, 1024, att_W2, 2048, ctxS, 1024, att_b2, 5120, 1024, 1024);
    big3(samples, 1024, att_W1 + 1024, 2048, S_log, 80, att_b1, 5120, 80, 1024);

    // ---- k1: encoder real (80 steps) ----
    hipLaunchKernelGGL(coop_enc80, dim3(256), dim3(512), 0, stream,
                       WencF, Xbig, hfragE, enc_seq, cglobE, barE1);

    // ---- Xwarm + EW2 projections (need enc_seq) ----
    big3(enc_seq, 1024, dec_W_ih, 2048, Xbig, 4096, bdec, 5120, 4096, 1024);
    big3(enc_seq, 1024, att_W2 + 1024, 2048, EW2, 1024, zb, 5120, 1024, 1024);

    // ---- k3: enc-pad || dec warm-up (80 steps, overlapped) ----
    hipLaunchKernelGGL(coop_padwarm, dim3(256), dim3(512), 0, stream,
                       WencF, WhhDF, benc, Xbig, cglobE,
                       hfragE, hfragD, enc_pad, cglobD, h_fp32, barPE, barPW);

    // ---- k4: attention decode (80 steps) ----
    hipLaunchKernelGGL(coop_dec80, dim3(256), dim3(512), 0, stream,
                       WihcF, WhhDF, att_W1, EW2, S_g, ctxS, S_log,
                       enc_pad, prelu_w, h_fp32, cglobD,
                       hfragD, ctxfrag, plog, h_all, gsum, barD);

    // ---- final vocab projection (NS=1, output-facing) ----
    {
        dim3 g((20000 + 127) / 128, (5120 + 127) / 128);
        hipLaunchKernelGGL((gemm_mfma_split<1>), g, dim3(256), 0, stream,
                           h_all, 1024, out_emb_W, 1024, out, 20000, out_emb_b, 5120, 20000, 1024);
    }
}

// Round 12
// 14971.194 us; speedup vs baseline: 3.5082x; 1.0020x over previous
//
#include <hip/hip_runtime.h>
#include <cstddef>
#include <cstdint>

typedef __attribute__((ext_vector_type(8))) short short8v;
typedef __attribute__((ext_vector_type(4))) float f32x4;

__device__ __forceinline__ float sigmf(float x) { return 1.0f / (1.0f + __expf(-x)); }

__device__ __forceinline__ unsigned short bf16_rn(float x) {
    union { float f; unsigned u; } v; v.f = x;
    unsigned r = v.u + 0x7FFF + ((v.u >> 16) & 1);
    return (unsigned short)(r >> 16);
}
__device__ __forceinline__ float bf16_to_f(unsigned short h) {
    union { unsigned u; float f; } v; v.u = ((unsigned)h) << 16; return v.f;
}
__device__ __forceinline__ unsigned long long pack4(unsigned short a, unsigned short b,
                                                    unsigned short c, unsigned short d) {
    return (unsigned long long)a | ((unsigned long long)b << 16)
         | ((unsigned long long)c << 32) | ((unsigned long long)d << 48);
}

#define MFMA_(d, va, vb) d = __builtin_amdgcn_mfma_f32_16x16x32_bf16(va, vb, d, 0, 0, 0)

#define AT_LD(p)        __hip_atomic_load((p), __ATOMIC_RELAXED, __HIP_MEMORY_SCOPE_AGENT)
#define AT_ST(p, v)     __hip_atomic_store((p), (v), __ATOMIC_RELAXED, __HIP_MEMORY_SCOPE_AGENT)
#define AT_ST_REL(p, v) __hip_atomic_store((p), (v), __ATOMIC_RELEASE, __HIP_MEMORY_SCOPE_AGENT)
#define AT_ADD(p, v)    __hip_atomic_fetch_add((p), (v), __ATOMIC_RELAXED, __HIP_MEMORY_SCOPE_AGENT)

// ---------------------------------------------------------------------------
// Fragment layout (A and W): F[p][rgw][kf][l][e]; rgw=r>>4, kf=k>>5,
// l=((k>>3)&3)*16+(r&15), e=k&7. Per-(p,rgw) chunk = 32*64*8 = 16384 shorts.
// ---------------------------------------------------------------------------
__device__ __forceinline__ void write_frag3_nt(unsigned short* __restrict__ dst, int NRGW,
                                               int r, int k, float x)
{
    unsigned short hi = bf16_rn(x); float r1 = x - bf16_to_f(hi);
    unsigned short md = bf16_rn(r1);
    unsigned short lo = bf16_rn(r1 - bf16_to_f(md));
    int base = (((r >> 4) * 32 + (k >> 5)) * 64 + ((k >> 3) & 3) * 16 + (r & 15)) * 8 + (k & 7);
    int ps = NRGW * 16384;
    __builtin_nontemporal_store(hi, &dst[base]);
    __builtin_nontemporal_store(md, &dst[ps + base]);
    __builtin_nontemporal_store(lo, &dst[2 * ps + base]);
}

__launch_bounds__(256)
__global__ void rearr_frag(const float* __restrict__ src, int ld, int c0,
                           unsigned short* __restrict__ dst, int R, int K)
{
    int idx = blockIdx.x * 256 + threadIdx.x;
    int kpr = K >> 3;
    if (idx >= R * kpr) return;
    int r = idx / kpr, k = (idx % kpr) * 8;
    int NRGW = R >> 4;
    const float* s = src + (size_t)r * ld + c0 + k;
    float4 v0 = *(const float4*)s, v1 = *(const float4*)(s + 4);
    float xs[8] = {v0.x, v0.y, v0.z, v0.w, v1.x, v1.y, v1.z, v1.w};
    unsigned short hi[8], md[8], lo[8];
#pragma unroll
    for (int e = 0; e < 8; ++e) {
        hi[e] = bf16_rn(xs[e]); float r1 = xs[e] - bf16_to_f(hi[e]);
        md[e] = bf16_rn(r1);
        lo[e] = bf16_rn(r1 - bf16_to_f(md[e]));
    }
    int base = (((r >> 4) * 32 + (k >> 5)) * 64 + ((k >> 3) & 3) * 16 + (r & 15)) * 8;
    size_t ps = (size_t)NRGW * 16384;
    *(unsigned long long*)&dst[base]          = pack4(hi[0], hi[1], hi[2], hi[3]);
    *(unsigned long long*)&dst[base + 4]      = pack4(hi[4], hi[5], hi[6], hi[7]);
    *(unsigned long long*)&dst[ps + base]     = pack4(md[0], md[1], md[2], md[3]);
    *(unsigned long long*)&dst[ps + base + 4] = pack4(md[4], md[5], md[6], md[7]);
    *(unsigned long long*)&dst[2*ps + base]     = pack4(lo[0], lo[1], lo[2], lo[3]);
    *(unsigned long long*)&dst[2*ps + base + 4] = pack4(lo[4], lo[5], lo[6], lo[7]);
}

// ---------------------------------------------------------------------------
// Two-level tree barrier; gidx = this block's group, ng groups, bpg blocks ea.
// ---------------------------------------------------------------------------
__device__ __forceinline__ void tree_barrier(unsigned* bar, int gidx, int ng, int bpg)
{
    __syncthreads();
    if (threadIdx.x == 0) {
        unsigned* gcnt = bar + gidx * 32;
        unsigned* ggen = bar + gidx * 32 + 1;
        unsigned* rcnt = bar + ng * 32;
        unsigned* rgen = bar + ng * 32 + 1;
        __threadfence();   // release
        unsigned mygen = AT_LD(ggen);
        unsigned prev = AT_ADD(gcnt, 1u);
        if (prev == (unsigned)(bpg - 1)) {
            AT_ST(gcnt, 0u);
            unsigned rg = AT_LD(rgen);
            unsigned rprev = AT_ADD(rcnt, 1u);
            if (rprev == (unsigned)(ng - 1)) {
                AT_ST(rcnt, 0u);
                AT_ST_REL(rgen, rg + 1u);
            } else {
                while (AT_LD(rgen) == rg) __builtin_amdgcn_s_sleep(1);
            }
            AT_ST_REL(ggen, mygen + 1u);
        } else {
            while (AT_LD(ggen) == mygen) __builtin_amdgcn_s_sleep(1);
        }
        __threadfence();   // acquire
    }
    __syncthreads();
}

// ---------------------------------------------------------------------------
// Batched fp32 GEMM via bf16-split MFMA (validated R3): C = A@W^T + bias.
// ---------------------------------------------------------------------------
template <int NS>
__launch_bounds__(256, 2)
__global__ void gemm_mfma_split(const float* __restrict__ A, int lda,
                                const float* __restrict__ W, int ldw,
                                float* __restrict__ C, int ldc,
                                const float* __restrict__ bias,
                                int M, int N, int K)
{
    __shared__ unsigned short Abf[NS][128][40];
    __shared__ unsigned short Bbf[NS][128][40];
    const int tid = threadIdx.x;
    const int m0 = blockIdx.y * 128, n0 = blockIdx.x * 128;
    const int wave = tid >> 6, lane = tid & 63;
    const int wr = wave >> 1, wc = wave & 1;
    const int lr = lane & 15, lk = (lane >> 4) * 8;

    f32x4 acc[4][4];
#pragma unroll
    for (int i = 0; i < 4; ++i)
#pragma unroll
        for (int j = 0; j < 4; ++j) acc[i][j] = (f32x4){0.f, 0.f, 0.f, 0.f};

    const int arow = tid >> 1;
    const int akh  = (tid & 1) * 16;
    int gr = m0 + arow; if (gr > M - 1) gr = M - 1;
    int gn = n0 + arow; if (gn > N - 1) gn = N - 1;
    const float* aptr = A + (size_t)gr * lda + akh;
    const float* wptr = W + (size_t)gn * ldw + akh;

    for (int k0 = 0; k0 < K; k0 += 32) {
#pragma unroll
        for (int q = 0; q < 4; ++q) {
            float4 v = *(const float4*)(aptr + k0 + q * 4);
            float xs[4] = {v.x, v.y, v.z, v.w};
            unsigned short h[4], hm[4], hl[4];
#pragma unroll
            for (int e = 0; e < 4; ++e) {
                h[e] = bf16_rn(xs[e]);
                if (NS == 3) {
                    float r1 = xs[e] - bf16_to_f(h[e]);
                    hm[e] = bf16_rn(r1);
                    hl[e] = bf16_rn(r1 - bf16_to_f(hm[e]));
                }
            }
            *(unsigned long long*)&Abf[0][arow][akh + q * 4] = pack4(h[0], h[1], h[2], h[3]);
            if (NS == 3) {
                *(unsigned long long*)&Abf[1][arow][akh + q * 4] = pack4(hm[0], hm[1], hm[2], hm[3]);
                *(unsigned long long*)&Abf[2][arow][akh + q * 4] = pack4(hl[0], hl[1], hl[2], hl[3]);
            }
        }
#pragma unroll
        for (int q = 0; q < 4; ++q) {
            float4 v = *(const float4*)(wptr + k0 + q * 4);
            float xs[4] = {v.x, v.y, v.z, v.w};
            unsigned short h[4], hm[4], hl[4];
#pragma unroll
            for (int e = 0; e < 4; ++e) {
                h[e] = bf16_rn(xs[e]);
                if (NS == 3) {
                    float r1 = xs[e] - bf16_to_f(h[e]);
                    hm[e] = bf16_rn(r1);
                    hl[e] = bf16_rn(r1 - bf16_to_f(hm[e]));
                }
            }
            *(unsigned long long*)&Bbf[0][arow][akh + q * 4] = pack4(h[0], h[1], h[2], h[3]);
            if (NS == 3) {
                *(unsigned long long*)&Bbf[1][arow][akh + q * 4] = pack4(hm[0], hm[1], hm[2], hm[3]);
                *(unsigned long long*)&Bbf[2][arow][akh + q * 4] = pack4(hl[0], hl[1], hl[2], hl[3]);
            }
        }
        __syncthreads();

        short8v a[NS][4], b[4];
#pragma unroll
        for (int p = 0; p < NS; ++p)
#pragma unroll
            for (int i = 0; i < 4; ++i)
                a[p][i] = *(const short8v*)&Abf[p][wr * 64 + i * 16 + lr][lk];
#pragma unroll
        for (int q = 0; q < NS; ++q) {
#pragma unroll
            for (int j = 0; j < 4; ++j)
                b[j] = *(const short8v*)&Bbf[q][wc * 64 + j * 16 + lr][lk];
            const int pmax = (NS == 1) ? 1 : (3 - q);
#pragma unroll
            for (int p = 0; p < 3; ++p) {
                if (p >= pmax) break;
#pragma unroll
                for (int i = 0; i < 4; ++i)
#pragma unroll
                    for (int j = 0; j < 4; ++j)
                        acc[i][j] = __builtin_amdgcn_mfma_f32_16x16x32_bf16(
                            a[p][i], b[j], acc[i][j], 0, 0, 0);
            }
        }
        __syncthreads();
    }

    const int crow = (lane >> 4) * 4;
#pragma unroll
    for (int i = 0; i < 4; ++i) {
        int mbase = m0 + wr * 64 + i * 16 + crow;
#pragma unroll
        for (int j = 0; j < 4; ++j) {
            int n = n0 + wc * 64 + j * 16 + lr;
            if (n < N) {
                float bv = bias[n];
#pragma unroll
                for (int r = 0; r < 4; ++r) {
                    int m = mbase + r;
                    if (m < M) C[(size_t)m * ldc + n] = acc[i][j][r] + bv;
                }
            }
        }
    }
}

__launch_bounds__(256)
__global__ void zero_f(float* __restrict__ p, int n)
{
    int i = blockIdx.x * 256 + threadIdx.x;
    if (i < n) p[i] = 0.f;
}

__launch_bounds__(256)
__global__ void vec_add2(const float* __restrict__ a, const float* __restrict__ b,
                         float* __restrict__ o, int n)
{
    int i = blockIdx.x * 256 + threadIdx.x;
    if (i < n) o[i] = a[i] + b[i];
}

__launch_bounds__(256)
__global__ void sample0_fill(const float* __restrict__ emW, const float* __restrict__ emb,
                             float* __restrict__ samples)
{
    int idx = blockIdx.x * 256 + threadIdx.x; // 65536
    int d = idx & 1023;
    samples[idx] = emW[(size_t)d * 20000 + 19998] + emb[d];
}

// stage one rg-chunk (96KB) of a 64-row frag buffer into LDS
__device__ __forceinline__ void stage_A(unsigned short* __restrict__ LDSA,
                                        const unsigned short* __restrict__ src,
                                        int rg, int tid)
{
#pragma unroll
    for (int p = 0; p < 3; ++p) {
        const unsigned short* sp = src + (size_t)(p * 4 + rg) * 16384;
        unsigned short* dp = LDSA + p * 16384;
#pragma unroll
        for (int it = 0; it < 4; ++it) {
            int idx = tid + it * 512;
            *(short8v*)&dp[idx * 8] = *(const short8v*)&sp[idx * 8];
        }
    }
}

// 16-kf MFMA block from LDSA rg-chunk vs wreg (encoder-style, in-block gates)
__device__ __forceinline__ f32x4 mfma16(const unsigned short* __restrict__ LDSA,
                                        const short8v* __restrict__ wreg,
                                        int kh, int lane)
{
    f32x4 acc0 = (f32x4){0.f,0.f,0.f,0.f}, acc1 = acc0;
#pragma unroll
    for (int i = 0; i < 16; ++i) {
        int kf = kh * 16 + i;
        short8v a0 = *(const short8v*)&LDSA[(kf * 64 + lane) * 8];
        short8v a1 = *(const short8v*)&LDSA[16384 + (kf * 64 + lane) * 8];
        short8v a2 = *(const short8v*)&LDSA[32768 + (kf * 64 + lane) * 8];
        short8v b0 = wreg[i * 3 + 0], b1 = wreg[i * 3 + 1], b2 = wreg[i * 3 + 2];
        f32x4& A = (i & 1) ? acc1 : acc0;
        MFMA_(A, a0, b0); MFMA_(A, a0, b1); MFMA_(A, a1, b0);
        MFMA_(A, a1, b1); MFMA_(A, a0, b2); MFMA_(A, a2, b0);
    }
    return acc0 + acc1;
}

// ---------------------------------------------------------------------------
// k1: encoder real steps 0..79. 256 blocks x 512. 1 barrier/step.
// XCD-local rg: rg = bid&3 (bid%8 = XCD => bid&3 constant per XCD).
// ---------------------------------------------------------------------------
__launch_bounds__(512, 1)
__global__ void coop_enc80(const unsigned short* __restrict__ WencF,
                           const float* __restrict__ Xbig,
                           unsigned short* __restrict__ hfrag,   // 2 bufs x 196608
                           float* __restrict__ enc_seq,
                           float* __restrict__ cglobE,
                           unsigned* __restrict__ bar)
{
    __shared__ unsigned short LDSA[3 * 16384];
    __shared__ float gbuf[8][16][16];
    const int bid = blockIdx.x, tid = threadIdx.x;
    const int w = tid >> 6, lane = tid & 63;
    const int g = w & 3, kh = w >> 2;
    const int rg = bid & 3, cg = bid >> 2;
    const int wbase = g * 64 + cg;
    const int r_l = (tid & 255) >> 4, c_l = tid & 15;
    const int row = rg * 16 + r_l, col = cg * 16 + c_l;
    float cstate = 0.f;

    short8v wreg[48];
#pragma unroll
    for (int i = 0; i < 16; ++i) {
        int kf = kh * 16 + i;
#pragma unroll
        for (int p = 0; p < 3; ++p)
            wreg[i * 3 + p] = *(const short8v*)&WencF[((size_t)(p * 256 + wbase) * 32 + kf) * 512 + lane * 8];
    }

    float pf[4];
    if (tid < 256) {
#pragma unroll
        for (int g2 = 0; g2 < 4; ++g2)
            pf[g2] = Xbig[(size_t)row * 4096 + g2 * 1024 + col];
    }

    for (int s = 0; s < 80; ++s) {
        const unsigned short* hf = hfrag + (s & 1) * 196608;
        stage_A(LDSA, hf, rg, tid);
        __syncthreads();
        f32x4 acc = mfma16(LDSA, wreg, kh, lane);
#pragma unroll
        for (int r = 0; r < 4; ++r)
            gbuf[w][(lane >> 4) * 4 + r][lane & 15] = acc[r];
        __syncthreads();

        if (tid < 256) {
            float gv[4];
#pragma unroll
            for (int g2 = 0; g2 < 4; ++g2)
                gv[g2] = gbuf[g2][r_l][c_l] + gbuf[4 + g2][r_l][c_l] + pf[g2];
            float cn = sigmf(gv[1]) * cstate + sigmf(gv[0]) * tanhf(gv[2]);
            float hn = sigmf(gv[3]) * tanhf(cn);
            cstate = cn;
            __builtin_nontemporal_store(hn, &enc_seq[(size_t)s * 65536 + row * 1024 + col]);
            write_frag3_nt(hfrag + ((s + 1) & 1) * 196608, 4, row, col, hn);
            if (s == 79) __builtin_nontemporal_store(cstate, &cglobE[row * 1024 + col]);
            else {
#pragma unroll
                for (int g2 = 0; g2 < 4; ++g2)
                    pf[g2] = Xbig[((size_t)(s + 1) * 64 + row) * 4096 + g2 * 1024 + col];
            }
        }
        tree_barrier(bar, bid >> 5, 8, 32);
    }
}

// ---------------------------------------------------------------------------
// k3: enc-pad (blocks 0..127) CONCURRENT WITH dec warm-up (blocks 128..255).
// XCD-local rg2 = lb&1 (same-XCD blocks share the rg pair).
// ---------------------------------------------------------------------------
__launch_bounds__(512, 1)
__global__ void coop_padwarm(const unsigned short* __restrict__ WencF,
                             const unsigned short* __restrict__ WdecF,
                             const float* __restrict__ benc,
                             const float* __restrict__ Xwarm,
                             const float* __restrict__ cglobE,
                             unsigned short* __restrict__ hfragE,
                             unsigned short* __restrict__ hfragD,
                             float* __restrict__ enc_pad,
                             float* __restrict__ cglobD,
                             float* __restrict__ h_fp32,
                             unsigned* __restrict__ barE,
                             unsigned* __restrict__ barW)
{
    __shared__ unsigned short LDSA[3 * 16384];
    __shared__ float gbuf[8][16][16];
    const int bid = blockIdx.x, tid = threadIdx.x;
    const int w = tid >> 6, lane = tid & 63;
    const int g = w & 3, kh = w >> 2;
    const bool isW = bid >= 128;
    const int lb = bid & 127;
    const int rg2 = lb & 1, cg = lb >> 1;
    const int wbase = g * 64 + cg;
    const int r_l = (tid & 255) >> 4, c_l = tid & 15;
    const int col = cg * 16 + c_l;
    const unsigned short* Wf = isW ? WdecF : WencF;
    unsigned short* hfrag = isW ? hfragD : hfragE;
    unsigned* bar = isW ? barW : barE;

    short8v wreg[48];
#pragma unroll
    for (int i = 0; i < 16; ++i) {
        int kf = kh * 16 + i;
#pragma unroll
        for (int p = 0; p < 3; ++p)
            wreg[i * 3 + p] = *(const short8v*)&Wf[((size_t)(p * 256 + wbase) * 32 + kf) * 512 + lane * 8];
    }

    float cst[2] = {0.f, 0.f};
    float pfx[2][4];
    if (tid < 256) {
#pragma unroll
        for (int l = 0; l < 2; ++l) {
            int row = rg2 * 32 + l * 16 + r_l;
            if (!isW) cst[l] = cglobE[row * 1024 + col];
#pragma unroll
            for (int g2 = 0; g2 < 4; ++g2)
                pfx[l][g2] = isW ? Xwarm[(size_t)row * 4096 + g2 * 1024 + col]
                                 : benc[g2 * 1024 + col];
        }
    }

    for (int s = 0; s < 80; ++s) {
        const unsigned short* hf = hfrag + (s & 1) * 196608;
        unsigned short* hout = hfrag + ((s + 1) & 1) * 196608;
#pragma unroll
        for (int l = 0; l < 2; ++l) {
            const int rgi = rg2 * 2 + l;
            stage_A(LDSA, hf, rgi, tid);
            __syncthreads();
            f32x4 acc = mfma16(LDSA, wreg, kh, lane);
#pragma unroll
            for (int r = 0; r < 4; ++r)
                gbuf[w][(lane >> 4) * 4 + r][lane & 15] = acc[r];
            __syncthreads();
            if (tid < 256) {
                const int row = rgi * 16 + r_l;
                float gv[4];
#pragma unroll
                for (int g2 = 0; g2 < 4; ++g2)
                    gv[g2] = gbuf[g2][r_l][c_l] + gbuf[4 + g2][r_l][c_l] + pfx[l][g2];
                float cn = sigmf(gv[1]) * cst[l] + sigmf(gv[0]) * tanhf(gv[2]);
                float hn = sigmf(gv[3]) * tanhf(cn);
                cst[l] = cn;
                if (!isW)
                    __builtin_nontemporal_store(hn, &enc_pad[(size_t)s * 65536 + row * 1024 + col]);
                write_frag3_nt(hout, 4, row, col, hn);
                if (isW) {
                    if (s == 79) {
                        __builtin_nontemporal_store(hn, &h_fp32[row * 1024 + col]);
                        __builtin_nontemporal_store(cn, &cglobD[row * 1024 + col]);
                    } else {
#pragma unroll
                        for (int g2 = 0; g2 < 4; ++g2)
                            pfx[l][g2] = Xwarm[((size_t)(s + 1) * 64 + row) * 4096 + g2 * 1024 + col];
                    }
                }
            }
            __syncthreads();
        }
        tree_barrier(bar, (lb >> 5), 4, 32);
    }
}

// ---------------------------------------------------------------------------
// k4: attention-decode only, s=80..159. 256 blocks x 512. 3 barriers/step.
// Phase B role: (rp=bid&1 -> rows rp*32..+32, u=bid>>1 -> 32 gate-cols);
// same-XCD blocks share rp (bid&1 fixed per XCD) -> halved frag traffic.
// Phase A'/C role: (b=bid>>2, jc=bid&3). EW2 slice LDS-resident.
// ---------------------------------------------------------------------------
__launch_bounds__(512, 1)
__global__ void coop_dec80(const unsigned short* __restrict__ WihcF,
                           const unsigned short* __restrict__ WhhF,
                           const float* __restrict__ W1,       // [80][2048]
                           const float* __restrict__ EW2,      // [80][64][1024]
                           const float* __restrict__ S_g,
                           const float* __restrict__ ctxS,
                           const float* __restrict__ S_log,
                           const float* __restrict__ enc_pad,
                           const float* __restrict__ prelu_w,
                           const float* __restrict__ h_fp32,
                           const float* __restrict__ cglobD,
                           unsigned short* __restrict__ hfrag,  // 2 bufs (step 80 reads buf0)
                           unsigned short* __restrict__ ctxfrag,
                           float* __restrict__ plog,            // [64][4][80]
                           float* __restrict__ h_all,
                           float* __restrict__ gsum,            // [4][64][1024]
                           unsigned* __restrict__ bar)
{
    __shared__ float EW2T[80 * 256];
    __shared__ float gred[8][1024];
    __shared__ float hq[256];
    __shared__ float wsm[80];
    __shared__ float rbuf[128];
    const int bid = blockIdx.x, tid = threadIdx.x;
    const int w = tid >> 6, lane = tid & 63;
    const int rp = bid & 1, u = bid >> 1;      // Phase B role
    const int kq = w;
    const int b = bid >> 2, jc = bid & 3;      // Phase A'/C role
    const float pw = prelu_w[0];

    // ---- weight slice: 2 coltiles x 8 kf x 3 planes = 48 short8v = 192 VGPR ----
    const unsigned short* Wsrc = (kq < 4) ? WihcF : WhhF;
    const int kfbase = (kq & 3) * 8;
    short8v wreg[48];
#pragma unroll
    for (int ct = 0; ct < 2; ++ct) {
        const int wbase2 = u * 2 + ct;
#pragma unroll
        for (int i = 0; i < 8; ++i) {
#pragma unroll
            for (int p = 0; p < 3; ++p)
                wreg[(ct * 8 + i) * 3 + p] =
                    *(const short8v*)&Wsrc[((size_t)(p * 256 + wbase2) * 32 + kfbase + i) * 512 + lane * 8];
        }
    }

    float cstate = (tid < 256) ? cglobD[b * 1024 + jc * 256 + tid] : 0.f;

    for (int i = tid; i < 80 * 256; i += 512) {
        int ss = i >> 8, j = i & 255;
        EW2T[i] = EW2[((size_t)ss * 64 + b) * 1024 + jc * 256 + j];
    }
    __syncthreads();

    for (int s = 80; s < 160; ++s) {
        unsigned short* hout = hfrag + ((s + 1) & 1) * 196608;
        const unsigned short* hf = hfrag + (s & 1) * 196608;
        const int t = s - 80;

        // ---- Phase A': logits + softmax + f + ctx ----
        if (s == 80) {
            float* hsm_ = (float*)gred;
            for (int i = tid; i < 1024; i += 512) hsm_[i] = h_fp32[b * 1024 + i];
            __syncthreads();
#pragma unroll
            for (int i = 0; i < 10; ++i) {
                int sx = w * 10 + i;
                float p = 0.f;
#pragma unroll
                for (int q = 0; q < 16; ++q)
                    p = fmaf(hsm_[lane + q * 64], W1[(size_t)sx * 2048 + lane + q * 64], p);
#pragma unroll
                for (int off = 32; off; off >>= 1) p += __shfl_down(p, off, 64);
                if (lane == 0) wsm[sx] = p + S_log[((size_t)t * 64 + b) * 80 + sx];
            }
            __syncthreads();
        } else {
            if (tid < 80) {
                float l4 = plog[(b * 4 + 0) * 80 + tid] + plog[(b * 4 + 1) * 80 + tid]
                         + plog[(b * 4 + 2) * 80 + tid] + plog[(b * 4 + 3) * 80 + tid];
                wsm[tid] = l4 + S_log[((size_t)t * 64 + b) * 80 + tid];
            }
            __syncthreads();
        }
        float v = (tid < 80) ? wsm[tid] : -3.4e38f;
        if (tid < 128) rbuf[tid] = v;
        __syncthreads();
        for (int off = 64; off >= 1; off >>= 1) {
            if (tid < off) rbuf[tid] = fmaxf(rbuf[tid], rbuf[tid + off]);
            __syncthreads();
        }
        float mx = rbuf[0];
        __syncthreads();
        float e = (tid < 80) ? __expf(wsm[tid] - mx) : 0.f;
        if (tid < 128) rbuf[tid] = e;
        __syncthreads();
        for (int off = 64; off >= 1; off >>= 1) {
            if (tid < off) rbuf[tid] += rbuf[tid + off];
            __syncthreads();
        }
        float inv = 1.f / rbuf[0];
        __syncthreads();
        if (tid < 80) wsm[tid] = e * inv;
        __syncthreads();
        if (tid < 256) {
            float f = 0.f;
#pragma unroll 8
            for (int ss = 0; ss < 80; ++ss)
                f = fmaf(wsm[ss], EW2T[ss * 256 + tid], f);
            int col = jc * 256 + tid;
            float val = f + ctxS[((size_t)t * 64 + b) * 1024 + col];
            val = (val >= 0.f) ? val : pw * val;
            val += enc_pad[((size_t)t * 64 + b) * 1024 + col];
            write_frag3_nt(ctxfrag, 4, b, col, val);
        }
        tree_barrier(bar, bid >> 5, 8, 32);

        // ---- prefetch Phase-C gate-adds ----
        float pf[4];
        if (tid < 256) {
            const float* xb = S_g + ((size_t)t * 64 + b) * 4096;
            int col = jc * 256 + tid;
#pragma unroll
            for (int g2 = 0; g2 < 4; ++g2) pf[g2] = xb[g2 * 1024 + col];
        }

        // ---- Phase B: gate GEMM partials (rows rp*32..+32, 32 gate-cols) ----
        {
            f32x4 acc[2][2];
#pragma unroll
            for (int rgl = 0; rgl < 2; ++rgl)
#pragma unroll
                for (int ct = 0; ct < 2; ++ct) acc[rgl][ct] = (f32x4){0.f,0.f,0.f,0.f};
            const unsigned short* asrc = (kq < 4) ? ctxfrag : hf;
#pragma unroll
            for (int i = 0; i < 8; ++i) {
                int kfl = kfbase + i;
#pragma unroll
                for (int rgl = 0; rgl < 2; ++rgl) {
                    const int rg = rp * 2 + rgl;
                    const unsigned short* ab = asrc + ((size_t)rg * 32 + kfl) * 512 + lane * 8;
                    short8v a0 = *(const short8v*)&ab[0];
                    short8v a1 = *(const short8v*)&ab[65536];
                    short8v a2 = *(const short8v*)&ab[131072];
#pragma unroll
                    for (int ct = 0; ct < 2; ++ct) {
                        short8v b0 = wreg[(ct * 8 + i) * 3 + 0];
                        short8v b1 = wreg[(ct * 8 + i) * 3 + 1];
                        short8v b2 = wreg[(ct * 8 + i) * 3 + 2];
                        MFMA_(acc[rgl][ct], a0, b0); MFMA_(acc[rgl][ct], a0, b1);
                        MFMA_(acc[rgl][ct], a1, b0); MFMA_(acc[rgl][ct], a1, b1);
                        MFMA_(acc[rgl][ct], a0, b2); MFMA_(acc[rgl][ct], a2, b0);
                    }
                }
            }
#pragma unroll
            for (int rgl = 0; rgl < 2; ++rgl)
#pragma unroll
                for (int ct = 0; ct < 2; ++ct)
#pragma unroll
                    for (int r = 0; r < 4; ++r)
                        gred[w][(rgl * 2 + ct) * 256 + lane * 4 + r] = acc[rgl][ct][r];
            __syncthreads();
#pragma unroll
            for (int e2 = 0; e2 < 2; ++e2) {
                int slot = tid * 2 + e2;
                int t4 = slot >> 8, l = (slot >> 2) & 63, r = slot & 3;
                float sum = 0.f;
#pragma unroll
                for (int w2 = 0; w2 < 8; ++w2) sum += gred[w2][slot];
                int rgl = t4 >> 1, ct = t4 & 1;
                int row = rp * 32 + rgl * 16 + (l >> 4) * 4 + r;
                int fr = (u * 2 + ct) * 16 + (l & 15);     // gate-col in 0..4095
                __builtin_nontemporal_store(sum,
                    &gsum[((size_t)(fr >> 10) * 64 + row) * 1024 + (fr & 1023)]);
            }
        }
        tree_barrier(bar, bid >> 5, 8, 32);

        // ---- Phase C: pointwise gates + h + plog partials ----
        if (tid < 256) {
            int col = jc * 256 + tid;
            float gv[4];
#pragma unroll
            for (int g2 = 0; g2 < 4; ++g2)
                gv[g2] = gsum[((size_t)g2 * 64 + b) * 1024 + col] + pf[g2];
            float cn = sigmf(gv[1]) * cstate + sigmf(gv[0]) * tanhf(gv[2]);
            float hn = sigmf(gv[3]) * tanhf(cn);
            cstate = cn;
            __builtin_nontemporal_store(hn, &h_all[((size_t)t * 64 + b) * 1024 + col]);
            write_frag3_nt(hout, 4, b, col, hn);
            hq[tid] = hn;
        }
        __syncthreads();
        if (s < 159) {
#pragma unroll
            for (int i = 0; i < 10; ++i) {
                int sx = w * 10 + i;
                float p = 0.f;
#pragma unroll
                for (int q = 0; q < 4; ++q)
                    p = fmaf(hq[lane + q * 64], W1[(size_t)sx * 2048 + jc * 256 + lane + q * 64], p);
#pragma unroll
                for (int off = 32; off; off >>= 1) p += __shfl_down(p, off, 64);
                if (lane == 0) __builtin_nontemporal_store(p, &plog[(b * 4 + jc) * 80 + sx]);
            }
        }
        tree_barrier(bar, bid >> 5, 8, 32);
    }
}

// ---------------------------------------------------------------------------
extern "C" void kernel_launch(void* const* d_in, const int* in_sizes, int n_in,
                              void* d_out, int out_size, void* d_ws, size_t ws_size,
                              hipStream_t stream)
{
    (void)in_sizes; (void)n_in; (void)out_size; (void)ws_size;

    const float* input_data     = (const float*)d_in[0];
    const float* correct_answer = (const float*)d_in[1];
    const float* enc_W_ih = (const float*)d_in[2];
    const float* enc_W_hh = (const float*)d_in[3];
    const float* enc_b_ih = (const float*)d_in[4];
    const float* enc_b_hh = (const float*)d_in[5];
    const float* dec_W_ih = (const float*)d_in[6];
    const float* dec_W_hh = (const float*)d_in[7];
    const float* dec_b_ih = (const float*)d_in[8];
    const float* dec_b_hh = (const float*)d_in[9];
    const float* in_emb_W = (const float*)d_in[10];
    const float* in_emb_b = (const float*)d_in[11];
    const float* out_emb_W = (const float*)d_in[12];
    const float* out_emb_b = (const float*)d_in[13];
    const float* att_W1 = (const float*)d_in[14];
    const float* att_b1 = (const float*)d_in[15];
    const float* att_W2 = (const float*)d_in[16];
    const float* att_b2 = (const float*)d_in[17];
    const float* prelu_w = (const float*)d_in[18];

    float* out = (float*)d_out;
    char* ws = (char*)d_ws;

    // ---- d_out scratch (all reads precede final vocab GEMM) ----
    float* Xbig    = out;
    float* S_g     = out + 20971520;
    float* ctxS    = out + 41943040;
    float* S_log   = out + 47185920;
    float* samples = out + 47595520;
    float* EW2     = out + 52838400;
    unsigned short* WencF = (unsigned short*)(out + 58081280);
    unsigned short* WhhDF = (unsigned short*)(out + 64372736);
    unsigned short* WihcF = (unsigned short*)(out + 70664192);

    // ---- d_ws map ----
    size_t off = 0;
    auto alloc = [&](size_t nfloats) { float* p = (float*)(ws + off); off += nfloats * 4; return p; };
    float* enc_seq = alloc(80 * 64 * 1024);
    float* enc_pad = alloc(80 * 64 * 1024);
    float* h_all   = alloc(80 * 64 * 1024);
    float* benc    = alloc(4096);
    float* bdec    = alloc(4096);
    float* zb      = alloc(1024);
    float* hfragE_f = alloc(196608);
    float* hfragD_f = alloc(196608);
    float* ctxfrag_f= alloc(98304);
    float* plog     = alloc(64 * 4 * 80);
    float* gsum     = alloc(262144);
    float* cglobE   = alloc(65536);
    float* cglobD   = alloc(65536);
    float* h_fp32   = alloc(65536);
    float* bar_f    = alloc(2048);
    unsigned short* hfragE  = (unsigned short*)hfragE_f;
    unsigned short* hfragD  = (unsigned short*)hfragD_f;
    unsigned short* ctxfrag = (unsigned short*)ctxfrag_f;
    unsigned* barE1 = (unsigned*)bar_f;
    unsigned* barPE = ((unsigned*)bar_f) + 512;
    unsigned* barPW = ((unsigned*)bar_f) + 1024;
    unsigned* barD  = ((unsigned*)bar_f) + 1536;

    auto big3 = [&](const float* A, int lda, const float* W, int ldw,
                    float* C, int ldc, const float* bias, int M, int N, int K) {
        dim3 g((N + 127) / 128, (M + 127) / 128);
        hipLaunchKernelGGL((gemm_mfma_split<3>), g, dim3(256), 0, stream,
                           A, lda, W, ldw, C, ldc, bias, M, N, K);
    };

    // ---- setup ----
    hipLaunchKernelGGL(vec_add2, dim3(16), dim3(256), 0, stream, enc_b_ih, enc_b_hh, benc, 4096);
    hipLaunchKernelGGL(vec_add2, dim3(16), dim3(256), 0, stream, dec_b_ih, dec_b_hh, bdec, 4096);
    hipLaunchKernelGGL(zero_f, dim3(4), dim3(256), 0, stream, zb, 1024);
    hipLaunchKernelGGL(zero_f, dim3(768), dim3(256), 0, stream, hfragE_f, 196608);
    hipLaunchKernelGGL(zero_f, dim3(768), dim3(256), 0, stream, hfragD_f, 196608);
    hipLaunchKernelGGL(zero_f, dim3(8), dim3(256), 0, stream, bar_f, 2048);

    // ---- weight frag rearranges ----
    hipLaunchKernelGGL(rearr_frag, dim3(2048), dim3(256), 0, stream, enc_W_hh, 1024, 0, WencF, 4096, 1024);
    hipLaunchKernelGGL(rearr_frag, dim3(2048), dim3(256), 0, stream, dec_W_hh, 1024, 0, WhhDF, 4096, 1024);
    hipLaunchKernelGGL(rearr_frag, dim3(2048), dim3(256), 0, stream, dec_W_ih, 2048, 1024, WihcF, 4096, 1024);

    // ---- batched big GEMMs (NS=3) ----
    big3(input_data, 4096, enc_W_ih, 4096, Xbig, 4096, benc, 5120, 4096, 4096);
    hipLaunchKernelGGL(sample0_fill, dim3(256), dim3(256), 0, stream, in_emb_W, in_emb_b, samples);
    big3(correct_answer + (size_t)64 * 20000, 20000, in_emb_W, 20000,
         samples + 65536, 1024, in_emb_b, 5056, 1024, 20000);
    big3(samples, 1024, dec_W_ih, 2048, S_g, 4096, bdec, 5120, 4096, 1024);
    big3(samples, 1024, att_W2, 2048, ctxS, 1024, att_b2, 5120, 1024, 1024);
    big3(samples, 1024, att_W1 + 1024, 2048, S_log, 80, att_b1, 5120, 80, 1024);

    // ---- k1: encoder real (80 steps) ----
    hipLaunchKernelGGL(coop_enc80, dim3(256), dim3(512), 0, stream,
                       WencF, Xbig, hfragE, enc_seq, cglobE, barE1);

    // ---- Xwarm + EW2 projections (need enc_seq) ----
    big3(enc_seq, 1024, dec_W_ih, 2048, Xbig, 4096, bdec, 5120, 4096, 1024);
    big3(enc_seq, 1024, att_W2 + 1024, 2048, EW2, 1024, zb, 5120, 1024, 1024);

    // ---- k3: enc-pad || dec warm-up (80 steps, overlapped) ----
    hipLaunchKernelGGL(coop_padwarm, dim3(256), dim3(512), 0, stream,
                       WencF, WhhDF, benc, Xbig, cglobE,
                       hfragE, hfragD, enc_pad, cglobD, h_fp32, barPE, barPW);

    // ---- k4: attention decode (80 steps) ----
    hipLaunchKernelGGL(coop_dec80, dim3(256), dim3(512), 0, stream,
                       WihcF, WhhDF, att_W1, EW2, S_g, ctxS, S_log,
                       enc_pad, prelu_w, h_fp32, cglobD,
                       hfragD, ctxfrag, plog, h_all, gsum, barD);

    // ---- final vocab projection (NS=1, output-facing) ----
    {
        dim3 g((20000 + 127) / 128, (5120 + 127) / 128);
        hipLaunchKernelGGL((gemm_mfma_split<1>), g, dim3(256), 0, stream,
                           h_all, 1024, out_emb_W, 1024, out, 20000, out_emb_b, 5120, 20000, 1024);
    }
}

// Round 13
// 14665.955 us; speedup vs baseline: 3.5812x; 1.0208x over previous
//
#include <hip/hip_runtime.h>
#include <cstddef>
#include <cstdint>

typedef __attribute__((ext_vector_type(8))) short short8v;
typedef __attribute__((ext_vector_type(4))) float f32x4;

__device__ __forceinline__ float sigmf(float x) { return 1.0f / (1.0f + __expf(-x)); }

__device__ __forceinline__ unsigned short bf16_rn(float x) {
    union { float f; unsigned u; } v; v.f = x;
    unsigned r = v.u + 0x7FFF + ((v.u >> 16) & 1);
    return (unsigned short)(r >> 16);
}
__device__ __forceinline__ float bf16_to_f(unsigned short h) {
    union { unsigned u; float f; } v; v.u = ((unsigned)h) << 16; return v.f;
}
__device__ __forceinline__ unsigned long long pack4(unsigned short a, unsigned short b,
                                                    unsigned short c, unsigned short d) {
    return (unsigned long long)a | ((unsigned long long)b << 16)
         | ((unsigned long long)c << 32) | ((unsigned long long)d << 48);
}

#define MFMA_(d, va, vb) d = __builtin_amdgcn_mfma_f32_16x16x32_bf16(va, vb, d, 0, 0, 0)

#define AT_LD(p)        __hip_atomic_load((p), __ATOMIC_RELAXED, __HIP_MEMORY_SCOPE_AGENT)
#define AT_ST(p, v)     __hip_atomic_store((p), (v), __ATOMIC_RELAXED, __HIP_MEMORY_SCOPE_AGENT)
#define AT_ST_REL(p, v) __hip_atomic_store((p), (v), __ATOMIC_RELEASE, __HIP_MEMORY_SCOPE_AGENT)
#define AT_ADD(p, v)    __hip_atomic_fetch_add((p), (v), __ATOMIC_RELAXED, __HIP_MEMORY_SCOPE_AGENT)

// ---------------------------------------------------------------------------
// Fragment layout (A and W): F[p][rgw][kf][l][e]; rgw=r>>4, kf=k>>5,
// l=((k>>3)&3)*16+(r&15), e=k&7. Per-(p,rgw) chunk = 32*64*8 = 16384 shorts.
// ---------------------------------------------------------------------------
__device__ __forceinline__ void write_frag3_nt(unsigned short* __restrict__ dst, int NRGW,
                                               int r, int k, float x)
{
    unsigned short hi = bf16_rn(x); float r1 = x - bf16_to_f(hi);
    unsigned short md = bf16_rn(r1);
    unsigned short lo = bf16_rn(r1 - bf16_to_f(md));
    int base = (((r >> 4) * 32 + (k >> 5)) * 64 + ((k >> 3) & 3) * 16 + (r & 15)) * 8 + (k & 7);
    int ps = NRGW * 16384;
    __builtin_nontemporal_store(hi, &dst[base]);
    __builtin_nontemporal_store(md, &dst[ps + base]);
    __builtin_nontemporal_store(lo, &dst[2 * ps + base]);
}

__launch_bounds__(256)
__global__ void rearr_frag(const float* __restrict__ src, int ld, int c0,
                           unsigned short* __restrict__ dst, int R, int K)
{
    int idx = blockIdx.x * 256 + threadIdx.x;
    int kpr = K >> 3;
    if (idx >= R * kpr) return;
    int r = idx / kpr, k = (idx % kpr) * 8;
    int NRGW = R >> 4;
    const float* s = src + (size_t)r * ld + c0 + k;
    float4 v0 = *(const float4*)s, v1 = *(const float4*)(s + 4);
    float xs[8] = {v0.x, v0.y, v0.z, v0.w, v1.x, v1.y, v1.z, v1.w};
    unsigned short hi[8], md[8], lo[8];
#pragma unroll
    for (int e = 0; e < 8; ++e) {
        hi[e] = bf16_rn(xs[e]); float r1 = xs[e] - bf16_to_f(hi[e]);
        md[e] = bf16_rn(r1);
        lo[e] = bf16_rn(r1 - bf16_to_f(md[e]));
    }
    int base = (((r >> 4) * 32 + (k >> 5)) * 64 + ((k >> 3) & 3) * 16 + (r & 15)) * 8;
    size_t ps = (size_t)NRGW * 16384;
    *(unsigned long long*)&dst[base]          = pack4(hi[0], hi[1], hi[2], hi[3]);
    *(unsigned long long*)&dst[base + 4]      = pack4(hi[4], hi[5], hi[6], hi[7]);
    *(unsigned long long*)&dst[ps + base]     = pack4(md[0], md[1], md[2], md[3]);
    *(unsigned long long*)&dst[ps + base + 4] = pack4(md[4], md[5], md[6], md[7]);
    *(unsigned long long*)&dst[2*ps + base]     = pack4(lo[0], lo[1], lo[2], lo[3]);
    *(unsigned long long*)&dst[2*ps + base + 4] = pack4(lo[4], lo[5], lo[6], lo[7]);
}

// ---------------------------------------------------------------------------
// Two-level tree barrier; gidx = this block's group, ng groups, bpg blocks ea.
// ---------------------------------------------------------------------------
__device__ __forceinline__ void tree_barrier(unsigned* bar, int gidx, int ng, int bpg)
{
    __syncthreads();
    if (threadIdx.x == 0) {
        unsigned* gcnt = bar + gidx * 32;
        unsigned* ggen = bar + gidx * 32 + 1;
        unsigned* rcnt = bar + ng * 32;
        unsigned* rgen = bar + ng * 32 + 1;
        __threadfence();   // release
        unsigned mygen = AT_LD(ggen);
        unsigned prev = AT_ADD(gcnt, 1u);
        if (prev == (unsigned)(bpg - 1)) {
            AT_ST(gcnt, 0u);
            unsigned rg = AT_LD(rgen);
            unsigned rprev = AT_ADD(rcnt, 1u);
            if (rprev == (unsigned)(ng - 1)) {
                AT_ST(rcnt, 0u);
                AT_ST_REL(rgen, rg + 1u);
            } else {
                while (AT_LD(rgen) == rg) __builtin_amdgcn_s_sleep(1);
            }
            AT_ST_REL(ggen, mygen + 1u);
        } else {
            while (AT_LD(ggen) == mygen) __builtin_amdgcn_s_sleep(1);
        }
        __threadfence();   // acquire
    }
    __syncthreads();
}

// ---------------------------------------------------------------------------
// Batched fp32 GEMM via bf16-split MFMA (validated R3): C = A@W^T + bias.
// ---------------------------------------------------------------------------
template <int NS>
__launch_bounds__(256, 2)
__global__ void gemm_mfma_split(const float* __restrict__ A, int lda,
                                const float* __restrict__ W, int ldw,
                                float* __restrict__ C, int ldc,
                                const float* __restrict__ bias,
                                int M, int N, int K)
{
    __shared__ unsigned short Abf[NS][128][40];
    __shared__ unsigned short Bbf[NS][128][40];
    const int tid = threadIdx.x;
    const int m0 = blockIdx.y * 128, n0 = blockIdx.x * 128;
    const int wave = tid >> 6, lane = tid & 63;
    const int wr = wave >> 1, wc = wave & 1;
    const int lr = lane & 15, lk = (lane >> 4) * 8;

    f32x4 acc[4][4];
#pragma unroll
    for (int i = 0; i < 4; ++i)
#pragma unroll
        for (int j = 0; j < 4; ++j) acc[i][j] = (f32x4){0.f, 0.f, 0.f, 0.f};

    const int arow = tid >> 1;
    const int akh  = (tid & 1) * 16;
    int gr = m0 + arow; if (gr > M - 1) gr = M - 1;
    int gn = n0 + arow; if (gn > N - 1) gn = N - 1;
    const float* aptr = A + (size_t)gr * lda + akh;
    const float* wptr = W + (size_t)gn * ldw + akh;

    for (int k0 = 0; k0 < K; k0 += 32) {
#pragma unroll
        for (int q = 0; q < 4; ++q) {
            float4 v = *(const float4*)(aptr + k0 + q * 4);
            float xs[4] = {v.x, v.y, v.z, v.w};
            unsigned short h[4], hm[4], hl[4];
#pragma unroll
            for (int e = 0; e < 4; ++e) {
                h[e] = bf16_rn(xs[e]);
                if (NS == 3) {
                    float r1 = xs[e] - bf16_to_f(h[e]);
                    hm[e] = bf16_rn(r1);
                    hl[e] = bf16_rn(r1 - bf16_to_f(hm[e]));
                }
            }
            *(unsigned long long*)&Abf[0][arow][akh + q * 4] = pack4(h[0], h[1], h[2], h[3]);
            if (NS == 3) {
                *(unsigned long long*)&Abf[1][arow][akh + q * 4] = pack4(hm[0], hm[1], hm[2], hm[3]);
                *(unsigned long long*)&Abf[2][arow][akh + q * 4] = pack4(hl[0], hl[1], hl[2], hl[3]);
            }
        }
#pragma unroll
        for (int q = 0; q < 4; ++q) {
            float4 v = *(const float4*)(wptr + k0 + q * 4);
            float xs[4] = {v.x, v.y, v.z, v.w};
            unsigned short h[4], hm[4], hl[4];
#pragma unroll
            for (int e = 0; e < 4; ++e) {
                h[e] = bf16_rn(xs[e]);
                if (NS == 3) {
                    float r1 = xs[e] - bf16_to_f(h[e]);
                    hm[e] = bf16_rn(r1);
                    hl[e] = bf16_rn(r1 - bf16_to_f(hm[e]));
                }
            }
            *(unsigned long long*)&Bbf[0][arow][akh + q * 4] = pack4(h[0], h[1], h[2], h[3]);
            if (NS == 3) {
                *(unsigned long long*)&Bbf[1][arow][akh + q * 4] = pack4(hm[0], hm[1], hm[2], hm[3]);
                *(unsigned long long*)&Bbf[2][arow][akh + q * 4] = pack4(hl[0], hl[1], hl[2], hl[3]);
            }
        }
        __syncthreads();

        short8v a[NS][4], b[4];
#pragma unroll
        for (int p = 0; p < NS; ++p)
#pragma unroll
            for (int i = 0; i < 4; ++i)
                a[p][i] = *(const short8v*)&Abf[p][wr * 64 + i * 16 + lr][lk];
#pragma unroll
        for (int q = 0; q < NS; ++q) {
#pragma unroll
            for (int j = 0; j < 4; ++j)
                b[j] = *(const short8v*)&Bbf[q][wc * 64 + j * 16 + lr][lk];
            const int pmax = (NS == 1) ? 1 : (3 - q);
#pragma unroll
            for (int p = 0; p < 3; ++p) {
                if (p >= pmax) break;
#pragma unroll
                for (int i = 0; i < 4; ++i)
#pragma unroll
                    for (int j = 0; j < 4; ++j)
                        acc[i][j] = __builtin_amdgcn_mfma_f32_16x16x32_bf16(
                            a[p][i], b[j], acc[i][j], 0, 0, 0);
            }
        }
        __syncthreads();
    }

    const int crow = (lane >> 4) * 4;
#pragma unroll
    for (int i = 0; i < 4; ++i) {
        int mbase = m0 + wr * 64 + i * 16 + crow;
#pragma unroll
        for (int j = 0; j < 4; ++j) {
            int n = n0 + wc * 64 + j * 16 + lr;
            if (n < N) {
                float bv = bias[n];
#pragma unroll
                for (int r = 0; r < 4; ++r) {
                    int m = mbase + r;
                    if (m < M) C[(size_t)m * ldc + n] = acc[i][j][r] + bv;
                }
            }
        }
    }
}

__launch_bounds__(256)
__global__ void zero_f(float* __restrict__ p, int n)
{
    int i = blockIdx.x * 256 + threadIdx.x;
    if (i < n) p[i] = 0.f;
}

__launch_bounds__(256)
__global__ void vec_add2(const float* __restrict__ a, const float* __restrict__ b,
                         float* __restrict__ o, int n)
{
    int i = blockIdx.x * 256 + threadIdx.x;
    if (i < n) o[i] = a[i] + b[i];
}

__launch_bounds__(256)
__global__ void sample0_fill(const float* __restrict__ emW, const float* __restrict__ emb,
                             float* __restrict__ samples)
{
    int idx = blockIdx.x * 256 + threadIdx.x; // 65536
    int d = idx & 1023;
    samples[idx] = emW[(size_t)d * 20000 + 19998] + emb[d];
}

// stage one rg-chunk (96KB) of a 64-row frag buffer into LDS
__device__ __forceinline__ void stage_A(unsigned short* __restrict__ LDSA,
                                        const unsigned short* __restrict__ src,
                                        int rg, int tid)
{
#pragma unroll
    for (int p = 0; p < 3; ++p) {
        const unsigned short* sp = src + (size_t)(p * 4 + rg) * 16384;
        unsigned short* dp = LDSA + p * 16384;
#pragma unroll
        for (int it = 0; it < 4; ++it) {
            int idx = tid + it * 512;
            *(short8v*)&dp[idx * 8] = *(const short8v*)&sp[idx * 8];
        }
    }
}

// 16-kf MFMA block from LDSA rg-chunk vs wreg (encoder-style, in-block gates)
__device__ __forceinline__ f32x4 mfma16(const unsigned short* __restrict__ LDSA,
                                        const short8v* __restrict__ wreg,
                                        int kh, int lane)
{
    f32x4 acc0 = (f32x4){0.f,0.f,0.f,0.f}, acc1 = acc0;
#pragma unroll
    for (int i = 0; i < 16; ++i) {
        int kf = kh * 16 + i;
        short8v a0 = *(const short8v*)&LDSA[(kf * 64 + lane) * 8];
        short8v a1 = *(const short8v*)&LDSA[16384 + (kf * 64 + lane) * 8];
        short8v a2 = *(const short8v*)&LDSA[32768 + (kf * 64 + lane) * 8];
        short8v b0 = wreg[i * 3 + 0], b1 = wreg[i * 3 + 1], b2 = wreg[i * 3 + 2];
        f32x4& A = (i & 1) ? acc1 : acc0;
        MFMA_(A, a0, b0); MFMA_(A, a0, b1); MFMA_(A, a1, b0);
        MFMA_(A, a1, b1); MFMA_(A, a0, b2); MFMA_(A, a2, b0);
    }
    return acc0 + acc1;
}

// ---------------------------------------------------------------------------
// k1: encoder real steps 0..79. 256 blocks x 512. 1 barrier/step.
// XCD-local rg: rg = bid&3. waves_per_eu(1) -> allow 256-VGPR alloc (wreg[48]).
// ---------------------------------------------------------------------------
__launch_bounds__(512, 1)
__attribute__((amdgpu_waves_per_eu(1, 2)))
__global__ void coop_enc80(const unsigned short* __restrict__ WencF,
                           const float* __restrict__ Xbig,
                           unsigned short* __restrict__ hfrag,   // 2 bufs x 196608
                           float* __restrict__ enc_seq,
                           float* __restrict__ cglobE,
                           unsigned* __restrict__ bar)
{
    __shared__ unsigned short LDSA[3 * 16384];
    __shared__ float gbuf[8][16][16];
    const int bid = blockIdx.x, tid = threadIdx.x;
    const int w = tid >> 6, lane = tid & 63;
    const int g = w & 3, kh = w >> 2;
    const int rg = bid & 3, cg = bid >> 2;
    const int wbase = g * 64 + cg;
    const int r_l = (tid & 255) >> 4, c_l = tid & 15;
    const int row = rg * 16 + r_l, col = cg * 16 + c_l;
    float cstate = 0.f;

    short8v wreg[48];
#pragma unroll
    for (int i = 0; i < 16; ++i) {
        int kf = kh * 16 + i;
#pragma unroll
        for (int p = 0; p < 3; ++p)
            wreg[i * 3 + p] = *(const short8v*)&WencF[((size_t)(p * 256 + wbase) * 32 + kf) * 512 + lane * 8];
    }

    float pf[4];
    if (tid < 256) {
#pragma unroll
        for (int g2 = 0; g2 < 4; ++g2)
            pf[g2] = Xbig[(size_t)row * 4096 + g2 * 1024 + col];
    }

    for (int s = 0; s < 80; ++s) {
        const unsigned short* hf = hfrag + (s & 1) * 196608;
        stage_A(LDSA, hf, rg, tid);
        __syncthreads();
        f32x4 acc = mfma16(LDSA, wreg, kh, lane);
#pragma unroll
        for (int r = 0; r < 4; ++r)
            gbuf[w][(lane >> 4) * 4 + r][lane & 15] = acc[r];
        __syncthreads();

        if (tid < 256) {
            float gv[4];
#pragma unroll
            for (int g2 = 0; g2 < 4; ++g2)
                gv[g2] = gbuf[g2][r_l][c_l] + gbuf[4 + g2][r_l][c_l] + pf[g2];
            float cn = sigmf(gv[1]) * cstate + sigmf(gv[0]) * tanhf(gv[2]);
            float hn = sigmf(gv[3]) * tanhf(cn);
            cstate = cn;
            __builtin_nontemporal_store(hn, &enc_seq[(size_t)s * 65536 + row * 1024 + col]);
            write_frag3_nt(hfrag + ((s + 1) & 1) * 196608, 4, row, col, hn);
            if (s == 79) __builtin_nontemporal_store(cstate, &cglobE[row * 1024 + col]);
            else {
#pragma unroll
                for (int g2 = 0; g2 < 4; ++g2)
                    pf[g2] = Xbig[((size_t)(s + 1) * 64 + row) * 4096 + g2 * 1024 + col];
            }
        }
        tree_barrier(bar, bid >> 5, 8, 32);
    }
}

// ---------------------------------------------------------------------------
// k3: enc-pad (blocks 0..127) CONCURRENT WITH dec warm-up (blocks 128..255).
// XCD-local rg2 = lb&1. waves_per_eu(1) to avoid wreg[48] spill.
// ---------------------------------------------------------------------------
__launch_bounds__(512, 1)
__attribute__((amdgpu_waves_per_eu(1, 2)))
__global__ void coop_padwarm(const unsigned short* __restrict__ WencF,
                             const unsigned short* __restrict__ WdecF,
                             const float* __restrict__ benc,
                             const float* __restrict__ Xwarm,
                             const float* __restrict__ cglobE,
                             unsigned short* __restrict__ hfragE,
                             unsigned short* __restrict__ hfragD,
                             float* __restrict__ enc_pad,
                             float* __restrict__ cglobD,
                             float* __restrict__ h_fp32,
                             unsigned* __restrict__ barE,
                             unsigned* __restrict__ barW)
{
    __shared__ unsigned short LDSA[3 * 16384];
    __shared__ float gbuf[8][16][16];
    const int bid = blockIdx.x, tid = threadIdx.x;
    const int w = tid >> 6, lane = tid & 63;
    const int g = w & 3, kh = w >> 2;
    const bool isW = bid >= 128;
    const int lb = bid & 127;
    const int rg2 = lb & 1, cg = lb >> 1;
    const int wbase = g * 64 + cg;
    const int r_l = (tid & 255) >> 4, c_l = tid & 15;
    const int col = cg * 16 + c_l;
    const unsigned short* Wf = isW ? WdecF : WencF;
    unsigned short* hfrag = isW ? hfragD : hfragE;
    unsigned* bar = isW ? barW : barE;

    short8v wreg[48];
#pragma unroll
    for (int i = 0; i < 16; ++i) {
        int kf = kh * 16 + i;
#pragma unroll
        for (int p = 0; p < 3; ++p)
            wreg[i * 3 + p] = *(const short8v*)&Wf[((size_t)(p * 256 + wbase) * 32 + kf) * 512 + lane * 8];
    }

    float cst[2] = {0.f, 0.f};
    float pfx[2][4];
    if (tid < 256) {
#pragma unroll
        for (int l = 0; l < 2; ++l) {
            int row = rg2 * 32 + l * 16 + r_l;
            if (!isW) cst[l] = cglobE[row * 1024 + col];
#pragma unroll
            for (int g2 = 0; g2 < 4; ++g2)
                pfx[l][g2] = isW ? Xwarm[(size_t)row * 4096 + g2 * 1024 + col]
                                 : benc[g2 * 1024 + col];
        }
    }

    for (int s = 0; s < 80; ++s) {
        const unsigned short* hf = hfrag + (s & 1) * 196608;
        unsigned short* hout = hfrag + ((s + 1) & 1) * 196608;
#pragma unroll
        for (int l = 0; l < 2; ++l) {
            const int rgi = rg2 * 2 + l;
            stage_A(LDSA, hf, rgi, tid);
            __syncthreads();
            f32x4 acc = mfma16(LDSA, wreg, kh, lane);
#pragma unroll
            for (int r = 0; r < 4; ++r)
                gbuf[w][(lane >> 4) * 4 + r][lane & 15] = acc[r];
            __syncthreads();
            if (tid < 256) {
                const int row = rgi * 16 + r_l;
                float gv[4];
#pragma unroll
                for (int g2 = 0; g2 < 4; ++g2)
                    gv[g2] = gbuf[g2][r_l][c_l] + gbuf[4 + g2][r_l][c_l] + pfx[l][g2];
                float cn = sigmf(gv[1]) * cst[l] + sigmf(gv[0]) * tanhf(gv[2]);
                float hn = sigmf(gv[3]) * tanhf(cn);
                cst[l] = cn;
                if (!isW)
                    __builtin_nontemporal_store(hn, &enc_pad[(size_t)s * 65536 + row * 1024 + col]);
                write_frag3_nt(hout, 4, row, col, hn);
                if (isW) {
                    if (s == 79) {
                        __builtin_nontemporal_store(hn, &h_fp32[row * 1024 + col]);
                        __builtin_nontemporal_store(cn, &cglobD[row * 1024 + col]);
                    } else {
#pragma unroll
                        for (int g2 = 0; g2 < 4; ++g2)
                            pfx[l][g2] = Xwarm[((size_t)(s + 1) * 64 + row) * 4096 + g2 * 1024 + col];
                    }
                }
            }
            __syncthreads();
        }
        tree_barrier(bar, (lb >> 5), 4, 32);
    }
}

// ---------------------------------------------------------------------------
// k4: attention-decode only, s=80..159. 256 blocks x 512. 3 barriers/step.
// R11-proven version: Phase B role (gg,cg), wreg[24] (96 VGPR, no spill).
// Phase A'/C role (b,jc). EW2 slice LDS-resident. First step full logits.
// ---------------------------------------------------------------------------
__launch_bounds__(512, 2)
__global__ void coop_dec80(const unsigned short* __restrict__ WihcF,
                           const unsigned short* __restrict__ WhhF,
                           const float* __restrict__ W1,       // [80][2048]
                           const float* __restrict__ EW2,      // [80][64][1024]
                           const float* __restrict__ S_g,
                           const float* __restrict__ ctxS,
                           const float* __restrict__ S_log,
                           const float* __restrict__ enc_pad,
                           const float* __restrict__ prelu_w,
                           const float* __restrict__ h_fp32,
                           const float* __restrict__ cglobD,
                           unsigned short* __restrict__ hfrag,  // 2 bufs (step 80 reads buf0)
                           unsigned short* __restrict__ ctxfrag,
                           float* __restrict__ plog,            // [64][4][80]
                           float* __restrict__ h_all,
                           float* __restrict__ gsum,            // [4][64][1024]
                           unsigned* __restrict__ bar)
{
    __shared__ float EW2T[80 * 256];
    __shared__ float gred[8][1024];
    __shared__ float hq[256];
    __shared__ float wsm[80];
    __shared__ float rbuf[128];
    const int bid = blockIdx.x, tid = threadIdx.x;
    const int w = tid >> 6, lane = tid & 63;
    const int gg = bid >> 6, cg = bid & 63;
    const int wbase = gg * 64 + cg;
    const int kq = w;
    const int b = bid >> 2, jc = bid & 3;
    const float pw = prelu_w[0];

    // ---- weight slice: 8 kf x 3 planes = 96 VGPRs ----
    const unsigned short* Wsrc = (kq < 4) ? WihcF : WhhF;
    const int kfbase = (kq & 3) * 8;
    short8v wreg[24];
#pragma unroll
    for (int i = 0; i < 8; ++i) {
#pragma unroll
        for (int p = 0; p < 3; ++p)
            wreg[i * 3 + p] = *(const short8v*)&Wsrc[((size_t)(p * 256 + wbase) * 32 + kfbase + i) * 512 + lane * 8];
    }

    float cstate = (tid < 256) ? cglobD[b * 1024 + jc * 256 + tid] : 0.f;

    for (int i = tid; i < 80 * 256; i += 512) {
        int ss = i >> 8, j = i & 255;
        EW2T[i] = EW2[((size_t)ss * 64 + b) * 1024 + jc * 256 + j];
    }
    __syncthreads();

    for (int s = 80; s < 160; ++s) {
        unsigned short* hout = hfrag + ((s + 1) & 1) * 196608;
        const unsigned short* hf = hfrag + (s & 1) * 196608;
        const int t = s - 80;

        // ---- Phase A': logits + softmax + f + ctx ----
        if (s == 80) {
            float* hsm_ = (float*)gred;
            for (int i = tid; i < 1024; i += 512) hsm_[i] = h_fp32[b * 1024 + i];
            __syncthreads();
#pragma unroll
            for (int i = 0; i < 10; ++i) {
                int sx = w * 10 + i;
                float p = 0.f;
#pragma unroll
                for (int q = 0; q < 16; ++q)
                    p = fmaf(hsm_[lane + q * 64], W1[(size_t)sx * 2048 + lane + q * 64], p);
#pragma unroll
                for (int off = 32; off; off >>= 1) p += __shfl_down(p, off, 64);
                if (lane == 0) wsm[sx] = p + S_log[((size_t)t * 64 + b) * 80 + sx];
            }
            __syncthreads();
        } else {
            if (tid < 80) {
                float l4 = plog[(b * 4 + 0) * 80 + tid] + plog[(b * 4 + 1) * 80 + tid]
                         + plog[(b * 4 + 2) * 80 + tid] + plog[(b * 4 + 3) * 80 + tid];
                wsm[tid] = l4 + S_log[((size_t)t * 64 + b) * 80 + tid];
            }
            __syncthreads();
        }
        float v = (tid < 80) ? wsm[tid] : -3.4e38f;
        if (tid < 128) rbuf[tid] = v;
        __syncthreads();
        for (int off = 64; off >= 1; off >>= 1) {
            if (tid < off) rbuf[tid] = fmaxf(rbuf[tid], rbuf[tid + off]);
            __syncthreads();
        }
        float mx = rbuf[0];
        __syncthreads();
        float e = (tid < 80) ? __expf(wsm[tid] - mx) : 0.f;
        if (tid < 128) rbuf[tid] = e;
        __syncthreads();
        for (int off = 64; off >= 1; off >>= 1) {
            if (tid < off) rbuf[tid] += rbuf[tid + off];
            __syncthreads();
        }
        float inv = 1.f / rbuf[0];
        __syncthreads();
        if (tid < 80) wsm[tid] = e * inv;
        __syncthreads();
        if (tid < 256) {
            float f = 0.f;
#pragma unroll 8
            for (int ss = 0; ss < 80; ++ss)
                f = fmaf(wsm[ss], EW2T[ss * 256 + tid], f);
            int col = jc * 256 + tid;
            float val = f + ctxS[((size_t)t * 64 + b) * 1024 + col];
            val = (val >= 0.f) ? val : pw * val;
            val += enc_pad[((size_t)t * 64 + b) * 1024 + col];
            write_frag3_nt(ctxfrag, 4, b, col, val);
        }
        tree_barrier(bar, bid >> 5, 8, 32);

        // ---- prefetch Phase-C gate-adds ----
        float pf[4];
        if (tid < 256) {
            const float* xb = S_g + ((size_t)t * 64 + b) * 4096;
            int col = jc * 256 + tid;
#pragma unroll
            for (int g2 = 0; g2 < 4; ++g2) pf[g2] = xb[g2 * 1024 + col];
        }

        // ---- Phase B: gate GEMM partials ----
        {
            f32x4 acc[4];
#pragma unroll
            for (int rg = 0; rg < 4; ++rg) acc[rg] = (f32x4){0.f,0.f,0.f,0.f};
            const unsigned short* asrc = (kq < 4) ? ctxfrag : hf;
#pragma unroll
            for (int i = 0; i < 8; ++i) {
                int kfl = kfbase + i;
#pragma unroll
                for (int rg = 0; rg < 4; ++rg) {
                    const unsigned short* ab = asrc + ((size_t)rg * 32 + kfl) * 512 + lane * 8;
                    short8v a0 = *(const short8v*)&ab[0];
                    short8v a1 = *(const short8v*)&ab[65536];
                    short8v a2 = *(const short8v*)&ab[131072];
                    short8v b0 = wreg[i * 3 + 0], b1 = wreg[i * 3 + 1], b2 = wreg[i * 3 + 2];
                    MFMA_(acc[rg], a0, b0); MFMA_(acc[rg], a0, b1); MFMA_(acc[rg], a1, b0);
                    MFMA_(acc[rg], a1, b1); MFMA_(acc[rg], a0, b2); MFMA_(acc[rg], a2, b0);
                }
            }
#pragma unroll
            for (int rg = 0; rg < 4; ++rg)
#pragma unroll
                for (int r = 0; r < 4; ++r)
                    gred[w][rg * 256 + lane * 4 + r] = acc[rg][r];
            __syncthreads();
#pragma unroll
            for (int e2 = 0; e2 < 2; ++e2) {
                int slot = tid * 2 + e2;
                int rg = slot >> 8, l = (slot >> 2) & 63, r = slot & 3;
                float sum = 0.f;
#pragma unroll
                for (int w2 = 0; w2 < 8; ++w2) sum += gred[w2][slot];
                int row = rg * 16 + (l >> 4) * 4 + r;
                int col = cg * 16 + (l & 15);
                __builtin_nontemporal_store(sum, &gsum[((size_t)gg * 64 + row) * 1024 + col]);
            }
        }
        tree_barrier(bar, bid >> 5, 8, 32);

        // ---- Phase C: pointwise gates + h + plog partials ----
        if (tid < 256) {
            int col = jc * 256 + tid;
            float gv[4];
#pragma unroll
            for (int g2 = 0; g2 < 4; ++g2)
                gv[g2] = gsum[((size_t)g2 * 64 + b) * 1024 + col] + pf[g2];
            float cn = sigmf(gv[1]) * cstate + sigmf(gv[0]) * tanhf(gv[2]);
            float hn = sigmf(gv[3]) * tanhf(cn);
            cstate = cn;
            __builtin_nontemporal_store(hn, &h_all[((size_t)t * 64 + b) * 1024 + col]);
            write_frag3_nt(hout, 4, b, col, hn);
            hq[tid] = hn;
        }
        __syncthreads();
        if (s < 159) {
#pragma unroll
            for (int i = 0; i < 10; ++i) {
                int sx = w * 10 + i;
                float p = 0.f;
#pragma unroll
                for (int q = 0; q < 4; ++q)
                    p = fmaf(hq[lane + q * 64], W1[(size_t)sx * 2048 + jc * 256 + lane + q * 64], p);
#pragma unroll
                for (int off = 32; off; off >>= 1) p += __shfl_down(p, off, 64);
                if (lane == 0) __builtin_nontemporal_store(p, &plog[(b * 4 + jc) * 80 + sx]);
            }
        }
        tree_barrier(bar, bid >> 5, 8, 32);
    }
}

// ---------------------------------------------------------------------------
extern "C" void kernel_launch(void* const* d_in, const int* in_sizes, int n_in,
                              void* d_out, int out_size, void* d_ws, size_t ws_size,
                              hipStream_t stream)
{
    (void)in_sizes; (void)n_in; (void)out_size; (void)ws_size;

    const float* input_data     = (const float*)d_in[0];
    const float* correct_answer = (const float*)d_in[1];
    const float* enc_W_ih = (const float*)d_in[2];
    const float* enc_W_hh = (const float*)d_in[3];
    const float* enc_b_ih = (const float*)d_in[4];
    const float* enc_b_hh = (const float*)d_in[5];
    const float* dec_W_ih = (const float*)d_in[6];
    const float* dec_W_hh = (const float*)d_in[7];
    const float* dec_b_ih = (const float*)d_in[8];
    const float* dec_b_hh = (const float*)d_in[9];
    const float* in_emb_W = (const float*)d_in[10];
    const float* in_emb_b = (const float*)d_in[11];
    const float* out_emb_W = (const float*)d_in[12];
    const float* out_emb_b = (const float*)d_in[13];
    const float* att_W1 = (const float*)d_in[14];
    const float* att_b1 = (const float*)d_in[15];
    const float* att_W2 = (const float*)d_in[16];
    const float* att_b2 = (const float*)d_in[17];
    const float* prelu_w = (const float*)d_in[18];

    float* out = (float*)d_out;
    char* ws = (char*)d_ws;

    // ---- d_out scratch (all reads precede final vocab GEMM) ----
    float* Xbig    = out;
    float* S_g     = out + 20971520;
    float* ctxS    = out + 41943040;
    float* S_log   = out + 47185920;
    float* samples = out + 47595520;
    float* EW2     = out + 52838400;
    unsigned short* WencF = (unsigned short*)(out + 58081280);
    unsigned short* WhhDF = (unsigned short*)(out + 64372736);
    unsigned short* WihcF = (unsigned short*)(out + 70664192);

    // ---- d_ws map ----
    size_t off = 0;
    auto alloc = [&](size_t nfloats) { float* p = (float*)(ws + off); off += nfloats * 4; return p; };
    float* enc_seq = alloc(80 * 64 * 1024);
    float* enc_pad = alloc(80 * 64 * 1024);
    float* h_all   = alloc(80 * 64 * 1024);
    float* benc    = alloc(4096);
    float* bdec    = alloc(4096);
    float* zb      = alloc(1024);
    float* hfragE_f = alloc(196608);
    float* hfragD_f = alloc(196608);
    float* ctxfrag_f= alloc(98304);
    float* plog     = alloc(64 * 4 * 80);
    float* gsum     = alloc(262144);
    float* cglobE   = alloc(65536);
    float* cglobD   = alloc(65536);
    float* h_fp32   = alloc(65536);
    float* bar_f    = alloc(2048);
    unsigned short* hfragE  = (unsigned short*)hfragE_f;
    unsigned short* hfragD  = (unsigned short*)hfragD_f;
    unsigned short* ctxfrag = (unsigned short*)ctxfrag_f;
    unsigned* barE1 = (unsigned*)bar_f;
    unsigned* barPE = ((unsigned*)bar_f) + 512;
    unsigned* barPW = ((unsigned*)bar_f) + 1024;
    unsigned* barD  = ((unsigned*)bar_f) + 1536;

    auto big3 = [&](const float* A, int lda, const float* W, int ldw,
                    float* C, int ldc, const float* bias, int M, int N, int K) {
        dim3 g((N + 127) / 128, (M + 127) / 128);
        hipLaunchKernelGGL((gemm_mfma_split<3>), g, dim3(256), 0, stream,
                           A, lda, W, ldw, C, ldc, bias, M, N, K);
    };

    // ---- setup ----
    hipLaunchKernelGGL(vec_add2, dim3(16), dim3(256), 0, stream, enc_b_ih, enc_b_hh, benc, 4096);
    hipLaunchKernelGGL(vec_add2, dim3(16), dim3(256), 0, stream, dec_b_ih, dec_b_hh, bdec, 4096);
    hipLaunchKernelGGL(zero_f, dim3(4), dim3(256), 0, stream, zb, 1024);
    hipLaunchKernelGGL(zero_f, dim3(768), dim3(256), 0, stream, hfragE_f, 196608);
    hipLaunchKernelGGL(zero_f, dim3(768), dim3(256), 0, stream, hfragD_f, 196608);
    hipLaunchKernelGGL(zero_f, dim3(8), dim3(256), 0, stream, bar_f, 2048);

    // ---- weight frag rearranges ----
    hipLaunchKernelGGL(rearr_frag, dim3(2048), dim3(256), 0, stream, enc_W_hh, 1024, 0, WencF, 4096, 1024);
    hipLaunchKernelGGL(rearr_frag, dim3(2048), dim3(256), 0, stream, dec_W_hh, 1024, 0, WhhDF, 4096, 1024);
    hipLaunchKernelGGL(rearr_frag, dim3(2048), dim3(256), 0, stream, dec_W_ih, 2048, 1024, WihcF, 4096, 1024);

    // ---- batched big GEMMs (NS=3) ----
    big3(input_data, 4096, enc_W_ih, 4096, Xbig, 4096, benc, 5120, 4096, 4096);
    hipLaunchKernelGGL(sample0_fill, dim3(256), dim3(256), 0, stream, in_emb_W, in_emb_b, samples);
    big3(correct_answer + (size_t)64 * 20000, 20000, in_emb_W, 20000,
         samples + 65536, 1024, in_emb_b, 5056, 1024, 20000);
    big3(samples, 1024, dec_W_ih, 2048, S_g, 4096, bdec, 5120, 4096, 1024);
    big3(samples, 1024, att_W2, 2048, ctxS, 1024, att_b2, 5120, 1024, 1024);
    big3(samples, 1024, att_W1 + 1024, 2048, S_log, 80, att_b1, 5120, 80, 1024);

    // ---- k1: encoder real (80 steps) ----
    hipLaunchKernelGGL(coop_enc80, dim3(256), dim3(512), 0, stream,
                       WencF, Xbig, hfragE, enc_seq, cglobE, barE1);

    // ---- Xwarm + EW2 projections (need enc_seq) ----
    big3(enc_seq, 1024, dec_W_ih, 2048, Xbig, 4096, bdec, 5120, 4096, 1024);
    big3(enc_seq, 1024, att_W2 + 1024, 2048, EW2, 1024, zb, 5120, 1024, 1024);

    // ---- k3: enc-pad || dec warm-up (80 steps, overlapped) ----
    hipLaunchKernelGGL(coop_padwarm, dim3(256), dim3(512), 0, stream,
                       WencF, WhhDF, benc, Xbig, cglobE,
                       hfragE, hfragD, enc_pad, cglobD, h_fp32, barPE, barPW);

    // ---- k4: attention decode (80 steps) ----
    hipLaunchKernelGGL(coop_dec80, dim3(256), dim3(512), 0, stream,
                       WihcF, WhhDF, att_W1, EW2, S_g, ctxS, S_log,
                       enc_pad, prelu_w, h_fp32, cglobD,
                       hfragD, ctxfrag, plog, h_all, gsum, barD);

    // ---- final vocab projection (NS=1, output-facing) ----
    {
        dim3 g((20000 + 127) / 128, (5120 + 127) / 128);
        hipLaunchKernelGGL((gemm_mfma_split<1>), g, dim3(256), 0, stream,
                           h_all, 1024, out_emb_W, 1024, out, 20000, out_emb_b, 5120, 20000, 1024);
    }
}

// Round 14
// 13837.221 us; speedup vs baseline: 3.7957x; 1.0599x over previous
//
#include <hip/hip_runtime.h>
#include <cstddef>
#include <cstdint>

typedef __attribute__((ext_vector_type(8))) short short8v;
typedef __attribute__((ext_vector_type(4))) float f32x4;

__device__ __forceinline__ float sigmf(float x) { return 1.0f / (1.0f + __expf(-x)); }

__device__ __forceinline__ unsigned short bf16_rn(float x) {
    union { float f; unsigned u; } v; v.f = x;
    unsigned r = v.u + 0x7FFF + ((v.u >> 16) & 1);
    return (unsigned short)(r >> 16);
}
__device__ __forceinline__ float bf16_to_f(unsigned short h) {
    union { unsigned u; float f; } v; v.u = ((unsigned)h) << 16; return v.f;
}
__device__ __forceinline__ unsigned long long pack4(unsigned short a, unsigned short b,
                                                    unsigned short c, unsigned short d) {
    return (unsigned long long)a | ((unsigned long long)b << 16)
         | ((unsigned long long)c << 32) | ((unsigned long long)d << 48);
}

#define MFMA_(d, va, vb) d = __builtin_amdgcn_mfma_f32_16x16x32_bf16(va, vb, d, 0, 0, 0)

#define AT_LD(p)        __hip_atomic_load((p), __ATOMIC_RELAXED, __HIP_MEMORY_SCOPE_AGENT)
#define AT_ST(p, v)     __hip_atomic_store((p), (v), __ATOMIC_RELAXED, __HIP_MEMORY_SCOPE_AGENT)
#define AT_ST_REL(p, v) __hip_atomic_store((p), (v), __ATOMIC_RELEASE, __HIP_MEMORY_SCOPE_AGENT)
#define AT_ADD(p, v)    __hip_atomic_fetch_add((p), (v), __ATOMIC_RELAXED, __HIP_MEMORY_SCOPE_AGENT)

// ---------------------------------------------------------------------------
// Fragment layout (A and W): F[p][rgw][kf][l][e]; rgw=r>>4, kf=k>>5,
// l=((k>>3)&3)*16+(r&15), e=k&7. Per-(p,rgw) chunk = 32*64*8 = 16384 shorts.
// ---------------------------------------------------------------------------
__device__ __forceinline__ void write_frag3_nt(unsigned short* __restrict__ dst, int NRGW,
                                               int r, int k, float x)
{
    unsigned short hi = bf16_rn(x); float r1 = x - bf16_to_f(hi);
    unsigned short md = bf16_rn(r1);
    unsigned short lo = bf16_rn(r1 - bf16_to_f(md));
    int base = (((r >> 4) * 32 + (k >> 5)) * 64 + ((k >> 3) & 3) * 16 + (r & 15)) * 8 + (k & 7);
    int ps = NRGW * 16384;
    __builtin_nontemporal_store(hi, &dst[base]);
    __builtin_nontemporal_store(md, &dst[ps + base]);
    __builtin_nontemporal_store(lo, &dst[2 * ps + base]);
}

__launch_bounds__(256)
__global__ void rearr_frag(const float* __restrict__ src, int ld, int c0,
                           unsigned short* __restrict__ dst, int R, int K)
{
    int idx = blockIdx.x * 256 + threadIdx.x;
    int kpr = K >> 3;
    if (idx >= R * kpr) return;
    int r = idx / kpr, k = (idx % kpr) * 8;
    int NRGW = R >> 4;
    const float* s = src + (size_t)r * ld + c0 + k;
    float4 v0 = *(const float4*)s, v1 = *(const float4*)(s + 4);
    float xs[8] = {v0.x, v0.y, v0.z, v0.w, v1.x, v1.y, v1.z, v1.w};
    unsigned short hi[8], md[8], lo[8];
#pragma unroll
    for (int e = 0; e < 8; ++e) {
        hi[e] = bf16_rn(xs[e]); float r1 = xs[e] - bf16_to_f(hi[e]);
        md[e] = bf16_rn(r1);
        lo[e] = bf16_rn(r1 - bf16_to_f(md[e]));
    }
    int base = (((r >> 4) * 32 + (k >> 5)) * 64 + ((k >> 3) & 3) * 16 + (r & 15)) * 8;
    size_t ps = (size_t)NRGW * 16384;
    *(unsigned long long*)&dst[base]          = pack4(hi[0], hi[1], hi[2], hi[3]);
    *(unsigned long long*)&dst[base + 4]      = pack4(hi[4], hi[5], hi[6], hi[7]);
    *(unsigned long long*)&dst[ps + base]     = pack4(md[0], md[1], md[2], md[3]);
    *(unsigned long long*)&dst[ps + base + 4] = pack4(md[4], md[5], md[6], md[7]);
    *(unsigned long long*)&dst[2*ps + base]     = pack4(lo[0], lo[1], lo[2], lo[3]);
    *(unsigned long long*)&dst[2*ps + base + 4] = pack4(lo[4], lo[5], lo[6], lo[7]);
}

// ---------------------------------------------------------------------------
// Two-level tree barrier; gidx = this block's group, ng groups, bpg blocks ea.
// ---------------------------------------------------------------------------
__device__ __forceinline__ void tree_barrier(unsigned* bar, int gidx, int ng, int bpg)
{
    __syncthreads();
    if (threadIdx.x == 0) {
        unsigned* gcnt = bar + gidx * 32;
        unsigned* ggen = bar + gidx * 32 + 1;
        unsigned* rcnt = bar + ng * 32;
        unsigned* rgen = bar + ng * 32 + 1;
        __threadfence();   // release
        unsigned mygen = AT_LD(ggen);
        unsigned prev = AT_ADD(gcnt, 1u);
        if (prev == (unsigned)(bpg - 1)) {
            AT_ST(gcnt, 0u);
            unsigned rg = AT_LD(rgen);
            unsigned rprev = AT_ADD(rcnt, 1u);
            if (rprev == (unsigned)(ng - 1)) {
                AT_ST(rcnt, 0u);
                AT_ST_REL(rgen, rg + 1u);
            } else {
                while (AT_LD(rgen) == rg) __builtin_amdgcn_s_sleep(1);
            }
            AT_ST_REL(ggen, mygen + 1u);
        } else {
            while (AT_LD(ggen) == mygen) __builtin_amdgcn_s_sleep(1);
        }
        __threadfence();   // acquire
    }
    __syncthreads();
}

// ---------------------------------------------------------------------------
// Batched fp32 GEMM via bf16-split MFMA (validated R3): C = A@W^T + bias.
// ---------------------------------------------------------------------------
template <int NS>
__launch_bounds__(256, 2)
__global__ void gemm_mfma_split(const float* __restrict__ A, int lda,
                                const float* __restrict__ W, int ldw,
                                float* __restrict__ C, int ldc,
                                const float* __restrict__ bias,
                                int M, int N, int K)
{
    __shared__ unsigned short Abf[NS][128][40];
    __shared__ unsigned short Bbf[NS][128][40];
    const int tid = threadIdx.x;
    const int m0 = blockIdx.y * 128, n0 = blockIdx.x * 128;
    const int wave = tid >> 6, lane = tid & 63;
    const int wr = wave >> 1, wc = wave & 1;
    const int lr = lane & 15, lk = (lane >> 4) * 8;

    f32x4 acc[4][4];
#pragma unroll
    for (int i = 0; i < 4; ++i)
#pragma unroll
        for (int j = 0; j < 4; ++j) acc[i][j] = (f32x4){0.f, 0.f, 0.f, 0.f};

    const int arow = tid >> 1;
    const int akh  = (tid & 1) * 16;
    int gr = m0 + arow; if (gr > M - 1) gr = M - 1;
    int gn = n0 + arow; if (gn > N - 1) gn = N - 1;
    const float* aptr = A + (size_t)gr * lda + akh;
    const float* wptr = W + (size_t)gn * ldw + akh;

    for (int k0 = 0; k0 < K; k0 += 32) {
#pragma unroll
        for (int q = 0; q < 4; ++q) {
            float4 v = *(const float4*)(aptr + k0 + q * 4);
            float xs[4] = {v.x, v.y, v.z, v.w};
            unsigned short h[4], hm[4], hl[4];
#pragma unroll
            for (int e = 0; e < 4; ++e) {
                h[e] = bf16_rn(xs[e]);
                if (NS == 3) {
                    float r1 = xs[e] - bf16_to_f(h[e]);
                    hm[e] = bf16_rn(r1);
                    hl[e] = bf16_rn(r1 - bf16_to_f(hm[e]));
                }
            }
            *(unsigned long long*)&Abf[0][arow][akh + q * 4] = pack4(h[0], h[1], h[2], h[3]);
            if (NS == 3) {
                *(unsigned long long*)&Abf[1][arow][akh + q * 4] = pack4(hm[0], hm[1], hm[2], hm[3]);
                *(unsigned long long*)&Abf[2][arow][akh + q * 4] = pack4(hl[0], hl[1], hl[2], hl[3]);
            }
        }
#pragma unroll
        for (int q = 0; q < 4; ++q) {
            float4 v = *(const float4*)(wptr + k0 + q * 4);
            float xs[4] = {v.x, v.y, v.z, v.w};
            unsigned short h[4], hm[4], hl[4];
#pragma unroll
            for (int e = 0; e < 4; ++e) {
                h[e] = bf16_rn(xs[e]);
                if (NS == 3) {
                    float r1 = xs[e] - bf16_to_f(h[e]);
                    hm[e] = bf16_rn(r1);
                    hl[e] = bf16_rn(r1 - bf16_to_f(hm[e]));
                }
            }
            *(unsigned long long*)&Bbf[0][arow][akh + q * 4] = pack4(h[0], h[1], h[2], h[3]);
            if (NS == 3) {
                *(unsigned long long*)&Bbf[1][arow][akh + q * 4] = pack4(hm[0], hm[1], hm[2], hm[3]);
                *(unsigned long long*)&Bbf[2][arow][akh + q * 4] = pack4(hl[0], hl[1], hl[2], hl[3]);
            }
        }
        __syncthreads();

        short8v a[NS][4], b[4];
#pragma unroll
        for (int p = 0; p < NS; ++p)
#pragma unroll
            for (int i = 0; i < 4; ++i)
                a[p][i] = *(const short8v*)&Abf[p][wr * 64 + i * 16 + lr][lk];
#pragma unroll
        for (int q = 0; q < NS; ++q) {
#pragma unroll
            for (int j = 0; j < 4; ++j)
                b[j] = *(const short8v*)&Bbf[q][wc * 64 + j * 16 + lr][lk];
            const int pmax = (NS == 1) ? 1 : (3 - q);
#pragma unroll
            for (int p = 0; p < 3; ++p) {
                if (p >= pmax) break;
#pragma unroll
                for (int i = 0; i < 4; ++i)
#pragma unroll
                    for (int j = 0; j < 4; ++j)
                        acc[i][j] = __builtin_amdgcn_mfma_f32_16x16x32_bf16(
                            a[p][i], b[j], acc[i][j], 0, 0, 0);
            }
        }
        __syncthreads();
    }

    const int crow = (lane >> 4) * 4;
#pragma unroll
    for (int i = 0; i < 4; ++i) {
        int mbase = m0 + wr * 64 + i * 16 + crow;
#pragma unroll
        for (int j = 0; j < 4; ++j) {
            int n = n0 + wc * 64 + j * 16 + lr;
            if (n < N) {
                float bv = bias[n];
#pragma unroll
                for (int r = 0; r < 4; ++r) {
                    int m = mbase + r;
                    if (m < M) C[(size_t)m * ldc + n] = acc[i][j][r] + bv;
                }
            }
        }
    }
}

__launch_bounds__(256)
__global__ void zero_f(float* __restrict__ p, int n)
{
    int i = blockIdx.x * 256 + threadIdx.x;
    if (i < n) p[i] = 0.f;
}

__launch_bounds__(256)
__global__ void vec_add2(const float* __restrict__ a, const float* __restrict__ b,
                         float* __restrict__ o, int n)
{
    int i = blockIdx.x * 256 + threadIdx.x;
    if (i < n) o[i] = a[i] + b[i];
}

__launch_bounds__(256)
__global__ void sample0_fill(const float* __restrict__ emW, const float* __restrict__ emb,
                             float* __restrict__ samples)
{
    int idx = blockIdx.x * 256 + threadIdx.x; // 65536
    int d = idx & 1023;
    samples[idx] = emW[(size_t)d * 20000 + 19998] + emb[d];
}

// stage one rg-chunk (96KB) of a 64-row frag buffer into LDS
__device__ __forceinline__ void stage_A(unsigned short* __restrict__ LDSA,
                                        const unsigned short* __restrict__ src,
                                        int rg, int tid)
{
#pragma unroll
    for (int p = 0; p < 3; ++p) {
        const unsigned short* sp = src + (size_t)(p * 4 + rg) * 16384;
        unsigned short* dp = LDSA + p * 16384;
#pragma unroll
        for (int it = 0; it < 4; ++it) {
            int idx = tid + it * 512;
            *(short8v*)&dp[idx * 8] = *(const short8v*)&sp[idx * 8];
        }
    }
}

// 16-kf MFMA block from LDSA rg-chunk vs wreg (encoder-style, in-block gates)
__device__ __forceinline__ f32x4 mfma16(const unsigned short* __restrict__ LDSA,
                                        const short8v* __restrict__ wreg,
                                        int kh, int lane)
{
    f32x4 acc0 = (f32x4){0.f,0.f,0.f,0.f}, acc1 = acc0;
#pragma unroll
    for (int i = 0; i < 16; ++i) {
        int kf = kh * 16 + i;
        short8v a0 = *(const short8v*)&LDSA[(kf * 64 + lane) * 8];
        short8v a1 = *(const short8v*)&LDSA[16384 + (kf * 64 + lane) * 8];
        short8v a2 = *(const short8v*)&LDSA[32768 + (kf * 64 + lane) * 8];
        short8v b0 = wreg[i * 3 + 0], b1 = wreg[i * 3 + 1], b2 = wreg[i * 3 + 2];
        f32x4& A = (i & 1) ? acc1 : acc0;
        MFMA_(A, a0, b0); MFMA_(A, a0, b1); MFMA_(A, a1, b0);
        MFMA_(A, a1, b1); MFMA_(A, a0, b2); MFMA_(A, a2, b0);
    }
    return acc0 + acc1;
}

// ---------------------------------------------------------------------------
// k1: encoder real steps 0..79. 256 blocks x 512. 1 barrier/step.
// XCD-local rg: rg = bid&3. waves_per_eu(1) -> allow 256-VGPR alloc (wreg[48]).
// ---------------------------------------------------------------------------
__launch_bounds__(512, 1)
__attribute__((amdgpu_waves_per_eu(1, 2)))
__global__ void coop_enc80(const unsigned short* __restrict__ WencF,
                           const float* __restrict__ Xbig,
                           unsigned short* __restrict__ hfrag,   // 2 bufs x 196608
                           float* __restrict__ enc_seq,
                           float* __restrict__ cglobE,
                           unsigned* __restrict__ bar)
{
    __shared__ unsigned short LDSA[3 * 16384];
    __shared__ float gbuf[8][16][16];
    const int bid = blockIdx.x, tid = threadIdx.x;
    const int w = tid >> 6, lane = tid & 63;
    const int g = w & 3, kh = w >> 2;
    const int rg = bid & 3, cg = bid >> 2;
    const int wbase = g * 64 + cg;
    const int r_l = (tid & 255) >> 4, c_l = tid & 15;
    const int row = rg * 16 + r_l, col = cg * 16 + c_l;
    float cstate = 0.f;

    short8v wreg[48];
#pragma unroll
    for (int i = 0; i < 16; ++i) {
        int kf = kh * 16 + i;
#pragma unroll
        for (int p = 0; p < 3; ++p)
            wreg[i * 3 + p] = *(const short8v*)&WencF[((size_t)(p * 256 + wbase) * 32 + kf) * 512 + lane * 8];
    }

    float pf[4];
    if (tid < 256) {
#pragma unroll
        for (int g2 = 0; g2 < 4; ++g2)
            pf[g2] = Xbig[(size_t)row * 4096 + g2 * 1024 + col];
    }

    for (int s = 0; s < 80; ++s) {
        const unsigned short* hf = hfrag + (s & 1) * 196608;
        stage_A(LDSA, hf, rg, tid);
        __syncthreads();
        f32x4 acc = mfma16(LDSA, wreg, kh, lane);
#pragma unroll
        for (int r = 0; r < 4; ++r)
            gbuf[w][(lane >> 4) * 4 + r][lane & 15] = acc[r];
        __syncthreads();

        if (tid < 256) {
            float gv[4];
#pragma unroll
            for (int g2 = 0; g2 < 4; ++g2)
                gv[g2] = gbuf[g2][r_l][c_l] + gbuf[4 + g2][r_l][c_l] + pf[g2];
            float cn = sigmf(gv[1]) * cstate + sigmf(gv[0]) * tanhf(gv[2]);
            float hn = sigmf(gv[3]) * tanhf(cn);
            cstate = cn;
            __builtin_nontemporal_store(hn, &enc_seq[(size_t)s * 65536 + row * 1024 + col]);
            write_frag3_nt(hfrag + ((s + 1) & 1) * 196608, 4, row, col, hn);
            if (s == 79) __builtin_nontemporal_store(cstate, &cglobE[row * 1024 + col]);
            else {
#pragma unroll
                for (int g2 = 0; g2 < 4; ++g2)
                    pf[g2] = Xbig[((size_t)(s + 1) * 64 + row) * 4096 + g2 * 1024 + col];
            }
        }
        tree_barrier(bar, bid >> 5, 8, 32);
    }
}

// ---------------------------------------------------------------------------
// k3: enc-pad (blocks 0..127) CONCURRENT WITH dec warm-up (blocks 128..255).
// XCD-local rg2 = lb&1. waves_per_eu(1) to avoid wreg[48] spill.
// ---------------------------------------------------------------------------
__launch_bounds__(512, 1)
__attribute__((amdgpu_waves_per_eu(1, 2)))
__global__ void coop_padwarm(const unsigned short* __restrict__ WencF,
                             const unsigned short* __restrict__ WdecF,
                             const float* __restrict__ benc,
                             const float* __restrict__ Xwarm,
                             const float* __restrict__ cglobE,
                             unsigned short* __restrict__ hfragE,
                             unsigned short* __restrict__ hfragD,
                             float* __restrict__ enc_pad,
                             float* __restrict__ cglobD,
                             float* __restrict__ h_fp32,
                             unsigned* __restrict__ barE,
                             unsigned* __restrict__ barW)
{
    __shared__ unsigned short LDSA[3 * 16384];
    __shared__ float gbuf[8][16][16];
    const int bid = blockIdx.x, tid = threadIdx.x;
    const int w = tid >> 6, lane = tid & 63;
    const int g = w & 3, kh = w >> 2;
    const bool isW = bid >= 128;
    const int lb = bid & 127;
    const int rg2 = lb & 1, cg = lb >> 1;
    const int wbase = g * 64 + cg;
    const int r_l = (tid & 255) >> 4, c_l = tid & 15;
    const int col = cg * 16 + c_l;
    const unsigned short* Wf = isW ? WdecF : WencF;
    unsigned short* hfrag = isW ? hfragD : hfragE;
    unsigned* bar = isW ? barW : barE;

    short8v wreg[48];
#pragma unroll
    for (int i = 0; i < 16; ++i) {
        int kf = kh * 16 + i;
#pragma unroll
        for (int p = 0; p < 3; ++p)
            wreg[i * 3 + p] = *(const short8v*)&Wf[((size_t)(p * 256 + wbase) * 32 + kf) * 512 + lane * 8];
    }

    float cst[2] = {0.f, 0.f};
    float pfx[2][4];
    if (tid < 256) {
#pragma unroll
        for (int l = 0; l < 2; ++l) {
            int row = rg2 * 32 + l * 16 + r_l;
            if (!isW) cst[l] = cglobE[row * 1024 + col];
#pragma unroll
            for (int g2 = 0; g2 < 4; ++g2)
                pfx[l][g2] = isW ? Xwarm[(size_t)row * 4096 + g2 * 1024 + col]
                                 : benc[g2 * 1024 + col];
        }
    }

    for (int s = 0; s < 80; ++s) {
        const unsigned short* hf = hfrag + (s & 1) * 196608;
        unsigned short* hout = hfrag + ((s + 1) & 1) * 196608;
#pragma unroll
        for (int l = 0; l < 2; ++l) {
            const int rgi = rg2 * 2 + l;
            stage_A(LDSA, hf, rgi, tid);
            __syncthreads();
            f32x4 acc = mfma16(LDSA, wreg, kh, lane);
#pragma unroll
            for (int r = 0; r < 4; ++r)
                gbuf[w][(lane >> 4) * 4 + r][lane & 15] = acc[r];
            __syncthreads();
            if (tid < 256) {
                const int row = rgi * 16 + r_l;
                float gv[4];
#pragma unroll
                for (int g2 = 0; g2 < 4; ++g2)
                    gv[g2] = gbuf[g2][r_l][c_l] + gbuf[4 + g2][r_l][c_l] + pfx[l][g2];
                float cn = sigmf(gv[1]) * cst[l] + sigmf(gv[0]) * tanhf(gv[2]);
                float hn = sigmf(gv[3]) * tanhf(cn);
                cst[l] = cn;
                if (!isW)
                    __builtin_nontemporal_store(hn, &enc_pad[(size_t)s * 65536 + row * 1024 + col]);
                write_frag3_nt(hout, 4, row, col, hn);
                if (isW) {
                    if (s == 79) {
                        __builtin_nontemporal_store(hn, &h_fp32[row * 1024 + col]);
                        __builtin_nontemporal_store(cn, &cglobD[row * 1024 + col]);
                    } else {
#pragma unroll
                        for (int g2 = 0; g2 < 4; ++g2)
                            pfx[l][g2] = Xwarm[((size_t)(s + 1) * 64 + row) * 4096 + g2 * 1024 + col];
                    }
                }
            }
            __syncthreads();
        }
        tree_barrier(bar, (lb >> 5), 4, 32);
    }
}

// ---------------------------------------------------------------------------
// k4: attention-decode, s=80..159. 256 blocks x 512. 2 barriers/step.
// Phase B role (gg,cg) unchanged. Phase C' role (b=bid>>2, jc=bid&3):
// gates computed REDUNDANTLY for all 1024 cols of batch b (c-state kept
// redundantly; identical fp32 ops => identical values), full h row in LDS,
// full logits computed locally (no plog exchange), then softmax + f + ctx
// for the jc slice. Prologue does the t=0 attention from h_fp32.
// ---------------------------------------------------------------------------
__launch_bounds__(512, 2)
__global__ void coop_dec80(const unsigned short* __restrict__ WihcF,
                           const unsigned short* __restrict__ WhhF,
                           const float* __restrict__ W1,       // [80][2048]
                           const float* __restrict__ EW2,      // [80][64][1024]
                           const float* __restrict__ S_g,
                           const float* __restrict__ ctxS,
                           const float* __restrict__ S_log,
                           const float* __restrict__ enc_pad,
                           const float* __restrict__ prelu_w,
                           const float* __restrict__ h_fp32,
                           const float* __restrict__ cglobD,
                           unsigned short* __restrict__ hfrag,  // 2 bufs (step 80 reads buf0)
                           unsigned short* __restrict__ ctxfrag,
                           float* __restrict__ h_all,
                           float* __restrict__ gsum,            // [4][64][1024]
                           unsigned* __restrict__ bar)
{
    __shared__ float EW2T[80 * 256];
    __shared__ float gred[8][1024];
    __shared__ float hfull[1024];
    __shared__ float wsm[80];
    __shared__ float rbuf[128];
    const int bid = blockIdx.x, tid = threadIdx.x;
    const int w = tid >> 6, lane = tid & 63;
    const int gg = bid >> 6, cg = bid & 63;
    const int wbase = gg * 64 + cg;
    const int kq = w;
    const int b = bid >> 2, jc = bid & 3;
    const float pw = prelu_w[0];

    // ---- weight slice: 8 kf x 3 planes = 96 VGPRs ----
    const unsigned short* Wsrc = (kq < 4) ? WihcF : WhhF;
    const int kfbase = (kq & 3) * 8;
    short8v wreg[24];
#pragma unroll
    for (int i = 0; i < 8; ++i) {
#pragma unroll
        for (int p = 0; p < 3; ++p)
            wreg[i * 3 + p] = *(const short8v*)&Wsrc[((size_t)(p * 256 + wbase) * 32 + kfbase + i) * 512 + lane * 8];
    }

    // ---- redundant full-row c-state: 2 cols/thread ----
    float c2[2];
    c2[0] = cglobD[b * 1024 + tid * 2];
    c2[1] = cglobD[b * 1024 + tid * 2 + 1];

    for (int i = tid; i < 80 * 256; i += 512) {
        int ss = i >> 8, j = i & 255;
        EW2T[i] = EW2[((size_t)ss * 64 + b) * 1024 + jc * 256 + j];
    }

    // ---- prologue: attention for t=0 from h_fp32 ----
    for (int i = tid; i < 1024; i += 512) hfull[i] = h_fp32[b * 1024 + i];
    __syncthreads();
    {
#pragma unroll
        for (int i = 0; i < 10; ++i) {
            int sx = w * 10 + i;
            float p = 0.f;
#pragma unroll
            for (int q = 0; q < 16; ++q)
                p = fmaf(hfull[lane + q * 64], W1[(size_t)sx * 2048 + lane + q * 64], p);
#pragma unroll
            for (int off = 32; off; off >>= 1) p += __shfl_down(p, off, 64);
            if (lane == 0) wsm[sx] = p + S_log[(size_t)b * 80 + sx];
        }
        __syncthreads();
        float v = (tid < 80) ? wsm[tid] : -3.4e38f;
        if (tid < 128) rbuf[tid] = v;
        __syncthreads();
        for (int off = 64; off >= 1; off >>= 1) {
            if (tid < off) rbuf[tid] = fmaxf(rbuf[tid], rbuf[tid + off]);
            __syncthreads();
        }
        float mx = rbuf[0];
        __syncthreads();
        float e = (tid < 80) ? __expf(wsm[tid] - mx) : 0.f;
        if (tid < 128) rbuf[tid] = e;
        __syncthreads();
        for (int off = 64; off >= 1; off >>= 1) {
            if (tid < off) rbuf[tid] += rbuf[tid + off];
            __syncthreads();
        }
        float inv = 1.f / rbuf[0];
        __syncthreads();
        if (tid < 80) wsm[tid] = e * inv;
        __syncthreads();
        if (tid < 256) {
            float f = 0.f;
#pragma unroll 8
            for (int ss = 0; ss < 80; ++ss)
                f = fmaf(wsm[ss], EW2T[ss * 256 + tid], f);
            int col = jc * 256 + tid;
            float val = f + ctxS[(size_t)b * 1024 + col];
            val = (val >= 0.f) ? val : pw * val;
            val += enc_pad[(size_t)b * 1024 + col];
            write_frag3_nt(ctxfrag, 4, b, col, val);
        }
    }
    tree_barrier(bar, bid >> 5, 8, 32);

    for (int t = 0; t < 80; ++t) {
        const int s = 80 + t;
        unsigned short* hout = hfrag + ((s + 1) & 1) * 196608;
        const unsigned short* hf = hfrag + (s & 1) * 196608;

        // ---- prefetch Phase-C' gate-adds (2 cols/thread) ----
        float pf2[2][4];
        {
            const float* xb = S_g + ((size_t)t * 64 + b) * 4096;
#pragma unroll
            for (int e = 0; e < 2; ++e) {
                int col = tid * 2 + e;
#pragma unroll
                for (int g2 = 0; g2 < 4; ++g2) pf2[e][g2] = xb[g2 * 1024 + col];
            }
        }

        // ---- Phase B: gate GEMM partials ----
        {
            f32x4 acc[4];
#pragma unroll
            for (int rg = 0; rg < 4; ++rg) acc[rg] = (f32x4){0.f,0.f,0.f,0.f};
            const unsigned short* asrc = (kq < 4) ? ctxfrag : hf;
#pragma unroll
            for (int i = 0; i < 8; ++i) {
                int kfl = kfbase + i;
#pragma unroll
                for (int rg = 0; rg < 4; ++rg) {
                    const unsigned short* ab = asrc + ((size_t)rg * 32 + kfl) * 512 + lane * 8;
                    short8v a0 = *(const short8v*)&ab[0];
                    short8v a1 = *(const short8v*)&ab[65536];
                    short8v a2 = *(const short8v*)&ab[131072];
                    short8v b0 = wreg[i * 3 + 0], b1 = wreg[i * 3 + 1], b2 = wreg[i * 3 + 2];
                    MFMA_(acc[rg], a0, b0); MFMA_(acc[rg], a0, b1); MFMA_(acc[rg], a1, b0);
                    MFMA_(acc[rg], a1, b1); MFMA_(acc[rg], a0, b2); MFMA_(acc[rg], a2, b0);
                }
            }
#pragma unroll
            for (int rg = 0; rg < 4; ++rg)
#pragma unroll
                for (int r = 0; r < 4; ++r)
                    gred[w][rg * 256 + lane * 4 + r] = acc[rg][r];
            __syncthreads();
#pragma unroll
            for (int e2 = 0; e2 < 2; ++e2) {
                int slot = tid * 2 + e2;
                int rg = slot >> 8, l = (slot >> 2) & 63, r = slot & 3;
                float sum = 0.f;
#pragma unroll
                for (int w2 = 0; w2 < 8; ++w2) sum += gred[w2][slot];
                int row = rg * 16 + (l >> 4) * 4 + r;
                int col = cg * 16 + (l & 15);
                __builtin_nontemporal_store(sum, &gsum[((size_t)gg * 64 + row) * 1024 + col]);
            }
        }
        tree_barrier(bar, bid >> 5, 8, 32);

        // ---- Phase C': full-row gates + h write + next-step attention ----
        {
            float hv[2];
#pragma unroll
            for (int e = 0; e < 2; ++e) {
                int col = tid * 2 + e;
                float gv[4];
#pragma unroll
                for (int g2 = 0; g2 < 4; ++g2)
                    gv[g2] = gsum[((size_t)g2 * 64 + b) * 1024 + col] + pf2[e][g2];
                float cn = sigmf(gv[1]) * c2[e] + sigmf(gv[0]) * tanhf(gv[2]);
                float hn = sigmf(gv[3]) * tanhf(cn);
                c2[e] = cn;
                hfull[col] = hn;
                hv[e] = hn;
            }
            __syncthreads();
            // write h_all + hfrag for own jc slice only
            if (tid >= jc * 128 && tid < (jc + 1) * 128) {
#pragma unroll
                for (int e = 0; e < 2; ++e) {
                    int col = tid * 2 + e;
                    __builtin_nontemporal_store(hv[e], &h_all[((size_t)t * 64 + b) * 1024 + col]);
                    write_frag3_nt(hout, 4, b, col, hv[e]);
                }
            }
            // attention for t+1 (local full logits from hfull)
            if (t < 79) {
#pragma unroll
                for (int i = 0; i < 10; ++i) {
                    int sx = w * 10 + i;
                    float p = 0.f;
#pragma unroll
                    for (int q = 0; q < 16; ++q)
                        p = fmaf(hfull[lane + q * 64], W1[(size_t)sx * 2048 + lane + q * 64], p);
#pragma unroll
                    for (int off = 32; off; off >>= 1) p += __shfl_down(p, off, 64);
                    if (lane == 0) wsm[sx] = p + S_log[((size_t)(t + 1) * 64 + b) * 80 + sx];
                }
                __syncthreads();
                float v = (tid < 80) ? wsm[tid] : -3.4e38f;
                if (tid < 128) rbuf[tid] = v;
                __syncthreads();
                for (int off = 64; off >= 1; off >>= 1) {
                    if (tid < off) rbuf[tid] = fmaxf(rbuf[tid], rbuf[tid + off]);
                    __syncthreads();
                }
                float mx = rbuf[0];
                __syncthreads();
                float e = (tid < 80) ? __expf(wsm[tid] - mx) : 0.f;
                if (tid < 128) rbuf[tid] = e;
                __syncthreads();
                for (int off = 64; off >= 1; off >>= 1) {
                    if (tid < off) rbuf[tid] += rbuf[tid + off];
                    __syncthreads();
                }
                float inv = 1.f / rbuf[0];
                __syncthreads();
                if (tid < 80) wsm[tid] = e * inv;
                __syncthreads();
                if (tid < 256) {
                    float f = 0.f;
#pragma unroll 8
                    for (int ss = 0; ss < 80; ++ss)
                        f = fmaf(wsm[ss], EW2T[ss * 256 + tid], f);
                    int col = jc * 256 + tid;
                    float val = f + ctxS[((size_t)(t + 1) * 64 + b) * 1024 + col];
                    val = (val >= 0.f) ? val : pw * val;
                    val += enc_pad[((size_t)(t + 1) * 64 + b) * 1024 + col];
                    write_frag3_nt(ctxfrag, 4, b, col, val);
                }
            }
        }
        tree_barrier(bar, bid >> 5, 8, 32);
    }
}

// ---------------------------------------------------------------------------
extern "C" void kernel_launch(void* const* d_in, const int* in_sizes, int n_in,
                              void* d_out, int out_size, void* d_ws, size_t ws_size,
                              hipStream_t stream)
{
    (void)in_sizes; (void)n_in; (void)out_size; (void)ws_size;

    const float* input_data     = (const float*)d_in[0];
    const float* correct_answer = (const float*)d_in[1];
    const float* enc_W_ih = (const float*)d_in[2];
    const float* enc_W_hh = (const float*)d_in[3];
    const float* enc_b_ih = (const float*)d_in[4];
    const float* enc_b_hh = (const float*)d_in[5];
    const float* dec_W_ih = (const float*)d_in[6];
    const float* dec_W_hh = (const float*)d_in[7];
    const float* dec_b_ih = (const float*)d_in[8];
    const float* dec_b_hh = (const float*)d_in[9];
    const float* in_emb_W = (const float*)d_in[10];
    const float* in_emb_b = (const float*)d_in[11];
    const float* out_emb_W = (const float*)d_in[12];
    const float* out_emb_b = (const float*)d_in[13];
    const float* att_W1 = (const float*)d_in[14];
    const float* att_b1 = (const float*)d_in[15];
    const float* att_W2 = (const float*)d_in[16];
    const float* att_b2 = (const float*)d_in[17];
    const float* prelu_w = (const float*)d_in[18];

    float* out = (float*)d_out;
    char* ws = (char*)d_ws;

    // ---- d_out scratch (all reads precede final vocab GEMM) ----
    float* Xbig    = out;
    float* S_g     = out + 20971520;
    float* ctxS    = out + 41943040;
    float* S_log   = out + 47185920;
    float* samples = out + 47595520;
    float* EW2     = out + 52838400;
    unsigned short* WencF = (unsigned short*)(out + 58081280);
    unsigned short* WhhDF = (unsigned short*)(out + 64372736);
    unsigned short* WihcF = (unsigned short*)(out + 70664192);

    // ---- d_ws map ----
    size_t off = 0;
    auto alloc = [&](size_t nfloats) { float* p = (float*)(ws + off); off += nfloats * 4; return p; };
    float* enc_seq = alloc(80 * 64 * 1024);
    float* enc_pad = alloc(80 * 64 * 1024);
    float* h_all   = alloc(80 * 64 * 1024);
    float* benc    = alloc(4096);
    float* bdec    = alloc(4096);
    float* zb      = alloc(1024);
    float* hfragE_f = alloc(196608);
    float* hfragD_f = alloc(196608);
    float* ctxfrag_f= alloc(98304);
    float* gsum     = alloc(262144);
    float* cglobE   = alloc(65536);
    float* cglobD   = alloc(65536);
    float* h_fp32   = alloc(65536);
    float* bar_f    = alloc(2048);
    unsigned short* hfragE  = (unsigned short*)hfragE_f;
    unsigned short* hfragD  = (unsigned short*)hfragD_f;
    unsigned short* ctxfrag = (unsigned short*)ctxfrag_f;
    unsigned* barE1 = (unsigned*)bar_f;
    unsigned* barPE = ((unsigned*)bar_f) + 512;
    unsigned* barPW = ((unsigned*)bar_f) + 1024;
    unsigned* barD  = ((unsigned*)bar_f) + 1536;

    auto big3 = [&](const float* A, int lda, const float* W, int ldw,
                    float* C, int ldc, const float* bias, int M, int N, int K) {
        dim3 g((N + 127) / 128, (M + 127) / 128);
        hipLaunchKernelGGL((gemm_mfma_split<3>), g, dim3(256), 0, stream,
                           A, lda, W, ldw, C, ldc, bias, M, N, K);
    };

    // ---- setup ----
    hipLaunchKernelGGL(vec_add2, dim3(16), dim3(256), 0, stream, enc_b_ih, enc_b_hh, benc, 4096);
    hipLaunchKernelGGL(vec_add2, dim3(16), dim3(256), 0, stream, dec_b_ih, dec_b_hh, bdec, 4096);
    hipLaunchKernelGGL(zero_f, dim3(4), dim3(256), 0, stream, zb, 1024);
    hipLaunchKernelGGL(zero_f, dim3(768), dim3(256), 0, stream, hfragE_f, 196608);
    hipLaunchKernelGGL(zero_f, dim3(768), dim3(256), 0, stream, hfragD_f, 196608);
    hipLaunchKernelGGL(zero_f, dim3(8), dim3(256), 0, stream, bar_f, 2048);

    // ---- weight frag rearranges ----
    hipLaunchKernelGGL(rearr_frag, dim3(2048), dim3(256), 0, stream, enc_W_hh, 1024, 0, WencF, 4096, 1024);
    hipLaunchKernelGGL(rearr_frag, dim3(2048), dim3(256), 0, stream, dec_W_hh, 1024, 0, WhhDF, 4096, 1024);
    hipLaunchKernelGGL(rearr_frag, dim3(2048), dim3(256), 0, stream, dec_W_ih, 2048, 1024, WihcF, 4096, 1024);

    // ---- batched big GEMMs (NS=3) ----
    big3(input_data, 4096, enc_W_ih, 4096, Xbig, 4096, benc, 5120, 4096, 4096);
    hipLaunchKernelGGL(sample0_fill, dim3(256), dim3(256), 0, stream, in_emb_W, in_emb_b, samples);
    big3(correct_answer + (size_t)64 * 20000, 20000, in_emb_W, 20000,
         samples + 65536, 1024, in_emb_b, 5056, 1024, 20000);
    big3(samples, 1024, dec_W_ih, 2048, S_g, 4096, bdec, 5120, 4096, 1024);
    big3(samples, 1024, att_W2, 2048, ctxS, 1024, att_b2, 5120, 1024, 1024);
    big3(samples, 1024, att_W1 + 1024, 2048, S_log, 80, att_b1, 5120, 80, 1024);

    // ---- k1: encoder real (80 steps) ----
    hipLaunchKernelGGL(coop_enc80, dim3(256), dim3(512), 0, stream,
                       WencF, Xbig, hfragE, enc_seq, cglobE, barE1);

    // ---- Xwarm + EW2 projections (need enc_seq) ----
    big3(enc_seq, 1024, dec_W_ih, 2048, Xbig, 4096, bdec, 5120, 4096, 1024);
    big3(enc_seq, 1024, att_W2 + 1024, 2048, EW2, 1024, zb, 5120, 1024, 1024);

    // ---- k3: enc-pad || dec warm-up (80 steps, overlapped) ----
    hipLaunchKernelGGL(coop_padwarm, dim3(256), dim3(512), 0, stream,
                       WencF, WhhDF, benc, Xbig, cglobE,
                       hfragE, hfragD, enc_pad, cglobD, h_fp32, barPE, barPW);

    // ---- k4: attention decode (80 steps, 2 barriers/step) ----
    hipLaunchKernelGGL(coop_dec80, dim3(256), dim3(512), 0, stream,
                       WihcF, WhhDF, att_W1, EW2, S_g, ctxS, S_log,
                       enc_pad, prelu_w, h_fp32, cglobD,
                       hfragD, ctxfrag, h_all, gsum, barD);

    // ---- final vocab projection (NS=1, output-facing) ----
    {
        dim3 g((20000 + 127) / 128, (5120 + 127) / 128);
        hipLaunchKernelGGL((gemm_mfma_split<1>), g, dim3(256), 0, stream,
                           h_all, 1024, out_emb_W, 1024, out, 20000, out_emb_b, 5120, 20000, 1024);
    }
}